// Round 1
// baseline (2478.302 us; speedup 1.0000x reference)
//
#include <hip/hip_runtime.h>
#include <math.h>
#include <stddef.h>

#define WG 256

// ---------------------------------------------------------------------------
// Build dense A0[dst, src] += 1 per edge (self-edges included).
__global__ void build_A0_k(const int* __restrict__ esrc, const int* __restrict__ edst,
                           float* __restrict__ A, int E, int n) {
  int e = blockIdx.x * blockDim.x + threadIdx.x;
  if (e < E) atomicAdd(&A[(size_t)edst[e] * n + esrc[e]], 1.0f);
}

// Row sums -> dinv = 1/sqrt(deg), fixv = 2 where diag==0 (improved GCN self loop).
__global__ void rowsum_k(const float* __restrict__ A, int n,
                         float* __restrict__ dinv, float* __restrict__ fixv) {
  __shared__ float red[WG];
  int row = blockIdx.x;
  const float* Ar = A + (size_t)row * n;
  float s = 0.f;
  for (int j = threadIdx.x; j < n; j += WG) s += Ar[j];
  red[threadIdx.x] = s;
  __syncthreads();
  for (int d = WG / 2; d > 0; d >>= 1) {
    if ((int)threadIdx.x < d) red[threadIdx.x] += red[threadIdx.x + d];
    __syncthreads();
  }
  if (threadIdx.x == 0) {
    float fx = (Ar[row] == 0.0f) ? 2.0f : 0.0f;
    float deg = red[0] + fx;
    dinv[row] = (deg > 0.f) ? 1.0f / sqrtf(deg) : 0.f;
    fixv[row] = fx;
  }
}

// ---------------------------------------------------------------------------
// fp32 SGEMM: C = L(MxK) @ R(KxN), optional GCN epilogue:
//   v = acc (+ fixv[i]*R[i,j]) ; v *= dinv[i] ; v += bias[j] ; relu
// Tile 64 x TNv x 16, 256 threads, 4 x (TNv/16) micro-tile.
// Requires: M % 64 == 0, K % 16 == 0 (always true here). N guarded.
template<int TNv>
__global__ void __launch_bounds__(256) sgemm_k(
    const float* __restrict__ L, const float* __restrict__ R, float* __restrict__ C,
    int M, int N, int K,
    const float* __restrict__ dinv, const float* __restrict__ fixv,
    const float* __restrict__ bias, int relu) {
  const int MN = TNv / 16;
  __shared__ float Ls[16][68];   // padded: store bank pattern -> <=2-way (free)
  __shared__ float Rs[16][TNv];
  int tid = threadIdx.x;
  int tx = tid & 15, ty = tid >> 4;
  int m0 = blockIdx.y * 64;
  int n0 = blockIdx.x * TNv;
  float acc[4][MN];
#pragma unroll
  for (int i = 0; i < 4; i++)
#pragma unroll
    for (int j = 0; j < MN; j++) acc[i][j] = 0.f;

  int lk = tid & 15, lm = tid >> 4;
  int rn = tid % TNv, rk = tid / TNv;
  const int KS = 256 / TNv;

  for (int kt = 0; kt < K; kt += 16) {
#pragma unroll
    for (int r = 0; r < 4; r++) {
      int m = lm + r * 16;
      Ls[lk][m] = L[(size_t)(m0 + m) * K + kt + lk];
    }
#pragma unroll
    for (int r = 0; r < 16 / KS; r++) {
      int k = rk + r * KS;
      int gn = n0 + rn;
      Rs[k][rn] = (gn < N) ? R[(size_t)(kt + k) * N + gn] : 0.f;
    }
    __syncthreads();
#pragma unroll
    for (int k = 0; k < 16; k++) {
      float a[4], b[MN];
#pragma unroll
      for (int i = 0; i < 4; i++) a[i] = Ls[k][ty * 4 + i];
#pragma unroll
      for (int j = 0; j < MN; j++) b[j] = Rs[k][tx * MN + j];
#pragma unroll
      for (int i = 0; i < 4; i++)
#pragma unroll
        for (int j = 0; j < MN; j++) acc[i][j] += a[i] * b[j];
    }
    __syncthreads();
  }
#pragma unroll
  for (int i = 0; i < 4; i++) {
    int gi = m0 + ty * 4 + i;
#pragma unroll
    for (int j = 0; j < MN; j++) {
      int gj = n0 + tx * MN + j;
      if (gj < N) {
        float v = acc[i][j];
        if (fixv) v += fixv[gi] * R[(size_t)gi * N + gj];
        if (dinv) v *= dinv[gi];
        if (bias) v += bias[gj];
        if (relu) v = fmaxf(v, 0.f);
        C[(size_t)gi * N + gj] = v;
      }
    }
  }
}

// ---------------------------------------------------------------------------
// TopK pooling pieces
__global__ void normw_k(const float* __restrict__ w, int c, float* __restrict__ nw) {
  __shared__ float red[WG];
  float v = 0.f;
  if ((int)threadIdx.x < c) { float t = w[threadIdx.x]; v = t * t; }
  red[threadIdx.x] = v;
  __syncthreads();
  for (int d = WG / 2; d > 0; d >>= 1) {
    if ((int)threadIdx.x < d) red[threadIdx.x] += red[threadIdx.x + d];
    __syncthreads();
  }
  if (threadIdx.x == 0) nw[0] = sqrtf(red[0]);
}

__global__ void score_k(const float* __restrict__ x, const float* __restrict__ w,
                        int n, int c, const float* __restrict__ nw, float* __restrict__ s) {
  int i = blockIdx.x * blockDim.x + threadIdx.x;
  if (i >= n) return;
  const float* xr = x + (size_t)i * c;
  float d = 0.f;
  for (int k = 0; k < c; k++) d += xr[k] * w[k];
  s[i] = tanhf(d / nw[0]);
}

// Full bitonic sort (descending score, ties -> lower index first: matches lax.top_k).
// Single block; n is a power of two <= 4096.
__global__ void __launch_bounds__(1024) sortpool_k(
    const float* __restrict__ scores, int n, int keep,
    int* __restrict__ perm, float* __restrict__ vals, int* __restrict__ rank) {
  __shared__ float ss[4096];
  __shared__ int si[4096];
  int tid = threadIdx.x;
  for (int i = tid; i < n; i += 1024) { ss[i] = scores[i]; si[i] = i; rank[i] = -1; }
  __syncthreads();
  for (int k = 2; k <= n; k <<= 1) {
    for (int j = k >> 1; j > 0; j >>= 1) {
      for (int i = tid; i < n; i += 1024) {
        int ixj = i ^ j;
        if (ixj > i) {
          float s1 = ss[i], s2 = ss[ixj];
          int a1 = si[i], a2 = si[ixj];
          bool before2 = (s2 > s1) || (s2 == s1 && a2 < a1); // elem@ixj ranks before elem@i
          bool up = ((i & k) == 0);
          if (up == before2) { ss[i] = s2; ss[ixj] = s1; si[i] = a2; si[ixj] = a1; }
        }
      }
      __syncthreads();
    }
  }
  for (int a = tid; a < keep; a += 1024) {
    perm[a] = si[a];
    vals[a] = ss[a];
    rank[si[a]] = a;
  }
}

__global__ void poolx_k(const float* __restrict__ x, const int* __restrict__ perm,
                        const float* __restrict__ vals, int keep, int c, float* __restrict__ out) {
  int t = blockIdx.x * blockDim.x + threadIdx.x;
  if (t >= keep * c) return;
  int a = t / c, j = t - a * c;
  out[t] = x[(size_t)perm[a] * c + j] * vals[a];
}

// ---------------------------------------------------------------------------
// Level-1 augment via SpGEMM on edge lists (all contributions exact small ints).
__global__ void count_k(const int* __restrict__ esrc, const int* __restrict__ edst,
                        int* __restrict__ cnt, int E) {
  int e = blockIdx.x * blockDim.x + threadIdx.x;
  if (e >= E) return;
  int s = esrc[e], d = edst[e];
  if (s != d) atomicAdd(&cnt[s], 1);
}

__global__ void __launch_bounds__(1024) exscan_k(const int* __restrict__ cnt, int* __restrict__ off) {
  __shared__ int part[1024];
  int t = threadIdx.x;
  int l0 = cnt[t * 4], l1 = cnt[t * 4 + 1], l2 = cnt[t * 4 + 2], l3 = cnt[t * 4 + 3];
  int s = l0 + l1 + l2 + l3;
  part[t] = s;
  __syncthreads();
  for (int d = 1; d < 1024; d <<= 1) {
    int v = part[t];
    int u = (t >= d) ? part[t - d] : 0;
    __syncthreads();
    part[t] = v + u;
    __syncthreads();
  }
  int ex = (t > 0) ? part[t - 1] : 0;
  off[t * 4] = ex;
  off[t * 4 + 1] = ex + l0;
  off[t * 4 + 2] = ex + l0 + l1;
  off[t * 4 + 3] = ex + l0 + l1 + l2;
  if (t == 1023) off[4096] = part[1023];
}

__global__ void scatter_k(const int* __restrict__ esrc, const int* __restrict__ edst,
                          const int* __restrict__ off, int* __restrict__ fill,
                          int* __restrict__ bys, int E) {
  int e = blockIdx.x * blockDim.x + threadIdx.x;
  if (e >= E) return;
  int s = esrc[e], d = edst[e];
  if (s == d) return;
  int p = off[s] + atomicAdd(&fill[s], 1);
  bys[p] = d;
}

// A1p[rank[i], rank[j]] += A0'[i,k]*A0'[k,j] : join e2=(j->k) with out-edges of k.
__global__ void pairs_k(const int* __restrict__ esrc, const int* __restrict__ edst,
                        const int* __restrict__ off, const int* __restrict__ bys,
                        const int* __restrict__ rank, float* __restrict__ A1p, int E, int m) {
  int e = blockIdx.x * blockDim.x + threadIdx.x;
  if (e >= E) return;
  int j = esrc[e], k = edst[e];
  if (j == k) return;
  int rj = rank[j];
  if (rj < 0) return;
  int b0 = off[k], b1 = off[k + 1];
  for (int t = b0; t < b1; t++) {
    int ri = rank[bys[t]];
    if (ri >= 0) atomicAdd(&A1p[(size_t)ri * m + rj], 1.0f);
  }
}

// + 2*A0' term
__global__ void dbl_k(const int* __restrict__ esrc, const int* __restrict__ edst,
                      const int* __restrict__ rank, float* __restrict__ A1p, int E, int m) {
  int e = blockIdx.x * blockDim.x + threadIdx.x;
  if (e >= E) return;
  int s = esrc[e], d = edst[e];
  if (s == d) return;
  int rs = rank[s], rd = rank[d];
  if (rs >= 0 && rd >= 0) atomicAdd(&A1p[(size_t)rd * m + rs], 2.0f);
}

__global__ void zerodiag_k(float* __restrict__ A, int m) {
  int a = blockIdx.x * blockDim.x + threadIdx.x;
  if (a < m) A[(size_t)a * m + a] = 0.f;
}

// Gather pooled operands for dense augments: B = A + I, rows/cols at perm.
__global__ void gatherL_k(const float* __restrict__ A, const int* __restrict__ perm,
                          int n, int m, float* __restrict__ BL) {
  int t = blockIdx.x * blockDim.x + threadIdx.x;
  if (t >= m * n) return;
  int a = t / n, k = t - a * n;
  int pa = perm[a];
  BL[t] = A[(size_t)pa * n + k] + ((pa == k) ? 1.0f : 0.0f);
}

__global__ void gatherR_k(const float* __restrict__ A, const int* __restrict__ perm,
                          int n, int m, float* __restrict__ BR) {
  int t = blockIdx.x * blockDim.x + threadIdx.x;
  if (t >= n * m) return;
  int k = t / m, b = t - k * m;
  int pb = perm[b];
  BR[t] = A[(size_t)k * n + pb] + ((k == pb) ? 1.0f : 0.0f);
}

// ---------------------------------------------------------------------------
// Unpool: cat[:,0:c] = res, cat[:,c:2c] = scatter(cur[:, :c]) via perm
__global__ void catinit_k(const float* __restrict__ res, int n, int c, float* __restrict__ cat) {
  int t = blockIdx.x * blockDim.x + threadIdx.x;
  int tot = n * 2 * c;
  if (t >= tot) return;
  int i = t / (2 * c), j = t - i * 2 * c;
  cat[t] = (j < c) ? res[(size_t)i * c + j] : 0.f;
}

__global__ void catscat_k(const int* __restrict__ perm, const float* __restrict__ cur,
                          int keep, int c, int cw, float* __restrict__ cat) {
  int t = blockIdx.x * blockDim.x + threadIdx.x;
  if (t >= keep * c) return;
  int a = t / c, j = t - a * c;
  cat[(size_t)perm[a] * (2 * c) + c + j] = cur[(size_t)a * cw + j];
}

__global__ void softmax_k(const float* __restrict__ z, float* __restrict__ out, int n, int c) {
  int i = blockIdx.x * blockDim.x + threadIdx.x;
  if (i >= n) return;
  const float* zr = z + (size_t)i * c;
  float m = zr[0];
  for (int j = 1; j < c; j++) m = fmaxf(m, zr[j]);
  float e[64];
  float s = 0.f;
  for (int j = 0; j < c; j++) { e[j] = expf(zr[j] - m); s += e[j]; }
  for (int j = 0; j < c; j++) out[(size_t)i * c + j] = e[j] / s;
}

// ---------------------------------------------------------------------------
extern "C" void kernel_launch(void* const* d_in, const int* in_sizes, int n_in,
                              void* d_out, int out_size, void* d_ws, size_t ws_size,
                              hipStream_t stream) {
  (void)n_in; (void)out_size; (void)ws_size;
  const float* xin = (const float*)d_in[0];
  const int* ei = (const int*)d_in[1];
  const int E = in_sizes[1] / 2;
  const int* esrc = ei;
  const int* edst = ei + E;
  const float* Wd[5] = {(const float*)d_in[2], (const float*)d_in[4], (const float*)d_in[6],
                        (const float*)d_in[8], (const float*)d_in[10]};
  const float* bd[5] = {(const float*)d_in[3], (const float*)d_in[5], (const float*)d_in[7],
                        (const float*)d_in[9], (const float*)d_in[11]};
  const float* pw[4] = {(const float*)d_in[12], (const float*)d_in[13],
                        (const float*)d_in[14], (const float*)d_in[15]};
  const float* Wu[4] = {(const float*)d_in[16], (const float*)d_in[18],
                        (const float*)d_in[20], (const float*)d_in[22]};
  const float* bu[4] = {(const float*)d_in[17], (const float*)d_in[19],
                        (const float*)d_in[21], (const float*)d_in[23]};
  const float* Wo = (const float*)d_in[24];
  const float* bo = (const float*)d_in[25];
  float* out = (float*)d_out;

  char* p = (char*)d_ws;
  auto bumpf = [&](size_t ne) -> float* { float* r = (float*)p; p += ((ne * 4 + 255) & ~(size_t)255); return r; };
  auto bumpi = [&](size_t ne) -> int* { int* r = (int*)p; p += ((ne * 4 + 255) & ~(size_t)255); return r; };

  float* A0 = bumpf((size_t)4096 * 4096);
  float* A1 = bumpf((size_t)2048 * 2048);
  float* A2 = bumpf((size_t)1024 * 1024);
  float* A3 = bumpf((size_t)512 * 512);
  float* A4 = bumpf((size_t)256 * 256);
  float* BL = bumpf((size_t)1024 * 2048);
  float* BR = bumpf((size_t)1024 * 2048);
  float* XS0 = bumpf((size_t)4096 * 32);
  float* XS1 = bumpf((size_t)2048 * 64);
  float* XS2 = bumpf((size_t)1024 * 128);
  float* XS3 = bumpf((size_t)512 * 256);
  float* XA = bumpf((size_t)4096 * 64);
  float* XB = bumpf((size_t)4096 * 32);
  float* Y = bumpf((size_t)4096 * 64);
  float* scores = bumpf(4096);
  float* vals = bumpf(2048);
  float* nw = bumpf(64);
  float* dinv = bumpf(4096);
  float* fixv = bumpf(4096);
  int* perm1 = bumpi(2048);
  int* perm2 = bumpi(1024);
  int* perm3 = bumpi(512);
  int* perm4 = bumpi(256);
  int* rank = bumpi(4096);
  int* cnt = bumpi(4096);
  int* offb = bumpi(4100);
  int* fill = bumpi(4096);
  int* bys = bumpi((size_t)E);

  auto sgemm = [&](const float* L, const float* R, float* C, int M, int N, int K,
                   const float* di, const float* fx, const float* bi, int relu) {
    if (N <= 32) {
      dim3 g((N + 31) / 32, M / 64);
      sgemm_k<32><<<g, dim3(256), 0, stream>>>(L, R, C, M, N, K, di, fx, bi, relu);
    } else {
      dim3 g((N + 63) / 64, M / 64);
      sgemm_k<64><<<g, dim3(256), 0, stream>>>(L, R, C, M, N, K, di, fx, bi, relu);
    }
  };
  auto gcn = [&](const float* A, int n, const float* x, int cin, const float* W, int cout,
                 const float* bi, int relu, float* zout, bool dosum) {
    if (dosum) rowsum_k<<<dim3(n), dim3(WG), 0, stream>>>(A, n, dinv, fixv);
    sgemm(x, W, Y, n, cout, cin, dinv, nullptr, nullptr, 0);        // y' = dinv .* (xW)
    sgemm(A, Y, zout, n, cout, n, dinv, fixv, bi, relu);            // z = dinv .* (A y' + fix*y') + b
  };
  auto pool = [&](const float* x, int n, int c, const float* w, int* perm, float* xout) {
    normw_k<<<dim3(1), dim3(WG), 0, stream>>>(w, c, nw);
    score_k<<<dim3((n + WG - 1) / WG), dim3(WG), 0, stream>>>(x, w, n, c, nw, scores);
    sortpool_k<<<dim3(1), dim3(1024), 0, stream>>>(scores, n, n / 2, perm, vals, rank);
    int keep = n / 2;
    poolx_k<<<dim3((keep * c + WG - 1) / WG), dim3(WG), 0, stream>>>(x, perm, vals, keep, c, xout);
  };
  auto aug = [&](const float* Ap, int n, const int* perm, float* Anew) {
    int m = n / 2;
    gatherL_k<<<dim3((m * n + WG - 1) / WG), dim3(WG), 0, stream>>>(Ap, perm, n, m, BL);
    gatherR_k<<<dim3((n * m + WG - 1) / WG), dim3(WG), 0, stream>>>(Ap, perm, n, m, BR);
    sgemm(BL, BR, Anew, m, m, n, nullptr, nullptr, nullptr, 0);
    zerodiag_k<<<dim3((m + WG - 1) / WG), dim3(WG), 0, stream>>>(Anew, m);
  };

  // ---- build A0, GCN0 ----
  hipMemsetAsync(A0, 0, (size_t)4096 * 4096 * 4, stream);
  build_A0_k<<<dim3((E + WG - 1) / WG), dim3(WG), 0, stream>>>(esrc, edst, A0, E, 4096);
  gcn(A0, 4096, xin, 128, Wd[0], 32, bd[0], 1, XS0, true);

  // ---- pool1 + sparse augment1 (directly pooled to 2048^2) ----
  pool(XS0, 4096, 32, pw[0], perm1, XA);
  hipMemsetAsync(cnt, 0, 4096 * 4, stream);
  hipMemsetAsync(fill, 0, 4096 * 4, stream);
  hipMemsetAsync(A1, 0, (size_t)2048 * 2048 * 4, stream);
  count_k<<<dim3((E + WG - 1) / WG), dim3(WG), 0, stream>>>(esrc, edst, cnt, E);
  exscan_k<<<dim3(1), dim3(1024), 0, stream>>>(cnt, offb);
  scatter_k<<<dim3((E + WG - 1) / WG), dim3(WG), 0, stream>>>(esrc, edst, offb, fill, bys, E);
  pairs_k<<<dim3((E + WG - 1) / WG), dim3(WG), 0, stream>>>(esrc, edst, offb, bys, rank, A1, E, 2048);
  dbl_k<<<dim3((E + WG - 1) / WG), dim3(WG), 0, stream>>>(esrc, edst, rank, A1, E, 2048);
  zerodiag_k<<<dim3((2048 + WG - 1) / WG), dim3(WG), 0, stream>>>(A1, 2048);
  gcn(A1, 2048, XA, 32, Wd[1], 64, bd[1], 1, XS1, true);

  // ---- levels 2..4: pool, pooled dense augment, GCN ----
  pool(XS1, 2048, 64, pw[1], perm2, XA);
  aug(A1, 2048, perm2, A2);
  gcn(A2, 1024, XA, 64, Wd[2], 128, bd[2], 1, XS2, true);

  pool(XS2, 1024, 128, pw[2], perm3, XA);
  aug(A2, 1024, perm3, A3);
  gcn(A3, 512, XA, 128, Wd[3], 256, bd[3], 1, XS3, true);

  pool(XS3, 512, 256, pw[3], perm4, XA);
  aug(A3, 512, perm4, A4);
  gcn(A4, 256, XA, 256, Wd[4], 512, bd[4], 1, XB, true);

  // ---- up path (concat skip + unpool scatter + GCN) ----
  catinit_k<<<dim3((512 * 512 + WG - 1) / WG), dim3(WG), 0, stream>>>(XS3, 512, 256, XA);
  catscat_k<<<dim3((256 * 256 + WG - 1) / WG), dim3(WG), 0, stream>>>(perm4, XB, 256, 256, 512, XA);
  gcn(A3, 512, XA, 512, Wu[0], 256, bu[0], 1, XB, true);

  catinit_k<<<dim3((1024 * 256 + WG - 1) / WG), dim3(WG), 0, stream>>>(XS2, 1024, 128, XA);
  catscat_k<<<dim3((512 * 128 + WG - 1) / WG), dim3(WG), 0, stream>>>(perm3, XB, 512, 128, 256, XA);
  gcn(A2, 1024, XA, 256, Wu[1], 128, bu[1], 1, XB, true);

  catinit_k<<<dim3((2048 * 128 + WG - 1) / WG), dim3(WG), 0, stream>>>(XS1, 2048, 64, XA);
  catscat_k<<<dim3((1024 * 64 + WG - 1) / WG), dim3(WG), 0, stream>>>(perm2, XB, 1024, 64, 128, XA);
  gcn(A1, 2048, XA, 128, Wu[2], 64, bu[2], 1, XB, true);

  catinit_k<<<dim3((4096 * 64 + WG - 1) / WG), dim3(WG), 0, stream>>>(XS0, 4096, 32, XA);
  catscat_k<<<dim3((2048 * 32 + WG - 1) / WG), dim3(WG), 0, stream>>>(perm1, XB, 2048, 32, 64, XA);
  gcn(A0, 4096, XA, 64, Wu[3], 32, bu[3], 0, XB, true);

  // ---- final GCN (reuses A0's dinv/fixv) + softmax ----
  sgemm(XB, Wo, Y, 4096, 37, 32, dinv, nullptr, nullptr, 0);
  sgemm(A0, Y, XA, 4096, 37, 4096, dinv, fixv, bo, 0);
  softmax_k<<<dim3((4096 + WG - 1) / WG), dim3(WG), 0, stream>>>(XA, out, 4096, 37);
}

// Round 2
// 2275.700 us; speedup vs baseline: 1.0890x; 1.0890x over previous
//
#include <hip/hip_runtime.h>
#include <math.h>
#include <stddef.h>

#define WG 256

// ---------------------------------------------------------------------------
// Build dense A0[dst, src] += 1 per edge (self-edges included).
__global__ void build_A0_k(const int* __restrict__ esrc, const int* __restrict__ edst,
                           float* __restrict__ A, int E, int n) {
  int e = blockIdx.x * blockDim.x + threadIdx.x;
  if (e < E) atomicAdd(&A[(size_t)edst[e] * n + esrc[e]], 1.0f);
}

// Row sums -> dinv = 1/sqrt(deg), fixv = 2 where diag==0 (improved GCN self loop).
__global__ void rowsum_k(const float* __restrict__ A, int n,
                         float* __restrict__ dinv, float* __restrict__ fixv) {
  __shared__ float red[WG];
  int row = blockIdx.x;
  const float* Ar = A + (size_t)row * n;
  float s = 0.f;
  for (int j = threadIdx.x; j < n; j += WG) s += Ar[j];
  red[threadIdx.x] = s;
  __syncthreads();
  for (int d = WG / 2; d > 0; d >>= 1) {
    if ((int)threadIdx.x < d) red[threadIdx.x] += red[threadIdx.x + d];
    __syncthreads();
  }
  if (threadIdx.x == 0) {
    float fx = (Ar[row] == 0.0f) ? 2.0f : 0.0f;
    float deg = red[0] + fx;
    dinv[row] = (deg > 0.f) ? 1.0f / sqrtf(deg) : 0.f;
    fixv[row] = fx;
  }
}

// ---------------------------------------------------------------------------
// fp32 SGEMM: C = L(MxK) @ R(KxN), optional row scale (dinv) + bias + relu.
// transC: store C transposed with leading dim ldc (C[j*ldc + i]).
template<int TNv>
__global__ void __launch_bounds__(256) sgemm_k(
    const float* __restrict__ L, const float* __restrict__ R, float* __restrict__ C,
    int M, int N, int K,
    const float* __restrict__ dinv, const float* __restrict__ bias, int relu,
    int transC, int ldc) {
  const int MN = TNv / 16;
  __shared__ float Ls[16][68];
  __shared__ float Rs[16][TNv];
  int tid = threadIdx.x;
  int tx = tid & 15, ty = tid >> 4;
  int m0 = blockIdx.y * 64;
  int n0 = blockIdx.x * TNv;
  float acc[4][MN];
#pragma unroll
  for (int i = 0; i < 4; i++)
#pragma unroll
    for (int j = 0; j < MN; j++) acc[i][j] = 0.f;

  int lk = tid & 15, lm = tid >> 4;
  int rn = tid % TNv, rk = tid / TNv;
  const int KS = 256 / TNv;

  for (int kt = 0; kt < K; kt += 16) {
#pragma unroll
    for (int r = 0; r < 4; r++) {
      int m = lm + r * 16;
      Ls[lk][m] = L[(size_t)(m0 + m) * K + kt + lk];
    }
#pragma unroll
    for (int r = 0; r < 16 / KS; r++) {
      int k = rk + r * KS;
      int gn = n0 + rn;
      Rs[k][rn] = (gn < N) ? R[(size_t)(kt + k) * N + gn] : 0.f;
    }
    __syncthreads();
#pragma unroll
    for (int k = 0; k < 16; k++) {
      float a[4], b[MN];
#pragma unroll
      for (int i = 0; i < 4; i++) a[i] = Ls[k][ty * 4 + i];
#pragma unroll
      for (int j = 0; j < MN; j++) b[j] = Rs[k][tx * MN + j];
#pragma unroll
      for (int i = 0; i < 4; i++)
#pragma unroll
        for (int j = 0; j < MN; j++) acc[i][j] += a[i] * b[j];
    }
    __syncthreads();
  }
#pragma unroll
  for (int i = 0; i < 4; i++) {
    int gi = m0 + ty * 4 + i;
#pragma unroll
    for (int j = 0; j < MN; j++) {
      int gj = n0 + tx * MN + j;
      if (gj < N) {
        float v = acc[i][j];
        if (dinv) v *= dinv[gi];
        if (bias) v += bias[gj];
        if (relu) v = fmaxf(v, 0.f);
        if (transC) C[(size_t)gj * ldc + gi] = v;
        else C[(size_t)gi * N + gj] = v;
      }
    }
  }
}

// ---------------------------------------------------------------------------
// Propagation: Z = Ahat(MxK) @ y' with y' given TRANSPOSED as YT[N][K].
// One wave per 4 rows; lanes = 16 K-lanes x 4 col-groups. No barriers in the
// K loop; A streamed coalesced float4; YT served from L1/L2. Butterfly-reduce
// over K-lanes, per-wave LDS transpose, fused epilogue:
//   z[i][c] = dinv[i]*(sum_k A[i][k] y'[k][c] + fixv[i]*y'[i][c]) + bias[c]
template<int NC>
__global__ void __launch_bounds__(256) prop_k(
    const float* __restrict__ A, const float* __restrict__ YT, float* __restrict__ C,
    int M, int N, int K,
    const float* __restrict__ dinv, const float* __restrict__ fixv,
    const float* __restrict__ bias, int relu) {
  const int CPG = NC / 4;
  __shared__ float red[4][4][NC];
  int tid = threadIdx.x;
  int wid = tid >> 6, lane = tid & 63;
  int kl = lane & 15, cg = lane >> 4;
  int m0 = (blockIdx.x * 4 + wid) * 4;
  int ncb = blockIdx.y * NC;
  float acc[4][CPG];
#pragma unroll
  for (int r = 0; r < 4; r++)
#pragma unroll
    for (int c = 0; c < CPG; c++) acc[r][c] = 0.f;

  for (int k0 = 0; k0 < K; k0 += 64) {
    float4 a4[4];
#pragma unroll
    for (int r = 0; r < 4; r++)
      a4[r] = *(const float4*)(A + (size_t)(m0 + r) * K + k0 + kl * 4);
#pragma unroll
    for (int c = 0; c < CPG; c++) {
      int cc = ncb + cg * CPG + c;
      if (cc < N) {
        float4 y4 = *(const float4*)(YT + (size_t)cc * K + k0 + kl * 4);
#pragma unroll
        for (int r = 0; r < 4; r++) {
          acc[r][c] += a4[r].x * y4.x;
          acc[r][c] += a4[r].y * y4.y;
          acc[r][c] += a4[r].z * y4.z;
          acc[r][c] += a4[r].w * y4.w;
        }
      }
    }
  }
  // reduce across the 16 K-lanes (xor masks 1,2,4,8)
#pragma unroll
  for (int m = 1; m <= 8; m <<= 1)
#pragma unroll
    for (int r = 0; r < 4; r++)
#pragma unroll
      for (int c = 0; c < CPG; c++)
        acc[r][c] += __shfl_xor(acc[r][c], m, 64);
  if (kl == 0) {
#pragma unroll
    for (int r = 0; r < 4; r++)
#pragma unroll
      for (int c = 0; c < CPG; c++) red[wid][r][cg * CPG + c] = acc[r][c];
  }
  __syncthreads();
  if (lane < NC) {
    int cc = ncb + lane;
    if (cc < N) {
      float bv = bias ? bias[cc] : 0.f;
#pragma unroll
      for (int r = 0; r < 4; r++) {
        int row = m0 + r;
        float v = red[wid][r][lane];
        if (fixv) v += fixv[row] * YT[(size_t)cc * K + row];
        v *= dinv[row];
        v += bv;
        if (relu) v = fmaxf(v, 0.f);
        C[(size_t)row * N + cc] = v;
      }
    }
  }
}

// ---------------------------------------------------------------------------
// TopK pooling pieces
__global__ void normw_k(const float* __restrict__ w, int c, float* __restrict__ nw) {
  __shared__ float red[WG];
  float v = 0.f;
  if ((int)threadIdx.x < c) { float t = w[threadIdx.x]; v = t * t; }
  red[threadIdx.x] = v;
  __syncthreads();
  for (int d = WG / 2; d > 0; d >>= 1) {
    if ((int)threadIdx.x < d) red[threadIdx.x] += red[threadIdx.x + d];
    __syncthreads();
  }
  if (threadIdx.x == 0) nw[0] = sqrtf(red[0]);
}

__global__ void score_k(const float* __restrict__ x, const float* __restrict__ w,
                        int n, int c, const float* __restrict__ nw, float* __restrict__ s) {
  int i = blockIdx.x * blockDim.x + threadIdx.x;
  if (i >= n) return;
  const float* xr = x + (size_t)i * c;
  float d = 0.f;
  for (int k = 0; k < c; k++) d += xr[k] * w[k];
  s[i] = tanhf(d / nw[0]);
}

// Full bitonic sort (descending score, ties -> lower index first: matches lax.top_k).
__global__ void __launch_bounds__(1024) sortpool_k(
    const float* __restrict__ scores, int n, int keep,
    int* __restrict__ perm, float* __restrict__ vals, int* __restrict__ rank) {
  __shared__ float ss[4096];
  __shared__ int si[4096];
  int tid = threadIdx.x;
  for (int i = tid; i < n; i += 1024) { ss[i] = scores[i]; si[i] = i; rank[i] = -1; }
  __syncthreads();
  for (int k = 2; k <= n; k <<= 1) {
    for (int j = k >> 1; j > 0; j >>= 1) {
      for (int i = tid; i < n; i += 1024) {
        int ixj = i ^ j;
        if (ixj > i) {
          float s1 = ss[i], s2 = ss[ixj];
          int a1 = si[i], a2 = si[ixj];
          bool before2 = (s2 > s1) || (s2 == s1 && a2 < a1);
          bool up = ((i & k) == 0);
          if (up == before2) { ss[i] = s2; ss[ixj] = s1; si[i] = a2; si[ixj] = a1; }
        }
      }
      __syncthreads();
    }
  }
  for (int a = tid; a < keep; a += 1024) {
    perm[a] = si[a];
    vals[a] = ss[a];
    rank[si[a]] = a;
  }
}

__global__ void poolx_k(const float* __restrict__ x, const int* __restrict__ perm,
                        const float* __restrict__ vals, int keep, int c, float* __restrict__ out) {
  int t = blockIdx.x * blockDim.x + threadIdx.x;
  if (t >= keep * c) return;
  int a = t / c, j = t - a * c;
  out[t] = x[(size_t)perm[a] * c + j] * vals[a];
}

// ---------------------------------------------------------------------------
// Level-1 augment via SpGEMM on edge lists (all contributions exact small ints).
__global__ void count_k(const int* __restrict__ esrc, const int* __restrict__ edst,
                        int* __restrict__ cnt, int E) {
  int e = blockIdx.x * blockDim.x + threadIdx.x;
  if (e >= E) return;
  int s = esrc[e], d = edst[e];
  if (s != d) atomicAdd(&cnt[s], 1);
}

__global__ void __launch_bounds__(1024) exscan_k(const int* __restrict__ cnt, int* __restrict__ off) {
  __shared__ int part[1024];
  int t = threadIdx.x;
  int l0 = cnt[t * 4], l1 = cnt[t * 4 + 1], l2 = cnt[t * 4 + 2], l3 = cnt[t * 4 + 3];
  int s = l0 + l1 + l2 + l3;
  part[t] = s;
  __syncthreads();
  for (int d = 1; d < 1024; d <<= 1) {
    int v = part[t];
    int u = (t >= d) ? part[t - d] : 0;
    __syncthreads();
    part[t] = v + u;
    __syncthreads();
  }
  int ex = (t > 0) ? part[t - 1] : 0;
  off[t * 4] = ex;
  off[t * 4 + 1] = ex + l0;
  off[t * 4 + 2] = ex + l0 + l1;
  off[t * 4 + 3] = ex + l0 + l1 + l2;
  if (t == 1023) off[4096] = part[1023];
}

__global__ void scatter_k(const int* __restrict__ esrc, const int* __restrict__ edst,
                          const int* __restrict__ off, int* __restrict__ fill,
                          int* __restrict__ bys, int E) {
  int e = blockIdx.x * blockDim.x + threadIdx.x;
  if (e >= E) return;
  int s = esrc[e], d = edst[e];
  if (s == d) return;
  int p = off[s] + atomicAdd(&fill[s], 1);
  bys[p] = d;
}

__global__ void pairs_k(const int* __restrict__ esrc, const int* __restrict__ edst,
                        const int* __restrict__ off, const int* __restrict__ bys,
                        const int* __restrict__ rank, float* __restrict__ A1p, int E, int m) {
  int e = blockIdx.x * blockDim.x + threadIdx.x;
  if (e >= E) return;
  int j = esrc[e], k = edst[e];
  if (j == k) return;
  int rj = rank[j];
  if (rj < 0) return;
  int b0 = off[k], b1 = off[k + 1];
  for (int t = b0; t < b1; t++) {
    int ri = rank[bys[t]];
    if (ri >= 0) atomicAdd(&A1p[(size_t)ri * m + rj], 1.0f);
  }
}

__global__ void dbl_k(const int* __restrict__ esrc, const int* __restrict__ edst,
                      const int* __restrict__ rank, float* __restrict__ A1p, int E, int m) {
  int e = blockIdx.x * blockDim.x + threadIdx.x;
  if (e >= E) return;
  int s = esrc[e], d = edst[e];
  if (s == d) return;
  int rs = rank[s], rd = rank[d];
  if (rs >= 0 && rd >= 0) atomicAdd(&A1p[(size_t)rd * m + rs], 2.0f);
}

__global__ void zerodiag_k(float* __restrict__ A, int m) {
  int a = blockIdx.x * blockDim.x + threadIdx.x;
  if (a < m) A[(size_t)a * m + a] = 0.f;
}

// Gather pooled operands for dense augments: B = A + I, rows/cols at perm.
__global__ void gatherL_k(const float* __restrict__ A, const int* __restrict__ perm,
                          int n, int m, float* __restrict__ BL) {
  int t = blockIdx.x * blockDim.x + threadIdx.x;
  if (t >= m * n) return;
  int a = t / n, k = t - a * n;
  int pa = perm[a];
  BL[t] = A[(size_t)pa * n + k] + ((pa == k) ? 1.0f : 0.0f);
}

__global__ void gatherR_k(const float* __restrict__ A, const int* __restrict__ perm,
                          int n, int m, float* __restrict__ BR) {
  int t = blockIdx.x * blockDim.x + threadIdx.x;
  if (t >= n * m) return;
  int k = t / m, b = t - k * m;
  int pb = perm[b];
  BR[t] = A[(size_t)k * n + pb] + ((k == pb) ? 1.0f : 0.0f);
}

// ---------------------------------------------------------------------------
__global__ void catinit_k(const float* __restrict__ res, int n, int c, float* __restrict__ cat) {
  int t = blockIdx.x * blockDim.x + threadIdx.x;
  int tot = n * 2 * c;
  if (t >= tot) return;
  int i = t / (2 * c), j = t - i * 2 * c;
  cat[t] = (j < c) ? res[(size_t)i * c + j] : 0.f;
}

__global__ void catscat_k(const int* __restrict__ perm, const float* __restrict__ cur,
                          int keep, int c, int cw, float* __restrict__ cat) {
  int t = blockIdx.x * blockDim.x + threadIdx.x;
  if (t >= keep * c) return;
  int a = t / c, j = t - a * c;
  cat[(size_t)perm[a] * (2 * c) + c + j] = cur[(size_t)a * cw + j];
}

__global__ void softmax_k(const float* __restrict__ z, float* __restrict__ out, int n, int c) {
  int i = blockIdx.x * blockDim.x + threadIdx.x;
  if (i >= n) return;
  const float* zr = z + (size_t)i * c;
  float m = zr[0];
  for (int j = 1; j < c; j++) m = fmaxf(m, zr[j]);
  float e[64];
  float s = 0.f;
  for (int j = 0; j < c; j++) { e[j] = expf(zr[j] - m); s += e[j]; }
  for (int j = 0; j < c; j++) out[(size_t)i * c + j] = e[j] / s;
}

// ---------------------------------------------------------------------------
extern "C" void kernel_launch(void* const* d_in, const int* in_sizes, int n_in,
                              void* d_out, int out_size, void* d_ws, size_t ws_size,
                              hipStream_t stream) {
  (void)n_in; (void)out_size; (void)ws_size;
  const float* xin = (const float*)d_in[0];
  const int* ei = (const int*)d_in[1];
  const int E = in_sizes[1] / 2;
  const int* esrc = ei;
  const int* edst = ei + E;
  const float* Wd[5] = {(const float*)d_in[2], (const float*)d_in[4], (const float*)d_in[6],
                        (const float*)d_in[8], (const float*)d_in[10]};
  const float* bd[5] = {(const float*)d_in[3], (const float*)d_in[5], (const float*)d_in[7],
                        (const float*)d_in[9], (const float*)d_in[11]};
  const float* pw[4] = {(const float*)d_in[12], (const float*)d_in[13],
                        (const float*)d_in[14], (const float*)d_in[15]};
  const float* Wu[4] = {(const float*)d_in[16], (const float*)d_in[18],
                        (const float*)d_in[20], (const float*)d_in[22]};
  const float* bu[4] = {(const float*)d_in[17], (const float*)d_in[19],
                        (const float*)d_in[21], (const float*)d_in[23]};
  const float* Wo = (const float*)d_in[24];
  const float* bo = (const float*)d_in[25];
  float* out = (float*)d_out;

  char* p = (char*)d_ws;
  auto bumpf = [&](size_t ne) -> float* { float* r = (float*)p; p += ((ne * 4 + 255) & ~(size_t)255); return r; };
  auto bumpi = [&](size_t ne) -> int* { int* r = (int*)p; p += ((ne * 4 + 255) & ~(size_t)255); return r; };

  float* A0 = bumpf((size_t)4096 * 4096);
  float* A1 = bumpf((size_t)2048 * 2048);
  float* A2 = bumpf((size_t)1024 * 1024);
  float* A3 = bumpf((size_t)512 * 512);
  float* A4 = bumpf((size_t)256 * 256);
  float* BL = bumpf((size_t)1024 * 2048);
  float* BR = bumpf((size_t)1024 * 2048);
  float* XS0 = bumpf((size_t)4096 * 32);
  float* XS1 = bumpf((size_t)2048 * 64);
  float* XS2 = bumpf((size_t)1024 * 128);
  float* XS3 = bumpf((size_t)512 * 256);
  float* XA = bumpf((size_t)4096 * 64);
  float* XB = bumpf((size_t)4096 * 32);
  float* YT = bumpf((size_t)4096 * 64);
  float* scores = bumpf(4096);
  float* vals = bumpf(2048);
  float* nw = bumpf(64);
  float* dinvL[5];
  float* fixvL[5];
  int nsz[5] = {4096, 2048, 1024, 512, 256};
  for (int i = 0; i < 5; i++) { dinvL[i] = bumpf(nsz[i]); fixvL[i] = bumpf(nsz[i]); }
  int* perm1 = bumpi(2048);
  int* perm2 = bumpi(1024);
  int* perm3 = bumpi(512);
  int* perm4 = bumpi(256);
  int* rank = bumpi(4096);
  int* cnt = bumpi(4096);
  int* offb = bumpi(4100);
  int* fill = bumpi(4096);
  int* bys = bumpi((size_t)E);

  auto sgemm = [&](const float* L, const float* R, float* C, int M, int N, int K,
                   const float* di, const float* bi, int relu, int transC, int ldc) {
    if (N <= 32) {
      dim3 g((N + 31) / 32, M / 64);
      sgemm_k<32><<<g, dim3(256), 0, stream>>>(L, R, C, M, N, K, di, bi, relu, transC, ldc);
    } else {
      dim3 g((N + 63) / 64, M / 64);
      sgemm_k<64><<<g, dim3(256), 0, stream>>>(L, R, C, M, N, K, di, bi, relu, transC, ldc);
    }
  };
  auto gcn = [&](const float* A, int n, const float* x, int cin, const float* W, int cout,
                 const float* bi, int relu, float* zout, const float* di, const float* fx) {
    // y' (transposed): YT[cout][n] = (dinv .* (x @ W))^T
    sgemm(x, W, YT, n, cout, cin, di, nullptr, 0, 1, n);
    if (cout <= 32) {
      dim3 g(n / 16, 1);
      prop_k<32><<<g, dim3(256), 0, stream>>>(A, YT, zout, n, cout, n, di, fx, bi, relu);
    } else {
      dim3 g(n / 16, (cout + 63) / 64);
      prop_k<64><<<g, dim3(256), 0, stream>>>(A, YT, zout, n, cout, n, di, fx, bi, relu);
    }
  };
  auto pool = [&](const float* x, int n, int c, const float* w, int* perm, float* xout) {
    normw_k<<<dim3(1), dim3(WG), 0, stream>>>(w, c, nw);
    score_k<<<dim3((n + WG - 1) / WG), dim3(WG), 0, stream>>>(x, w, n, c, nw, scores);
    sortpool_k<<<dim3(1), dim3(1024), 0, stream>>>(scores, n, n / 2, perm, vals, rank);
    int keep = n / 2;
    poolx_k<<<dim3((keep * c + WG - 1) / WG), dim3(WG), 0, stream>>>(x, perm, vals, keep, c, xout);
  };
  auto aug = [&](const float* Ap, int n, const int* perm, float* Anew) {
    int m = n / 2;
    gatherL_k<<<dim3((m * n + WG - 1) / WG), dim3(WG), 0, stream>>>(Ap, perm, n, m, BL);
    gatherR_k<<<dim3((n * m + WG - 1) / WG), dim3(WG), 0, stream>>>(Ap, perm, n, m, BR);
    sgemm(BL, BR, Anew, m, m, n, nullptr, nullptr, 0, 0, 0);
    zerodiag_k<<<dim3((m + WG - 1) / WG), dim3(WG), 0, stream>>>(Anew, m);
  };

  // ---- build A0, GCN0 ----
  hipMemsetAsync(A0, 0, (size_t)4096 * 4096 * 4, stream);
  build_A0_k<<<dim3((E + WG - 1) / WG), dim3(WG), 0, stream>>>(esrc, edst, A0, E, 4096);
  rowsum_k<<<dim3(4096), dim3(WG), 0, stream>>>(A0, 4096, dinvL[0], fixvL[0]);
  gcn(A0, 4096, xin, 128, Wd[0], 32, bd[0], 1, XS0, dinvL[0], fixvL[0]);

  // ---- pool1 + sparse augment1 (directly pooled to 2048^2) ----
  pool(XS0, 4096, 32, pw[0], perm1, XA);
  hipMemsetAsync(cnt, 0, 4096 * 4, stream);
  hipMemsetAsync(fill, 0, 4096 * 4, stream);
  hipMemsetAsync(A1, 0, (size_t)2048 * 2048 * 4, stream);
  count_k<<<dim3((E + WG - 1) / WG), dim3(WG), 0, stream>>>(esrc, edst, cnt, E);
  exscan_k<<<dim3(1), dim3(1024), 0, stream>>>(cnt, offb);
  scatter_k<<<dim3((E + WG - 1) / WG), dim3(WG), 0, stream>>>(esrc, edst, offb, fill, bys, E);
  pairs_k<<<dim3((E + WG - 1) / WG), dim3(WG), 0, stream>>>(esrc, edst, offb, bys, rank, A1, E, 2048);
  dbl_k<<<dim3((E + WG - 1) / WG), dim3(WG), 0, stream>>>(esrc, edst, rank, A1, E, 2048);
  zerodiag_k<<<dim3((2048 + WG - 1) / WG), dim3(WG), 0, stream>>>(A1, 2048);
  rowsum_k<<<dim3(2048), dim3(WG), 0, stream>>>(A1, 2048, dinvL[1], fixvL[1]);
  gcn(A1, 2048, XA, 32, Wd[1], 64, bd[1], 1, XS1, dinvL[1], fixvL[1]);

  // ---- levels 2..4 ----
  pool(XS1, 2048, 64, pw[1], perm2, XA);
  aug(A1, 2048, perm2, A2);
  rowsum_k<<<dim3(1024), dim3(WG), 0, stream>>>(A2, 1024, dinvL[2], fixvL[2]);
  gcn(A2, 1024, XA, 64, Wd[2], 128, bd[2], 1, XS2, dinvL[2], fixvL[2]);

  pool(XS2, 1024, 128, pw[2], perm3, XA);
  aug(A2, 1024, perm3, A3);
  rowsum_k<<<dim3(512), dim3(WG), 0, stream>>>(A3, 512, dinvL[3], fixvL[3]);
  gcn(A3, 512, XA, 128, Wd[3], 256, bd[3], 1, XS3, dinvL[3], fixvL[3]);

  pool(XS3, 512, 256, pw[3], perm4, XA);
  aug(A3, 512, perm4, A4);
  rowsum_k<<<dim3(256), dim3(WG), 0, stream>>>(A4, 256, dinvL[4], fixvL[4]);
  gcn(A4, 256, XA, 256, Wd[4], 512, bd[4], 1, XB, dinvL[4], fixvL[4]);

  // ---- up path ----
  catinit_k<<<dim3((512 * 512 + WG - 1) / WG), dim3(WG), 0, stream>>>(XS3, 512, 256, XA);
  catscat_k<<<dim3((256 * 256 + WG - 1) / WG), dim3(WG), 0, stream>>>(perm4, XB, 256, 256, 512, XA);
  gcn(A3, 512, XA, 512, Wu[0], 256, bu[0], 1, XB, dinvL[3], fixvL[3]);

  catinit_k<<<dim3((1024 * 256 + WG - 1) / WG), dim3(WG), 0, stream>>>(XS2, 1024, 128, XA);
  catscat_k<<<dim3((512 * 128 + WG - 1) / WG), dim3(WG), 0, stream>>>(perm3, XB, 512, 128, 256, XA);
  gcn(A2, 1024, XA, 256, Wu[1], 128, bu[1], 1, XB, dinvL[2], fixvL[2]);

  catinit_k<<<dim3((2048 * 128 + WG - 1) / WG), dim3(WG), 0, stream>>>(XS1, 2048, 64, XA);
  catscat_k<<<dim3((1024 * 64 + WG - 1) / WG), dim3(WG), 0, stream>>>(perm2, XB, 1024, 64, 128, XA);
  gcn(A1, 2048, XA, 128, Wu[2], 64, bu[2], 1, XB, dinvL[1], fixvL[1]);

  catinit_k<<<dim3((4096 * 64 + WG - 1) / WG), dim3(WG), 0, stream>>>(XS0, 4096, 32, XA);
  catscat_k<<<dim3((2048 * 32 + WG - 1) / WG), dim3(WG), 0, stream>>>(perm1, XB, 2048, 32, 64, XA);
  gcn(A0, 4096, XA, 64, Wu[3], 32, bu[3], 0, XB, dinvL[0], fixvL[0]);

  // ---- final GCN + softmax ----
  sgemm(XB, Wo, YT, 4096, 37, 32, dinvL[0], nullptr, 0, 1, 4096);
  {
    dim3 g(4096 / 16, 1);
    prop_k<64><<<g, dim3(256), 0, stream>>>(A0, YT, XA, 4096, 37, 4096,
                                            dinvL[0], fixvL[0], bo, 0);
  }
  softmax_k<<<dim3((4096 + WG - 1) / WG), dim3(WG), 0, stream>>>(XA, out, 4096, 37);
}

// Round 3
// 1366.961 us; speedup vs baseline: 1.8130x; 1.6648x over previous
//
#include <hip/hip_runtime.h>
#include <math.h>
#include <stddef.h>

#define WG 256

typedef short short8_t __attribute__((ext_vector_type(8)));
typedef float f32x4_t __attribute__((ext_vector_type(4)));

// ---------------------------------------------------------------------------
// Edge stats: in-degree (all edges incl self) + self-edge count.
__global__ void edgestats_k(const int* __restrict__ esrc, const int* __restrict__ edst,
                            int* __restrict__ cnt, int* __restrict__ selfc, int E) {
  int e = blockIdx.x * blockDim.x + threadIdx.x;
  if (e >= E) return;
  int s = esrc[e], d = edst[e];
  atomicAdd(&cnt[d], 1);
  if (s == d) atomicAdd(&selfc[d], 1);
}

__global__ void finalize0_k(const int* __restrict__ cnt, const int* __restrict__ selfc,
                            float* __restrict__ dinv, float* __restrict__ fixv, int n) {
  int i = blockIdx.x * blockDim.x + threadIdx.x;
  if (i >= n) return;
  float fx = (selfc[i] == 0) ? 2.0f : 0.0f;
  float deg = (float)cnt[i] + fx;
  dinv[i] = (deg > 0.f) ? 1.0f / sqrtf(deg) : 0.f;
  fixv[i] = fx;
}

__global__ void __launch_bounds__(1024) exscan_k(const int* __restrict__ cnt, int* __restrict__ off) {
  __shared__ int part[1024];
  int t = threadIdx.x;
  int l0 = cnt[t * 4], l1 = cnt[t * 4 + 1], l2 = cnt[t * 4 + 2], l3 = cnt[t * 4 + 3];
  int s = l0 + l1 + l2 + l3;
  part[t] = s;
  __syncthreads();
  for (int d = 1; d < 1024; d <<= 1) {
    int v = part[t];
    int u = (t >= d) ? part[t - d] : 0;
    __syncthreads();
    part[t] = v + u;
    __syncthreads();
  }
  int ex = (t > 0) ? part[t - 1] : 0;
  off[t * 4] = ex;
  off[t * 4 + 1] = ex + l0;
  off[t * 4 + 2] = ex + l0 + l1;
  off[t * 4 + 3] = ex + l0 + l1 + l2;
  if (t == 1023) off[4096] = part[1023];
}

__global__ void scatterd_k(const int* __restrict__ esrc, const int* __restrict__ edst,
                           const int* __restrict__ off, int* __restrict__ fill,
                           int* __restrict__ bys, int E) {
  int e = blockIdx.x * blockDim.x + threadIdx.x;
  if (e >= E) return;
  int d = edst[e];
  int p = off[d] + atomicAdd(&fill[d], 1);
  bys[p] = esrc[e];
}

// Sort each CSR row by value -> deterministic summation order in SpMV.
__global__ void __launch_bounds__(256) sortcsr_k(const int* __restrict__ off, int* __restrict__ bys) {
  __shared__ int buf[4][192];
  int w = threadIdx.x >> 6, l = threadIdx.x & 63;
  int row = blockIdx.x * 4 + w;
  int b0 = off[row];
  int len = off[row + 1] - b0;
  int ok = (len <= 192);
  if (ok) for (int i = l; i < len; i += 64) buf[w][i] = bys[b0 + i];
  __syncthreads();
  if (ok && l == 0) {
    for (int i = 1; i < len; i++) {
      int v = buf[w][i]; int j = i - 1;
      while (j >= 0 && buf[w][j] > v) { buf[w][j + 1] = buf[w][j]; j--; }
      buf[w][j + 1] = v;
    }
  }
  __syncthreads();
  if (ok) for (int i = l; i < len; i += 64) bys[b0 + i] = buf[w][i];
}

// SpMV: Z[d][c] = dinv[d]*(sum_{e:dst=d} y[src_e][c] + fixv[d]*y[d][c]) + bias[c]
template<int SMALL>
__global__ void __launch_bounds__(256) spmv_k(const int* __restrict__ off, const int* __restrict__ bys,
                                              const float* __restrict__ y, int N,
                                              const float* __restrict__ dinv, const float* __restrict__ fixv,
                                              const float* __restrict__ bias, int relu,
                                              float* __restrict__ Z) {
  int w = threadIdx.x >> 6, l = threadIdx.x & 63;
  int row = blockIdx.x * 4 + w;
  int b0 = off[row], b1 = off[row + 1];
  if (SMALL) {  // N == 32
    int c = l & 31, eh = l >> 5;
    float acc = 0.f;
    for (int e = b0 + eh; e < b1; e += 2) { int s = bys[e]; acc += y[(size_t)s * N + c]; }
    acc += __shfl_xor(acc, 32, 64);
    if (eh == 0) {
      float v = acc + fixv[row] * y[(size_t)row * N + c];
      v = v * dinv[row] + (bias ? bias[c] : 0.f);
      if (relu) v = fmaxf(v, 0.f);
      Z[(size_t)row * N + c] = v;
    }
  } else {
    bool act = l < N;
    float acc = 0.f;
    for (int e = b0; e < b1; e++) { int s = bys[e]; if (act) acc += y[(size_t)s * N + l]; }
    if (act) {
      float v = acc + fixv[row] * y[(size_t)row * N + l];
      v = v * dinv[row] + (bias ? bias[l] : 0.f);
      if (relu) v = fmaxf(v, 0.f);
      Z[(size_t)row * N + l] = v;
    }
  }
}

// ---------------------------------------------------------------------------
// Row sums over dense A -> dinv = 1/sqrt(deg), fixv (diag is zero for augmented A).
__global__ void rowsum_k(const float* __restrict__ A, int n,
                         float* __restrict__ dinv, float* __restrict__ fixv) {
  __shared__ float red[WG];
  int row = blockIdx.x;
  const float* Ar = A + (size_t)row * n;
  float s = 0.f;
  for (int j = threadIdx.x; j < n; j += WG) s += Ar[j];
  red[threadIdx.x] = s;
  __syncthreads();
  for (int d = WG / 2; d > 0; d >>= 1) {
    if ((int)threadIdx.x < d) red[threadIdx.x] += red[threadIdx.x + d];
    __syncthreads();
  }
  if (threadIdx.x == 0) {
    float fx = (Ar[row] == 0.0f) ? 2.0f : 0.0f;
    float deg = red[0] + fx;
    dinv[row] = (deg > 0.f) ? 1.0f / sqrtf(deg) : 0.f;
    fixv[row] = fx;
  }
}

// ---------------------------------------------------------------------------
// fp32 SGEMM (small xW mats + aug3/4): C = L(MxK)@R(KxN), row scale/bias/relu,
// optional transposed store.
template<int TNv>
__global__ void __launch_bounds__(256) sgemm_k(
    const float* __restrict__ L, const float* __restrict__ R, float* __restrict__ C,
    int M, int N, int K,
    const float* __restrict__ dinv, const float* __restrict__ bias, int relu,
    int transC, int ldc) {
  const int MN = TNv / 16;
  __shared__ float Ls[16][68];
  __shared__ float Rs[16][TNv];
  int tid = threadIdx.x;
  int tx = tid & 15, ty = tid >> 4;
  int m0 = blockIdx.y * 64;
  int n0 = blockIdx.x * TNv;
  float acc[4][MN];
#pragma unroll
  for (int i = 0; i < 4; i++)
#pragma unroll
    for (int j = 0; j < MN; j++) acc[i][j] = 0.f;

  int lk = tid & 15, lm = tid >> 4;
  int rn = tid % TNv, rk = tid / TNv;
  const int KS = 256 / TNv;

  for (int kt = 0; kt < K; kt += 16) {
#pragma unroll
    for (int r = 0; r < 4; r++) {
      int m = lm + r * 16;
      Ls[lk][m] = L[(size_t)(m0 + m) * K + kt + lk];
    }
#pragma unroll
    for (int r = 0; r < 16 / KS; r++) {
      int k = rk + r * KS;
      int gn = n0 + rn;
      Rs[k][rn] = (gn < N) ? R[(size_t)(kt + k) * N + gn] : 0.f;
    }
    __syncthreads();
#pragma unroll
    for (int k = 0; k < 16; k++) {
      float a[4], b[MN];
#pragma unroll
      for (int i = 0; i < 4; i++) a[i] = Ls[k][ty * 4 + i];
#pragma unroll
      for (int j = 0; j < MN; j++) b[j] = Rs[k][tx * MN + j];
#pragma unroll
      for (int i = 0; i < 4; i++)
#pragma unroll
        for (int j = 0; j < MN; j++) acc[i][j] += a[i] * b[j];
    }
    __syncthreads();
  }
#pragma unroll
  for (int i = 0; i < 4; i++) {
    int gi = m0 + ty * 4 + i;
#pragma unroll
    for (int j = 0; j < MN; j++) {
      int gj = n0 + tx * MN + j;
      if (gj < N) {
        float v = acc[i][j];
        if (dinv) v *= dinv[gi];
        if (bias) v += bias[gj];
        if (relu) v = fmaxf(v, 0.f);
        if (transC) C[(size_t)gj * ldc + gi] = v;
        else C[(size_t)gi * N + gj] = v;
      }
    }
  }
}

// ---------------------------------------------------------------------------
// bf16 MFMA NT GEMM: C(MxN fp32) = A(MxK) @ B(NxK)^T ; A,B fp32 holding exact
// small integers (<=256) -> bf16 truncation is exact. 128x128 tile, Kstep 32.
__global__ void __launch_bounds__(256) mfma_nt_k(const float* __restrict__ A, const float* __restrict__ B,
                                                 float* __restrict__ C, int M, int N, int K) {
  __shared__ short As[128 * 32];
  __shared__ short Bs[128 * 32];
  int tid = threadIdx.x;
  int w = tid >> 6, l = tid & 63;
  int wy = w >> 1, wx = w & 1;
  int q = l >> 4, r = l & 15;
  int m0 = blockIdx.y * 128, n0 = blockIdx.x * 128;
  f32x4_t acc[4][4];
#pragma unroll
  for (int i = 0; i < 4; i++)
#pragma unroll
    for (int j = 0; j < 4; j++) acc[i][j] = (f32x4_t){0.f, 0.f, 0.f, 0.f};

  int srow = tid & 127, scp = tid >> 7;  // 128 rows x 2 chunk-pairs
  const float* Ag = A + (size_t)(m0 + srow) * K + scp * 16;
  const float* Bg = B + (size_t)(n0 + srow) * K + scp * 16;
  int g = srow >> 4, rr = srow & 15;
  int d0 = ((g * 4 + scp * 2) * 16 + rr) * 8;
  int d1 = ((g * 4 + scp * 2 + 1) * 16 + rr) * 8;

  for (int kt = 0; kt < K; kt += 32) {
    float4 a0 = *(const float4*)(Ag + kt), a1 = *(const float4*)(Ag + kt + 4);
    float4 a2 = *(const float4*)(Ag + kt + 8), a3 = *(const float4*)(Ag + kt + 12);
    float4 b0 = *(const float4*)(Bg + kt), b1 = *(const float4*)(Bg + kt + 4);
    float4 b2 = *(const float4*)(Bg + kt + 8), b3 = *(const float4*)(Bg + kt + 12);
    __syncthreads();
    short8_t sa, sb;
    sa[0] = (short)(__float_as_uint(a0.x) >> 16); sa[1] = (short)(__float_as_uint(a0.y) >> 16);
    sa[2] = (short)(__float_as_uint(a0.z) >> 16); sa[3] = (short)(__float_as_uint(a0.w) >> 16);
    sa[4] = (short)(__float_as_uint(a1.x) >> 16); sa[5] = (short)(__float_as_uint(a1.y) >> 16);
    sa[6] = (short)(__float_as_uint(a1.z) >> 16); sa[7] = (short)(__float_as_uint(a1.w) >> 16);
    *(short8_t*)&As[d0] = sa;
    sa[0] = (short)(__float_as_uint(a2.x) >> 16); sa[1] = (short)(__float_as_uint(a2.y) >> 16);
    sa[2] = (short)(__float_as_uint(a2.z) >> 16); sa[3] = (short)(__float_as_uint(a2.w) >> 16);
    sa[4] = (short)(__float_as_uint(a3.x) >> 16); sa[5] = (short)(__float_as_uint(a3.y) >> 16);
    sa[6] = (short)(__float_as_uint(a3.z) >> 16); sa[7] = (short)(__float_as_uint(a3.w) >> 16);
    *(short8_t*)&As[d1] = sa;
    sb[0] = (short)(__float_as_uint(b0.x) >> 16); sb[1] = (short)(__float_as_uint(b0.y) >> 16);
    sb[2] = (short)(__float_as_uint(b0.z) >> 16); sb[3] = (short)(__float_as_uint(b0.w) >> 16);
    sb[4] = (short)(__float_as_uint(b1.x) >> 16); sb[5] = (short)(__float_as_uint(b1.y) >> 16);
    sb[6] = (short)(__float_as_uint(b1.z) >> 16); sb[7] = (short)(__float_as_uint(b1.w) >> 16);
    *(short8_t*)&Bs[d0] = sb;
    sb[0] = (short)(__float_as_uint(b2.x) >> 16); sb[1] = (short)(__float_as_uint(b2.y) >> 16);
    sb[2] = (short)(__float_as_uint(b2.z) >> 16); sb[3] = (short)(__float_as_uint(b2.w) >> 16);
    sb[4] = (short)(__float_as_uint(b3.x) >> 16); sb[5] = (short)(__float_as_uint(b3.y) >> 16);
    sb[6] = (short)(__float_as_uint(b3.z) >> 16); sb[7] = (short)(__float_as_uint(b3.w) >> 16);
    *(short8_t*)&Bs[d1] = sb;
    __syncthreads();
    short8_t af[4], bf[4];
#pragma unroll
    for (int sm = 0; sm < 4; sm++) af[sm] = *(short8_t*)&As[(((wy * 4 + sm) * 4 + q) * 16 + r) * 8];
#pragma unroll
    for (int sn = 0; sn < 4; sn++) bf[sn] = *(short8_t*)&Bs[(((wx * 4 + sn) * 4 + q) * 16 + r) * 8];
#pragma unroll
    for (int sm = 0; sm < 4; sm++)
#pragma unroll
      for (int sn = 0; sn < 4; sn++)
        acc[sm][sn] = __builtin_amdgcn_mfma_f32_16x16x32_bf16(af[sm], bf[sn], acc[sm][sn], 0, 0, 0);
  }
#pragma unroll
  for (int sm = 0; sm < 4; sm++) {
#pragma unroll
    for (int sn = 0; sn < 4; sn++) {
      int grow = m0 + wy * 64 + sm * 16 + q * 4;
      int gcol = n0 + wx * 64 + sn * 16 + r;
#pragma unroll
      for (int v = 0; v < 4; v++) C[(size_t)(grow + v) * N + gcol] = acc[sm][sn][v];
    }
  }
}

// ---------------------------------------------------------------------------
// Build pooled B1 operands from edges: BL[a][s]=mult(perm[a]<-s), BR[b][d]=mult(d<-perm[b]); diag=1.
__global__ void blbuild_k(const int* __restrict__ esrc, const int* __restrict__ edst,
                          const int* __restrict__ rank1, float* __restrict__ BL,
                          float* __restrict__ BR, int E) {
  int e = blockIdx.x * blockDim.x + threadIdx.x;
  if (e >= E) return;
  int s = esrc[e], d = edst[e];
  if (s == d) return;
  int a = rank1[d];
  if (a >= 0) atomicAdd(&BL[(size_t)a * 4096 + s], 1.0f);
  int b = rank1[s];
  if (b >= 0) atomicAdd(&BR[(size_t)b * 4096 + d], 1.0f);
}

__global__ void bldiag_k(const int* __restrict__ perm, float* __restrict__ BL,
                         float* __restrict__ BR, int m) {
  int a = blockIdx.x * blockDim.x + threadIdx.x;
  if (a >= m) return;
  BL[(size_t)a * 4096 + perm[a]] = 1.0f;
  BR[(size_t)a * 4096 + perm[a]] = 1.0f;
}

// Tiled transpose D = S^T (n x n fp32)
__global__ void transpose_k(const float* __restrict__ S, float* __restrict__ D, int n) {
  __shared__ float tile[32][33];
  int bx = blockIdx.x * 32, by = blockIdx.y * 32;
  int tx = threadIdx.x, ty = threadIdx.y;
  for (int j = 0; j < 32; j += 8) tile[ty + j][tx] = S[(size_t)(by + ty + j) * n + bx + tx];
  __syncthreads();
  for (int j = 0; j < 32; j += 8) D[(size_t)(bx + ty + j) * n + by + tx] = tile[tx][ty + j];
}

// Row gather + I: out[a][k] = S[perm[a]][k] + (perm[a]==k)
__global__ void gatherL_k(const float* __restrict__ S, const int* __restrict__ perm,
                          int n, int m, float* __restrict__ out) {
  int t = blockIdx.x * blockDim.x + threadIdx.x;
  if (t >= m * n) return;
  int a = t / n, k = t - a * n;
  int pa = perm[a];
  out[t] = S[(size_t)pa * n + k] + ((pa == k) ? 1.0f : 0.0f);
}

// Col gather + I (for fp32 sgemm path): out[k][b] = S[k][perm[b]] + (k==perm[b])
__global__ void gatherR_k(const float* __restrict__ S, const int* __restrict__ perm,
                          int n, int m, float* __restrict__ out) {
  int t = blockIdx.x * blockDim.x + threadIdx.x;
  if (t >= n * m) return;
  int k = t / m, b = t - k * m;
  int pb = perm[b];
  out[t] = S[(size_t)k * n + pb] + ((k == pb) ? 1.0f : 0.0f);
}

__global__ void zerodiag_k(float* __restrict__ A, int m) {
  int a = blockIdx.x * blockDim.x + threadIdx.x;
  if (a < m) A[(size_t)a * m + a] = 0.f;
}

// ---------------------------------------------------------------------------
// Dense propagation, split-K stage: P[z][m][c] = sum_{k in chunk z} A[m][k]*YT[c][k]
__global__ void __launch_bounds__(256) prop_stage_k(const float* __restrict__ A, const float* __restrict__ YT,
                                                    float* __restrict__ P, int M, int N, int K, int Kc) {
  __shared__ float red[4][4][64];
  int tid = threadIdx.x, wid = tid >> 6, lane = tid & 63;
  int kl = lane & 15, cg = lane >> 4;
  int m0 = (blockIdx.x * 4 + wid) * 4;
  int ncb = blockIdx.y * 64;
  int z = blockIdx.z;
  int kbeg = z * Kc, kend = kbeg + Kc;
  float acc[4][16];
#pragma unroll
  for (int r0 = 0; r0 < 4; r0++)
#pragma unroll
    for (int c = 0; c < 16; c++) acc[r0][c] = 0.f;

  for (int k0 = kbeg; k0 < kend; k0 += 64) {
    float4 a4[4];
#pragma unroll
    for (int r0 = 0; r0 < 4; r0++)
      a4[r0] = *(const float4*)(A + (size_t)(m0 + r0) * K + k0 + kl * 4);
#pragma unroll
    for (int c = 0; c < 16; c++) {
      int cc = ncb + cg * 16 + c;
      float4 y4 = *(const float4*)(YT + (size_t)cc * K + k0 + kl * 4);
#pragma unroll
      for (int r0 = 0; r0 < 4; r0++) {
        acc[r0][c] += a4[r0].x * y4.x;
        acc[r0][c] += a4[r0].y * y4.y;
        acc[r0][c] += a4[r0].z * y4.z;
        acc[r0][c] += a4[r0].w * y4.w;
      }
    }
  }
#pragma unroll
  for (int m = 1; m <= 8; m <<= 1)
#pragma unroll
    for (int r0 = 0; r0 < 4; r0++)
#pragma unroll
      for (int c = 0; c < 16; c++)
        acc[r0][c] += __shfl_xor(acc[r0][c], m, 64);
  if (kl == 0) {
#pragma unroll
    for (int r0 = 0; r0 < 4; r0++)
#pragma unroll
      for (int c = 0; c < 16; c++) red[wid][r0][cg * 16 + c] = acc[r0][c];
  }
  __syncthreads();
  int cc = ncb + lane;
#pragma unroll
  for (int r0 = 0; r0 < 4; r0++)
    P[((size_t)z * M + (m0 + r0)) * N + cc] = red[wid][r0][lane];
}

// Reduce split-K partials + GCN epilogue.
__global__ void propred_k(const float* __restrict__ P, const float* __restrict__ YT,
                          float* __restrict__ C, int M, int N, int K, int KS,
                          const float* __restrict__ dinv, const float* __restrict__ fixv,
                          const float* __restrict__ bias, int relu) {
  int t = blockIdx.x * blockDim.x + threadIdx.x;
  if (t >= M * N) return;
  int row = t / N, c = t - row * N;
  float s = 0.f;
  for (int z = 0; z < KS; z++) s += P[((size_t)z * M + row) * N + c];
  s += fixv[row] * YT[(size_t)c * K + row];
  s = s * dinv[row] + bias[c];
  if (relu) s = fmaxf(s, 0.f);
  C[t] = s;
}

// ---------------------------------------------------------------------------
// TopK pooling
__global__ void normw_k(const float* __restrict__ w, int c, float* __restrict__ nw) {
  __shared__ float red[WG];
  float v = 0.f;
  if ((int)threadIdx.x < c) { float t = w[threadIdx.x]; v = t * t; }
  red[threadIdx.x] = v;
  __syncthreads();
  for (int d = WG / 2; d > 0; d >>= 1) {
    if ((int)threadIdx.x < d) red[threadIdx.x] += red[threadIdx.x + d];
    __syncthreads();
  }
  if (threadIdx.x == 0) nw[0] = sqrtf(red[0]);
}

__global__ void score_k(const float* __restrict__ x, const float* __restrict__ w,
                        int n, int c, const float* __restrict__ nw, float* __restrict__ s) {
  int i = blockIdx.x * blockDim.x + threadIdx.x;
  if (i >= n) return;
  const float* xr = x + (size_t)i * c;
  float d = 0.f;
  for (int k = 0; k < c; k++) d += xr[k] * w[k];
  s[i] = tanhf(d / nw[0]);
}

__global__ void __launch_bounds__(1024) sortpool_k(
    const float* __restrict__ scores, int n, int keep,
    int* __restrict__ perm, float* __restrict__ vals, int* __restrict__ rank) {
  __shared__ float ss[4096];
  __shared__ int si[4096];
  int tid = threadIdx.x;
  for (int i = tid; i < n; i += 1024) { ss[i] = scores[i]; si[i] = i; rank[i] = -1; }
  __syncthreads();
  for (int k = 2; k <= n; k <<= 1) {
    for (int j = k >> 1; j > 0; j >>= 1) {
      for (int i = tid; i < n; i += 1024) {
        int ixj = i ^ j;
        if (ixj > i) {
          float s1 = ss[i], s2 = ss[ixj];
          int a1 = si[i], a2 = si[ixj];
          bool before2 = (s2 > s1) || (s2 == s1 && a2 < a1);
          bool up = ((i & k) == 0);
          if (up == before2) { ss[i] = s2; ss[ixj] = s1; si[i] = a2; si[ixj] = a1; }
        }
      }
      __syncthreads();
    }
  }
  for (int a = tid; a < keep; a += 1024) {
    perm[a] = si[a];
    vals[a] = ss[a];
    rank[si[a]] = a;
  }
}

__global__ void poolx_k(const float* __restrict__ x, const int* __restrict__ perm,
                        const float* __restrict__ vals, int keep, int c, float* __restrict__ out) {
  int t = blockIdx.x * blockDim.x + threadIdx.x;
  if (t >= keep * c) return;
  int a = t / c, j = t - a * c;
  out[t] = x[(size_t)perm[a] * c + j] * vals[a];
}

// ---------------------------------------------------------------------------
__global__ void catinit_k(const float* __restrict__ res, int n, int c, float* __restrict__ cat) {
  int t = blockIdx.x * blockDim.x + threadIdx.x;
  int tot = n * 2 * c;
  if (t >= tot) return;
  int i = t / (2 * c), j = t - i * 2 * c;
  cat[t] = (j < c) ? res[(size_t)i * c + j] : 0.f;
}

__global__ void catscat_k(const int* __restrict__ perm, const float* __restrict__ cur,
                          int keep, int c, int cw, float* __restrict__ cat) {
  int t = blockIdx.x * blockDim.x + threadIdx.x;
  if (t >= keep * c) return;
  int a = t / c, j = t - a * c;
  cat[(size_t)perm[a] * (2 * c) + c + j] = cur[(size_t)a * cw + j];
}

__global__ void softmax_k(const float* __restrict__ z, float* __restrict__ out, int n, int c) {
  int i = blockIdx.x * blockDim.x + threadIdx.x;
  if (i >= n) return;
  const float* zr = z + (size_t)i * c;
  float m = zr[0];
  for (int j = 1; j < c; j++) m = fmaxf(m, zr[j]);
  float e[64];
  float s = 0.f;
  for (int j = 0; j < c; j++) { e[j] = expf(zr[j] - m); s += e[j]; }
  for (int j = 0; j < c; j++) out[(size_t)i * c + j] = e[j] / s;
}

// ---------------------------------------------------------------------------
extern "C" void kernel_launch(void* const* d_in, const int* in_sizes, int n_in,
                              void* d_out, int out_size, void* d_ws, size_t ws_size,
                              hipStream_t stream) {
  (void)n_in; (void)out_size; (void)ws_size;
  const float* xin = (const float*)d_in[0];
  const int* ei = (const int*)d_in[1];
  const int E = in_sizes[1] / 2;
  const int* esrc = ei;
  const int* edst = ei + E;
  const float* Wd[5] = {(const float*)d_in[2], (const float*)d_in[4], (const float*)d_in[6],
                        (const float*)d_in[8], (const float*)d_in[10]};
  const float* bd[5] = {(const float*)d_in[3], (const float*)d_in[5], (const float*)d_in[7],
                        (const float*)d_in[9], (const float*)d_in[11]};
  const float* pw[4] = {(const float*)d_in[12], (const float*)d_in[13],
                        (const float*)d_in[14], (const float*)d_in[15]};
  const float* Wu[4] = {(const float*)d_in[16], (const float*)d_in[18],
                        (const float*)d_in[20], (const float*)d_in[22]};
  const float* bu[4] = {(const float*)d_in[17], (const float*)d_in[19],
                        (const float*)d_in[21], (const float*)d_in[23]};
  const float* Wo = (const float*)d_in[24];
  const float* bo = (const float*)d_in[25];
  float* out = (float*)d_out;

  char* p = (char*)d_ws;
  auto bumpf = [&](size_t ne) -> float* { float* r = (float*)p; p += ((ne * 4 + 255) & ~(size_t)255); return r; };
  auto bumpi = [&](size_t ne) -> int* { int* r = (int*)p; p += ((ne * 4 + 255) & ~(size_t)255); return r; };

  float* A1 = bumpf((size_t)2048 * 2048);
  float* A2 = bumpf((size_t)1024 * 1024);
  float* A3 = bumpf((size_t)512 * 512);
  float* A4 = bumpf((size_t)256 * 256);
  float* BL1 = bumpf((size_t)2048 * 4096);  // union: Pbuf | A1T | BLf34 | BRf34
  float* BR1 = bumpf((size_t)2048 * 4096);  // union: BLf2 | BRf2
  float* y = bumpf((size_t)4096 * 64);
  float* YT = bumpf((size_t)4096 * 64);
  float* XS0 = bumpf((size_t)4096 * 32);
  float* XS1 = bumpf((size_t)2048 * 64);
  float* XS2 = bumpf((size_t)1024 * 128);
  float* XS3 = bumpf((size_t)512 * 256);
  float* XA = bumpf((size_t)4096 * 64);
  float* XB = bumpf((size_t)4096 * 32);
  float* scores = bumpf(4096);
  float* vals = bumpf(2048);
  float* nw = bumpf(64);
  float* dinvL[5];
  float* fixvL[5];
  int nsz[5] = {4096, 2048, 1024, 512, 256};
  for (int i = 0; i < 5; i++) { dinvL[i] = bumpf(nsz[i]); fixvL[i] = bumpf(nsz[i]); }
  int* perm1 = bumpi(2048);
  int* perm2 = bumpi(1024);
  int* perm3 = bumpi(512);
  int* perm4 = bumpi(256);
  int* rank = bumpi(4096);
  int* cnt = bumpi(4096);
  int* offb = bumpi(4100);
  int* fill = bumpi(4096);
  int* selfc = bumpi(4096);
  int* bys = bumpi((size_t)E);

  // Unions inside BL1/BR1 (both dead after aug1 MFMA)
  float* Pbuf = BL1;                               // 1M floats
  float* A1T = BL1 + (size_t)1 * 1024 * 1024;      // 4M floats
  float* BLf34 = BL1 + (size_t)5 * 1024 * 1024;    // 0.5M
  float* BRf34 = BL1 + (size_t)5 * 1024 * 1024 + 512 * 1024;
  float* BLf2 = BR1;                               // 2M
  float* BRf2 = BR1 + (size_t)2 * 1024 * 1024;     // 2M

  auto sgemm = [&](const float* L, const float* R, float* C, int M, int N, int K,
                   const float* di, const float* bi, int relu, int transC, int ldc) {
    if (N <= 32) {
      dim3 g((N + 31) / 32, M / 64);
      sgemm_k<32><<<g, dim3(256), 0, stream>>>(L, R, C, M, N, K, di, bi, relu, transC, ldc);
    } else {
      dim3 g((N + 63) / 64, M / 64);
      sgemm_k<64><<<g, dim3(256), 0, stream>>>(L, R, C, M, N, K, di, bi, relu, transC, ldc);
    }
  };
  auto gcn_dense = [&](const float* A, int n, const float* x, int cin, const float* W, int cout,
                       const float* bi, int relu, float* zout, const float* di, const float* fx,
                       int Kc, int KS) {
    sgemm(x, W, YT, n, cout, cin, di, nullptr, 0, 1, n);  // YT[cout][n] = (di .* xW)^T
    dim3 g(n / 16, cout / 64, KS);
    prop_stage_k<<<g, dim3(256), 0, stream>>>(A, YT, Pbuf, n, cout, n, Kc);
    propred_k<<<dim3((n * cout + WG - 1) / WG), dim3(WG), 0, stream>>>(
        Pbuf, YT, zout, n, cout, n, KS, di, fx, bi, relu);
  };
  auto pool = [&](const float* x, int n, int c, const float* w, int* perm, float* xout) {
    normw_k<<<dim3(1), dim3(WG), 0, stream>>>(w, c, nw);
    score_k<<<dim3((n + WG - 1) / WG), dim3(WG), 0, stream>>>(x, w, n, c, nw, scores);
    sortpool_k<<<dim3(1), dim3(1024), 0, stream>>>(scores, n, n / 2, perm, vals, rank);
    int keep = n / 2;
    poolx_k<<<dim3((keep * c + WG - 1) / WG), dim3(WG), 0, stream>>>(x, perm, vals, keep, c, xout);
  };

  // ---- CSR(A0) by dst + degree/fix ----
  hipMemsetAsync(cnt, 0, 4096 * 4, stream);
  hipMemsetAsync(fill, 0, 4096 * 4, stream);
  hipMemsetAsync(selfc, 0, 4096 * 4, stream);
  edgestats_k<<<dim3((E + WG - 1) / WG), dim3(WG), 0, stream>>>(esrc, edst, cnt, selfc, E);
  exscan_k<<<dim3(1), dim3(1024), 0, stream>>>(cnt, offb);
  scatterd_k<<<dim3((E + WG - 1) / WG), dim3(WG), 0, stream>>>(esrc, edst, offb, fill, bys, E);
  sortcsr_k<<<dim3(1024), dim3(256), 0, stream>>>(offb, bys);
  finalize0_k<<<dim3(16), dim3(WG), 0, stream>>>(cnt, selfc, dinvL[0], fixvL[0], 4096);

  // ---- GCN0 (sparse A0) ----
  sgemm(xin, Wd[0], y, 4096, 32, 128, dinvL[0], nullptr, 0, 0, 0);
  spmv_k<1><<<dim3(1024), dim3(256), 0, stream>>>(offb, bys, y, 32, dinvL[0], fixvL[0], bd[0], 1, XS0);

  // ---- pool1 + aug1 (pooled B1 @ B1 via MFMA, bit-exact in bf16) ----
  pool(XS0, 4096, 32, pw[0], perm1, XA);
  hipMemsetAsync(BL1, 0, (size_t)2048 * 4096 * 4, stream);
  hipMemsetAsync(BR1, 0, (size_t)2048 * 4096 * 4, stream);
  blbuild_k<<<dim3((E + WG - 1) / WG), dim3(WG), 0, stream>>>(esrc, edst, rank, BL1, BR1, E);
  bldiag_k<<<dim3(8), dim3(WG), 0, stream>>>(perm1, BL1, BR1, 2048);
  mfma_nt_k<<<dim3(16, 16), dim3(256), 0, stream>>>(BL1, BR1, A1, 2048, 2048, 4096);
  zerodiag_k<<<dim3(8), dim3(WG), 0, stream>>>(A1, 2048);
  rowsum_k<<<dim3(2048), dim3(WG), 0, stream>>>(A1, 2048, dinvL[1], fixvL[1]);
  gcn_dense(A1, 2048, XA, 32, Wd[1], 64, bd[1], 1, XS1, dinvL[1], fixvL[1], 256, 8);

  // ---- level 2 ----
  pool(XS1, 2048, 64, pw[1], perm2, XA);
  transpose_k<<<dim3(64, 64), dim3(32, 8), 0, stream>>>(A1, A1T, 2048);
  gatherL_k<<<dim3((1024 * 2048 + WG - 1) / WG), dim3(WG), 0, stream>>>(A1, perm2, 2048, 1024, BLf2);
  gatherL_k<<<dim3((1024 * 2048 + WG - 1) / WG), dim3(WG), 0, stream>>>(A1T, perm2, 2048, 1024, BRf2);
  mfma_nt_k<<<dim3(8, 8), dim3(256), 0, stream>>>(BLf2, BRf2, A2, 1024, 1024, 2048);
  zerodiag_k<<<dim3(4), dim3(WG), 0, stream>>>(A2, 1024);
  rowsum_k<<<dim3(1024), dim3(WG), 0, stream>>>(A2, 1024, dinvL[2], fixvL[2]);
  gcn_dense(A2, 1024, XA, 64, Wd[2], 128, bd[2], 1, XS2, dinvL[2], fixvL[2], 128, 8);

  // ---- level 3 (fp32 sgemm augment: values exceed bf16-exact range) ----
  pool(XS2, 1024, 128, pw[2], perm3, XA);
  gatherL_k<<<dim3((512 * 1024 + WG - 1) / WG), dim3(WG), 0, stream>>>(A2, perm3, 1024, 512, BLf34);
  gatherR_k<<<dim3((1024 * 512 + WG - 1) / WG), dim3(WG), 0, stream>>>(A2, perm3, 1024, 512, BRf34);
  sgemm(BLf34, BRf34, A3, 512, 512, 1024, nullptr, nullptr, 0, 0, 0);
  zerodiag_k<<<dim3(2), dim3(WG), 0, stream>>>(A3, 512);
  rowsum_k<<<dim3(512), dim3(WG), 0, stream>>>(A3, 512, dinvL[3], fixvL[3]);
  gcn_dense(A3, 512, XA, 128, Wd[3], 256, bd[3], 1, XS3, dinvL[3], fixvL[3], 64, 8);

  // ---- level 4 ----
  pool(XS3, 512, 256, pw[3], perm4, XA);
  gatherL_k<<<dim3((256 * 512 + WG - 1) / WG), dim3(WG), 0, stream>>>(A3, perm4, 512, 256, BLf34);
  gatherR_k<<<dim3((512 * 256 + WG - 1) / WG), dim3(WG), 0, stream>>>(A3, perm4, 512, 256, BRf34);
  sgemm(BLf34, BRf34, A4, 256, 256, 512, nullptr, nullptr, 0, 0, 0);
  zerodiag_k<<<dim3(1), dim3(WG), 0, stream>>>(A4, 256);
  rowsum_k<<<dim3(256), dim3(WG), 0, stream>>>(A4, 256, dinvL[4], fixvL[4]);
  gcn_dense(A4, 256, XA, 256, Wd[4], 512, bd[4], 1, XB, dinvL[4], fixvL[4], 64, 4);

  // ---- up path ----
  catinit_k<<<dim3((512 * 512 + WG - 1) / WG), dim3(WG), 0, stream>>>(XS3, 512, 256, XA);
  catscat_k<<<dim3((256 * 256 + WG - 1) / WG), dim3(WG), 0, stream>>>(perm4, XB, 256, 256, 512, XA);
  gcn_dense(A3, 512, XA, 512, Wu[0], 256, bu[0], 1, XB, dinvL[3], fixvL[3], 64, 8);

  catinit_k<<<dim3((1024 * 256 + WG - 1) / WG), dim3(WG), 0, stream>>>(XS2, 1024, 128, XA);
  catscat_k<<<dim3((512 * 128 + WG - 1) / WG), dim3(WG), 0, stream>>>(perm3, XB, 512, 128, 256, XA);
  gcn_dense(A2, 1024, XA, 256, Wu[1], 128, bu[1], 1, XB, dinvL[2], fixvL[2], 128, 8);

  catinit_k<<<dim3((2048 * 128 + WG - 1) / WG), dim3(WG), 0, stream>>>(XS1, 2048, 64, XA);
  catscat_k<<<dim3((1024 * 64 + WG - 1) / WG), dim3(WG), 0, stream>>>(perm2, XB, 1024, 64, 128, XA);
  gcn_dense(A1, 2048, XA, 128, Wu[2], 64, bu[2], 1, XB, dinvL[1], fixvL[1], 256, 8);

  catinit_k<<<dim3((4096 * 64 + WG - 1) / WG), dim3(WG), 0, stream>>>(XS0, 4096, 32, XA);
  catscat_k<<<dim3((2048 * 32 + WG - 1) / WG), dim3(WG), 0, stream>>>(perm1, XB, 2048, 32, 64, XA);
  sgemm(XA, Wu[3], y, 4096, 32, 64, dinvL[0], nullptr, 0, 0, 0);
  spmv_k<1><<<dim3(1024), dim3(256), 0, stream>>>(offb, bys, y, 32, dinvL[0], fixvL[0], bu[3], 0, XB);

  // ---- final GCN (sparse A0) + softmax ----
  sgemm(XB, Wo, y, 4096, 37, 32, dinvL[0], nullptr, 0, 0, 0);
  spmv_k<0><<<dim3(1024), dim3(256), 0, stream>>>(offb, bys, y, 37, dinvL[0], fixvL[0], bo, 0, XA);
  softmax_k<<<dim3((4096 + WG - 1) / WG), dim3(WG), 0, stream>>>(XA, out, 4096, 37);
}

// Round 4
// 1080.624 us; speedup vs baseline: 2.2934x; 1.2650x over previous
//
#include <hip/hip_runtime.h>
#include <math.h>
#include <stddef.h>

#define WG 256

typedef short short8_t __attribute__((ext_vector_type(8)));
typedef float f32x4_t __attribute__((ext_vector_type(4)));

// ---------------------------------------------------------------------------
// Edge stats: in-degree (all edges incl self) + self-edge count.
__global__ void edgestats_k(const int* __restrict__ esrc, const int* __restrict__ edst,
                            int* __restrict__ cnt, int* __restrict__ selfc, int E) {
  int e = blockIdx.x * blockDim.x + threadIdx.x;
  if (e >= E) return;
  int s = esrc[e], d = edst[e];
  atomicAdd(&cnt[d], 1);
  if (s == d) atomicAdd(&selfc[d], 1);
}

__global__ void finalize0_k(const int* __restrict__ cnt, const int* __restrict__ selfc,
                            float* __restrict__ dinv, float* __restrict__ fixv, int n) {
  int i = blockIdx.x * blockDim.x + threadIdx.x;
  if (i >= n) return;
  float fx = (selfc[i] == 0) ? 2.0f : 0.0f;
  float deg = (float)cnt[i] + fx;
  dinv[i] = (deg > 0.f) ? 1.0f / sqrtf(deg) : 0.f;
  fixv[i] = fx;
}

__global__ void __launch_bounds__(1024) exscan_k(const int* __restrict__ cnt, int* __restrict__ off) {
  __shared__ int part[1024];
  int t = threadIdx.x;
  int l0 = cnt[t * 4], l1 = cnt[t * 4 + 1], l2 = cnt[t * 4 + 2], l3 = cnt[t * 4 + 3];
  int s = l0 + l1 + l2 + l3;
  part[t] = s;
  __syncthreads();
  for (int d = 1; d < 1024; d <<= 1) {
    int v = part[t];
    int u = (t >= d) ? part[t - d] : 0;
    __syncthreads();
    part[t] = v + u;
    __syncthreads();
  }
  int ex = (t > 0) ? part[t - 1] : 0;
  off[t * 4] = ex;
  off[t * 4 + 1] = ex + l0;
  off[t * 4 + 2] = ex + l0 + l1;
  off[t * 4 + 3] = ex + l0 + l1 + l2;
  if (t == 1023) off[4096] = part[1023];
}

// in-CSR (by dst, incl self) for SpMV
__global__ void scatterd_k(const int* __restrict__ esrc, const int* __restrict__ edst,
                           const int* __restrict__ off, int* __restrict__ fill,
                           int* __restrict__ bys, int E) {
  int e = blockIdx.x * blockDim.x + threadIdx.x;
  if (e >= E) return;
  int d = edst[e];
  int p = off[d] + atomicAdd(&fill[d], 1);
  bys[p] = esrc[e];
}

// out-CSR (by src, EXCL self) for the aug1 edge-join
__global__ void outcount_k(const int* __restrict__ esrc, const int* __restrict__ edst,
                           int* __restrict__ cnt, int E) {
  int e = blockIdx.x * blockDim.x + threadIdx.x;
  if (e >= E) return;
  int s = esrc[e], d = edst[e];
  if (s != d) atomicAdd(&cnt[s], 1);
}

__global__ void outscatter_k(const int* __restrict__ esrc, const int* __restrict__ edst,
                             const int* __restrict__ off, int* __restrict__ fill,
                             int* __restrict__ bys, int E) {
  int e = blockIdx.x * blockDim.x + threadIdx.x;
  if (e >= E) return;
  int s = esrc[e], d = edst[e];
  if (s == d) return;
  int p = off[s] + atomicAdd(&fill[s], 1);
  bys[p] = d;
}

// SpMV: Z[d][c] = dinv[d]*(sum_{e:dst=d} y[src_e][c] + fixv[d]*y[d][c]) + bias[c]
template<int SMALL>
__global__ void __launch_bounds__(256) spmv_k(const int* __restrict__ off, const int* __restrict__ bys,
                                              const float* __restrict__ y, int N,
                                              const float* __restrict__ dinv, const float* __restrict__ fixv,
                                              const float* __restrict__ bias, int relu,
                                              float* __restrict__ Z) {
  int w = threadIdx.x >> 6, l = threadIdx.x & 63;
  int row = blockIdx.x * 4 + w;
  int b0 = off[row], b1 = off[row + 1];
  if (SMALL) {  // N == 32
    int c = l & 31, eh = l >> 5;
    float acc = 0.f;
    for (int e = b0 + eh; e < b1; e += 2) { int s = bys[e]; acc += y[(size_t)s * N + c]; }
    acc += __shfl_xor(acc, 32, 64);
    if (eh == 0) {
      float v = acc + fixv[row] * y[(size_t)row * N + c];
      v = v * dinv[row] + (bias ? bias[c] : 0.f);
      if (relu) v = fmaxf(v, 0.f);
      Z[(size_t)row * N + c] = v;
    }
  } else {
    bool act = l < N;
    float acc = 0.f;
    for (int e = b0; e < b1; e++) { int s = bys[e]; if (act) acc += y[(size_t)s * N + l]; }
    if (act) {
      float v = acc + fixv[row] * y[(size_t)row * N + l];
      v = v * dinv[row] + (bias ? bias[l] : 0.f);
      if (relu) v = fmaxf(v, 0.f);
      Z[(size_t)row * N + l] = v;
    }
  }
}

// ---------------------------------------------------------------------------
// Augmented-A normalization: zero diag in place, deg = offdiag rowsum + 2, fix=2.
__global__ void rowsum_k(float* __restrict__ A, int n,
                         float* __restrict__ dinv, float* __restrict__ fixv) {
  __shared__ float red[WG];
  int row = blockIdx.x;
  float* Ar = A + (size_t)row * n;
  float s = 0.f;
  for (int j = threadIdx.x; j < n; j += WG) {
    if (j == row) Ar[j] = 0.f;
    else s += Ar[j];
  }
  red[threadIdx.x] = s;
  __syncthreads();
  for (int d = WG / 2; d > 0; d >>= 1) {
    if ((int)threadIdx.x < d) red[threadIdx.x] += red[threadIdx.x + d];
    __syncthreads();
  }
  if (threadIdx.x == 0) {
    float deg = red[0] + 2.0f;
    dinv[row] = 1.0f / sqrtf(deg);
    fixv[row] = 2.0f;
  }
}

// ---------------------------------------------------------------------------
// fp32 SGEMM (xW mats + aug3/4): C = L(MxK)@R(KxN), row scale/bias/relu,
// optional transposed store.
template<int TNv>
__global__ void __launch_bounds__(256) sgemm_k(
    const float* __restrict__ L, const float* __restrict__ R, float* __restrict__ C,
    int M, int N, int K,
    const float* __restrict__ dinv, const float* __restrict__ bias, int relu,
    int transC, int ldc) {
  const int MN = TNv / 16;
  __shared__ float Ls[16][68];
  __shared__ float Rs[16][TNv];
  int tid = threadIdx.x;
  int tx = tid & 15, ty = tid >> 4;
  int m0 = blockIdx.y * 64;
  int n0 = blockIdx.x * TNv;
  float acc[4][MN];
#pragma unroll
  for (int i = 0; i < 4; i++)
#pragma unroll
    for (int j = 0; j < MN; j++) acc[i][j] = 0.f;

  int lk = tid & 15, lm = tid >> 4;
  int rn = tid % TNv, rk = tid / TNv;
  const int KS = 256 / TNv;

  for (int kt = 0; kt < K; kt += 16) {
#pragma unroll
    for (int r = 0; r < 4; r++) {
      int m = lm + r * 16;
      Ls[lk][m] = L[(size_t)(m0 + m) * K + kt + lk];
    }
#pragma unroll
    for (int r = 0; r < 16 / KS; r++) {
      int k = rk + r * KS;
      int gn = n0 + rn;
      Rs[k][rn] = (gn < N) ? R[(size_t)(kt + k) * N + gn] : 0.f;
    }
    __syncthreads();
#pragma unroll
    for (int k = 0; k < 16; k++) {
      float a[4], b[MN];
#pragma unroll
      for (int i = 0; i < 4; i++) a[i] = Ls[k][ty * 4 + i];
#pragma unroll
      for (int j = 0; j < MN; j++) b[j] = Rs[k][tx * MN + j];
#pragma unroll
      for (int i = 0; i < 4; i++)
#pragma unroll
        for (int j = 0; j < MN; j++) acc[i][j] += a[i] * b[j];
    }
    __syncthreads();
  }
#pragma unroll
  for (int i = 0; i < 4; i++) {
    int gi = m0 + ty * 4 + i;
#pragma unroll
    for (int j = 0; j < MN; j++) {
      int gj = n0 + tx * MN + j;
      if (gj < N) {
        float v = acc[i][j];
        if (dinv) v *= dinv[gi];
        if (bias) v += bias[gj];
        if (relu) v = fmaxf(v, 0.f);
        if (transC) C[(size_t)gj * ldc + gi] = v;
        else C[(size_t)gi * N + gj] = v;
      }
    }
  }
}

// ---------------------------------------------------------------------------
// bf16 MFMA NT GEMM, split-K: P[z] = A(Mx[kbeg,kend)) @ B^T ; exact small ints.
__global__ void __launch_bounds__(256) mfma_nt_k(const float* __restrict__ A, const float* __restrict__ B,
                                                 float* __restrict__ P, int M, int N, int lda, int Kc) {
  __shared__ short As[128 * 32];
  __shared__ short Bs[128 * 32];
  int tid = threadIdx.x;
  int w = tid >> 6, l = tid & 63;
  int wy = w >> 1, wx = w & 1;
  int q = l >> 4, r = l & 15;
  int m0 = blockIdx.y * 128, n0 = blockIdx.x * 128;
  int kbeg = blockIdx.z * Kc;
  float* C = P + (size_t)blockIdx.z * M * N;
  f32x4_t acc[4][4];
#pragma unroll
  for (int i = 0; i < 4; i++)
#pragma unroll
    for (int j = 0; j < 4; j++) acc[i][j] = (f32x4_t){0.f, 0.f, 0.f, 0.f};

  int srow = tid & 127, scp = tid >> 7;
  const float* Ag = A + (size_t)(m0 + srow) * lda + scp * 16 + kbeg;
  const float* Bg = B + (size_t)(n0 + srow) * lda + scp * 16 + kbeg;
  int g = srow >> 4, rr = srow & 15;
  int d0 = ((g * 4 + scp * 2) * 16 + rr) * 8;
  int d1 = ((g * 4 + scp * 2 + 1) * 16 + rr) * 8;

  for (int kt = 0; kt < Kc; kt += 32) {
    float4 a0 = *(const float4*)(Ag + kt), a1 = *(const float4*)(Ag + kt + 4);
    float4 a2 = *(const float4*)(Ag + kt + 8), a3 = *(const float4*)(Ag + kt + 12);
    float4 b0 = *(const float4*)(Bg + kt), b1 = *(const float4*)(Bg + kt + 4);
    float4 b2 = *(const float4*)(Bg + kt + 8), b3 = *(const float4*)(Bg + kt + 12);
    __syncthreads();
    short8_t sa, sb;
    sa[0] = (short)(__float_as_uint(a0.x) >> 16); sa[1] = (short)(__float_as_uint(a0.y) >> 16);
    sa[2] = (short)(__float_as_uint(a0.z) >> 16); sa[3] = (short)(__float_as_uint(a0.w) >> 16);
    sa[4] = (short)(__float_as_uint(a1.x) >> 16); sa[5] = (short)(__float_as_uint(a1.y) >> 16);
    sa[6] = (short)(__float_as_uint(a1.z) >> 16); sa[7] = (short)(__float_as_uint(a1.w) >> 16);
    *(short8_t*)&As[d0] = sa;
    sa[0] = (short)(__float_as_uint(a2.x) >> 16); sa[1] = (short)(__float_as_uint(a2.y) >> 16);
    sa[2] = (short)(__float_as_uint(a2.z) >> 16); sa[3] = (short)(__float_as_uint(a2.w) >> 16);
    sa[4] = (short)(__float_as_uint(a3.x) >> 16); sa[5] = (short)(__float_as_uint(a3.y) >> 16);
    sa[6] = (short)(__float_as_uint(a3.z) >> 16); sa[7] = (short)(__float_as_uint(a3.w) >> 16);
    *(short8_t*)&As[d1] = sa;
    sb[0] = (short)(__float_as_uint(b0.x) >> 16); sb[1] = (short)(__float_as_uint(b0.y) >> 16);
    sb[2] = (short)(__float_as_uint(b0.z) >> 16); sb[3] = (short)(__float_as_uint(b0.w) >> 16);
    sb[4] = (short)(__float_as_uint(b1.x) >> 16); sb[5] = (short)(__float_as_uint(b1.y) >> 16);
    sb[6] = (short)(__float_as_uint(b1.z) >> 16); sb[7] = (short)(__float_as_uint(b1.w) >> 16);
    *(short8_t*)&Bs[d0] = sb;
    sb[0] = (short)(__float_as_uint(b2.x) >> 16); sb[1] = (short)(__float_as_uint(b2.y) >> 16);
    sb[2] = (short)(__float_as_uint(b2.z) >> 16); sb[3] = (short)(__float_as_uint(b2.w) >> 16);
    sb[4] = (short)(__float_as_uint(b3.x) >> 16); sb[5] = (short)(__float_as_uint(b3.y) >> 16);
    sb[6] = (short)(__float_as_uint(b3.z) >> 16); sb[7] = (short)(__float_as_uint(b3.w) >> 16);
    *(short8_t*)&Bs[d1] = sb;
    __syncthreads();
    short8_t af[4], bf[4];
#pragma unroll
    for (int sm = 0; sm < 4; sm++) af[sm] = *(short8_t*)&As[(((wy * 4 + sm) * 4 + q) * 16 + r) * 8];
#pragma unroll
    for (int sn = 0; sn < 4; sn++) bf[sn] = *(short8_t*)&Bs[(((wx * 4 + sn) * 4 + q) * 16 + r) * 8];
#pragma unroll
    for (int sm = 0; sm < 4; sm++)
#pragma unroll
      for (int sn = 0; sn < 4; sn++)
        acc[sm][sn] = __builtin_amdgcn_mfma_f32_16x16x32_bf16(af[sm], bf[sn], acc[sm][sn], 0, 0, 0);
  }
#pragma unroll
  for (int sm = 0; sm < 4; sm++) {
#pragma unroll
    for (int sn = 0; sn < 4; sn++) {
      int grow = m0 + wy * 64 + sm * 16 + q * 4;
      int gcol = n0 + wx * 64 + sn * 16 + r;
#pragma unroll
      for (int v = 0; v < 4; v++) C[(size_t)(grow + v) * N + gcol] = acc[sm][sn][v];
    }
  }
}

__global__ void mfred_k(const float* __restrict__ P, float* __restrict__ C, int MN, int KS) {
  int t = blockIdx.x * blockDim.x + threadIdx.x;
  if (t >= MN) return;
  float s = 0.f;
  for (int z = 0; z < KS; z++) s += P[(size_t)z * MN + t];
  C[t] = s;
}

// ---------------------------------------------------------------------------
// aug1 SpGEMM: A1[rank(p),rank(j)] += #paths j->k->p, then += 2*A0' pooled.
__global__ void pairs_k(const int* __restrict__ esrc, const int* __restrict__ edst,
                        const int* __restrict__ off, const int* __restrict__ bys,
                        const int* __restrict__ rank1, float* __restrict__ A1p, int E, int m) {
  int e = blockIdx.x * blockDim.x + threadIdx.x;
  if (e >= E) return;
  int j = esrc[e], k = edst[e];
  if (j == k) return;
  int rj = rank1[j];
  if (rj < 0) return;
  int b0 = off[k], b1 = off[k + 1];
  for (int t = b0; t < b1; t++) {
    int ri = rank1[bys[t]];
    if (ri >= 0) atomicAdd(&A1p[(size_t)ri * m + rj], 1.0f);
  }
}

__global__ void dbl_k(const int* __restrict__ esrc, const int* __restrict__ edst,
                      const int* __restrict__ rank1, float* __restrict__ A1p, int E, int m) {
  int e = blockIdx.x * blockDim.x + threadIdx.x;
  if (e >= E) return;
  int s = esrc[e], d = edst[e];
  if (s == d) return;
  int rs = rank1[s], rd = rank1[d];
  if (rs >= 0 && rd >= 0) atomicAdd(&A1p[(size_t)rd * m + rs], 2.0f);
}

// Tiled transpose D = S^T (n x n fp32)
__global__ void transpose_k(const float* __restrict__ S, float* __restrict__ D, int n) {
  __shared__ float tile[32][33];
  int bx = blockIdx.x * 32, by = blockIdx.y * 32;
  int tx = threadIdx.x, ty = threadIdx.y;
  for (int j = 0; j < 32; j += 8) tile[ty + j][tx] = S[(size_t)(by + ty + j) * n + bx + tx];
  __syncthreads();
  for (int j = 0; j < 32; j += 8) D[(size_t)(bx + ty + j) * n + by + tx] = tile[tx][ty + j];
}

// Row gather + I: out[a][k] = S[perm[a]][k] + (perm[a]==k)
__global__ void gatherL_k(const float* __restrict__ S, const int* __restrict__ perm,
                          int n, int m, float* __restrict__ out) {
  int t = blockIdx.x * blockDim.x + threadIdx.x;
  if (t >= m * n) return;
  int a = t / n, k = t - a * n;
  int pa = perm[a];
  out[t] = S[(size_t)pa * n + k] + ((pa == k) ? 1.0f : 0.0f);
}

// Col gather + I: out[k][b] = S[k][perm[b]] + (k==perm[b])
__global__ void gatherR_k(const float* __restrict__ S, const int* __restrict__ perm,
                          int n, int m, float* __restrict__ out) {
  int t = blockIdx.x * blockDim.x + threadIdx.x;
  if (t >= n * m) return;
  int k = t / m, b = t - k * m;
  int pb = perm[b];
  out[t] = S[(size_t)k * n + pb] + ((k == pb) ? 1.0f : 0.0f);
}

// ---------------------------------------------------------------------------
// Dense propagation, split-K stage: P[z][m][c] = sum_{k in chunk z} A[m][k]*YT[c][k]
__global__ void __launch_bounds__(256) prop_stage_k(const float* __restrict__ A, const float* __restrict__ YT,
                                                    float* __restrict__ P, int M, int N, int K, int Kc) {
  __shared__ float red[4][4][64];
  int tid = threadIdx.x, wid = tid >> 6, lane = tid & 63;
  int kl = lane & 15, cg = lane >> 4;
  int m0 = (blockIdx.x * 4 + wid) * 4;
  int ncb = blockIdx.y * 64;
  int z = blockIdx.z;
  int kbeg = z * Kc, kend = kbeg + Kc;
  float acc[4][16];
#pragma unroll
  for (int r0 = 0; r0 < 4; r0++)
#pragma unroll
    for (int c = 0; c < 16; c++) acc[r0][c] = 0.f;

  for (int k0 = kbeg; k0 < kend; k0 += 64) {
    float4 a4[4];
#pragma unroll
    for (int r0 = 0; r0 < 4; r0++)
      a4[r0] = *(const float4*)(A + (size_t)(m0 + r0) * K + k0 + kl * 4);
#pragma unroll
    for (int c = 0; c < 16; c++) {
      int cc = ncb + cg * 16 + c;
      float4 y4 = *(const float4*)(YT + (size_t)cc * K + k0 + kl * 4);
#pragma unroll
      for (int r0 = 0; r0 < 4; r0++) {
        acc[r0][c] += a4[r0].x * y4.x;
        acc[r0][c] += a4[r0].y * y4.y;
        acc[r0][c] += a4[r0].z * y4.z;
        acc[r0][c] += a4[r0].w * y4.w;
      }
    }
  }
#pragma unroll
  for (int m = 1; m <= 8; m <<= 1)
#pragma unroll
    for (int r0 = 0; r0 < 4; r0++)
#pragma unroll
      for (int c = 0; c < 16; c++)
        acc[r0][c] += __shfl_xor(acc[r0][c], m, 64);
  if (kl == 0) {
#pragma unroll
    for (int r0 = 0; r0 < 4; r0++)
#pragma unroll
      for (int c = 0; c < 16; c++) red[wid][r0][cg * 16 + c] = acc[r0][c];
  }
  __syncthreads();
  int cc = ncb + lane;
#pragma unroll
  for (int r0 = 0; r0 < 4; r0++)
    P[((size_t)z * M + (m0 + r0)) * N + cc] = red[wid][r0][lane];
}

// Reduce split-K partials + GCN epilogue.
__global__ void propred_k(const float* __restrict__ P, const float* __restrict__ YT,
                          float* __restrict__ C, int M, int N, int K, int KS,
                          const float* __restrict__ dinv, const float* __restrict__ fixv,
                          const float* __restrict__ bias, int relu) {
  int t = blockIdx.x * blockDim.x + threadIdx.x;
  if (t >= M * N) return;
  int row = t / N, c = t - row * N;
  float s = 0.f;
  for (int z = 0; z < KS; z++) s += P[((size_t)z * M + row) * N + c];
  s += fixv[row] * YT[(size_t)c * K + row];
  s = s * dinv[row] + bias[c];
  if (relu) s = fmaxf(s, 0.f);
  C[t] = s;
}

// ---------------------------------------------------------------------------
// TopK pooling: scores (norm fused), counting-rank (exact lax.top_k order), gather.
__global__ void __launch_bounds__(256) score_k(const float* __restrict__ x, const float* __restrict__ w,
                                               int n, int c, float* __restrict__ s) {
  __shared__ float ws[256];
  __shared__ float red[256];
  __shared__ float nrm;
  int tid = threadIdx.x;
  float t = (tid < c) ? w[tid] : 0.f;
  ws[tid] = t;
  red[tid] = t * t;
  __syncthreads();
  for (int d = 128; d > 0; d >>= 1) {
    if (tid < d) red[tid] += red[tid + d];
    __syncthreads();
  }
  if (tid == 0) nrm = sqrtf(red[0]);
  __syncthreads();
  int i = blockIdx.x * 256 + tid;
  if (i >= n) return;
  const float* xr = x + (size_t)i * c;
  float d = 0.f;
  for (int k = 0; k < c; k++) d += xr[k] * ws[k];
  s[i] = tanhf(d / nrm);
}

// rank(i) = #{j : s_j > s_i || (s_j == s_i && j < i)}  == stable descending pos.
__global__ void __launch_bounds__(256) rankperm_k(const float* __restrict__ scores, int n, int keep,
                                                  int* __restrict__ perm, float* __restrict__ vals,
                                                  int* __restrict__ rankL) {
  __shared__ float ss[4096];
  int tid = threadIdx.x;
  for (int j = tid; j < n; j += 256) ss[j] = scores[j];
  __syncthreads();
  int i = blockIdx.x * 256 + tid;
  float si = ss[i];
  int r = 0;
  for (int j = 0; j < n; j++) {
    float sj = ss[j];
    r += (sj > si) || (sj == si && j < i);
  }
  if (r < keep) { perm[r] = i; vals[r] = si; rankL[i] = r; }
  else rankL[i] = -1;
}

__global__ void poolx_k(const float* __restrict__ x, const int* __restrict__ perm,
                        const float* __restrict__ vals, int keep, int c, float* __restrict__ out) {
  int t = blockIdx.x * blockDim.x + threadIdx.x;
  if (t >= keep * c) return;
  int a = t / c, j = t - a * c;
  out[t] = x[(size_t)perm[a] * c + j] * vals[a];
}

// ---------------------------------------------------------------------------
// Fused unpool+concat: cat[i] = [res[i], rank[i]>=0 ? cur[rank[i]][:c] : 0]
__global__ void catfull_k(const float* __restrict__ res, const float* __restrict__ cur,
                          const int* __restrict__ rankL, int n, int c, int cw,
                          float* __restrict__ cat) {
  int t = blockIdx.x * blockDim.x + threadIdx.x;
  if (t >= n * 2 * c) return;
  int i = t / (2 * c), j = t - i * 2 * c;
  if (j < c) cat[t] = res[(size_t)i * c + j];
  else {
    int rr = rankL[i];
    cat[t] = (rr >= 0) ? cur[(size_t)rr * cw + (j - c)] : 0.f;
  }
}

__global__ void softmax_k(const float* __restrict__ z, float* __restrict__ out, int n, int c) {
  int i = blockIdx.x * blockDim.x + threadIdx.x;
  if (i >= n) return;
  const float* zr = z + (size_t)i * c;
  float m = zr[0];
  for (int j = 1; j < c; j++) m = fmaxf(m, zr[j]);
  float e[64];
  float s = 0.f;
  for (int j = 0; j < c; j++) { e[j] = expf(zr[j] - m); s += e[j]; }
  for (int j = 0; j < c; j++) out[(size_t)i * c + j] = e[j] / s;
}

// ---------------------------------------------------------------------------
extern "C" void kernel_launch(void* const* d_in, const int* in_sizes, int n_in,
                              void* d_out, int out_size, void* d_ws, size_t ws_size,
                              hipStream_t stream) {
  (void)n_in; (void)out_size; (void)ws_size;
  const float* xin = (const float*)d_in[0];
  const int* ei = (const int*)d_in[1];
  const int E = in_sizes[1] / 2;
  const int* esrc = ei;
  const int* edst = ei + E;
  const float* Wd[5] = {(const float*)d_in[2], (const float*)d_in[4], (const float*)d_in[6],
                        (const float*)d_in[8], (const float*)d_in[10]};
  const float* bd[5] = {(const float*)d_in[3], (const float*)d_in[5], (const float*)d_in[7],
                        (const float*)d_in[9], (const float*)d_in[11]};
  const float* pw[4] = {(const float*)d_in[12], (const float*)d_in[13],
                        (const float*)d_in[14], (const float*)d_in[15]};
  const float* Wu[4] = {(const float*)d_in[16], (const float*)d_in[18],
                        (const float*)d_in[20], (const float*)d_in[22]};
  const float* bu[4] = {(const float*)d_in[17], (const float*)d_in[19],
                        (const float*)d_in[21], (const float*)d_in[23]};
  const float* Wo = (const float*)d_in[24];
  const float* bo = (const float*)d_in[25];
  float* out = (float*)d_out;

  char* p = (char*)d_ws;
  auto bumpf = [&](size_t ne) -> float* { float* r = (float*)p; p += ((ne * 4 + 255) & ~(size_t)255); return r; };
  auto bumpi = [&](size_t ne) -> int* { int* r = (int*)p; p += ((ne * 4 + 255) & ~(size_t)255); return r; };

  float* A1 = bumpf((size_t)2048 * 2048);
  float* A2 = bumpf((size_t)1024 * 1024);
  float* A3 = bumpf((size_t)512 * 512);
  float* A4 = bumpf((size_t)256 * 256);
  float* WS1 = bumpf((size_t)8 * 1024 * 1024);   // Pbuf (<=32MB)
  float* WS2 = bumpf((size_t)8 * 1024 * 1024);   // BLf2|BRf2|A1T ; BLf34|BRf34
  float* y = bumpf((size_t)4096 * 64);
  float* YT = bumpf((size_t)4096 * 64);
  float* XS0 = bumpf((size_t)4096 * 32);
  float* XS1 = bumpf((size_t)2048 * 64);
  float* XS2 = bumpf((size_t)1024 * 128);
  float* XS3 = bumpf((size_t)512 * 256);
  float* XA = bumpf((size_t)4096 * 64);
  float* XB = bumpf((size_t)4096 * 32);
  float* scores = bumpf(4096);
  float* vals = bumpf(2048);
  float* dinvL[5];
  float* fixvL[5];
  int nsz[5] = {4096, 2048, 1024, 512, 256};
  for (int i = 0; i < 5; i++) { dinvL[i] = bumpf(nsz[i]); fixvL[i] = bumpf(nsz[i]); }
  int* perm1 = bumpi(2048);
  int* perm2 = bumpi(1024);
  int* perm3 = bumpi(512);
  int* perm4 = bumpi(256);
  int* rank1 = bumpi(4096);
  int* rank2 = bumpi(2048);
  int* rank3 = bumpi(1024);
  int* rank4 = bumpi(512);
  int* cnt = bumpi(4096);
  int* offb = bumpi(4100);
  int* fill = bumpi(4096);
  int* selfc = bumpi(4096);
  int* outcnt = bumpi(4096);
  int* outoff = bumpi(4100);
  int* outfill = bumpi(4096);
  int* bys = bumpi((size_t)E);
  int* outbys = bumpi((size_t)E);

  float* Pbuf = WS1;
  float* BLf2 = WS2;                                   // 1024x2048 = 8MB
  float* BRf2 = WS2 + (size_t)2 * 1024 * 1024;         // 8MB
  float* A1T = WS2 + (size_t)4 * 1024 * 1024;          // 16MB
  float* BLf34 = WS2;                                  // <=2MB
  float* BRf34 = WS2 + (size_t)1024 * 1024;            // <=2MB

  auto sgemm = [&](const float* L, const float* R, float* C, int M, int N, int K,
                   const float* di, const float* bi, int relu, int transC, int ldc) {
    if (N <= 32) {
      dim3 g((N + 31) / 32, M / 64);
      sgemm_k<32><<<g, dim3(256), 0, stream>>>(L, R, C, M, N, K, di, bi, relu, transC, ldc);
    } else {
      dim3 g((N + 63) / 64, M / 64);
      sgemm_k<64><<<g, dim3(256), 0, stream>>>(L, R, C, M, N, K, di, bi, relu, transC, ldc);
    }
  };
  auto gcn_dense = [&](const float* A, int n, const float* x, int cin, const float* W, int cout,
                       const float* bi, int relu, float* zout, const float* di, const float* fx,
                       int Kc, int KS) {
    sgemm(x, W, YT, n, cout, cin, di, nullptr, 0, 1, n);  // YT[cout][n] = (di .* xW)^T
    dim3 g(n / 16, cout / 64, KS);
    prop_stage_k<<<g, dim3(256), 0, stream>>>(A, YT, Pbuf, n, cout, n, Kc);
    propred_k<<<dim3((n * cout + WG - 1) / WG), dim3(WG), 0, stream>>>(
        Pbuf, YT, zout, n, cout, n, KS, di, fx, bi, relu);
  };
  auto pool = [&](const float* x, int n, int c, const float* w, int* perm, int* rankL, float* xout) {
    score_k<<<dim3(n / 256), dim3(256), 0, stream>>>(x, w, n, c, scores);
    rankperm_k<<<dim3(n / 256), dim3(256), 0, stream>>>(scores, n, n / 2, perm, vals, rankL);
    int keep = n / 2;
    poolx_k<<<dim3((keep * c + WG - 1) / WG), dim3(WG), 0, stream>>>(x, perm, vals, keep, c, xout);
  };

  // ---- CSR build (in by dst incl self; out by src excl self) + degrees ----
  hipMemsetAsync(cnt, 0, 4096 * 4, stream);
  hipMemsetAsync(fill, 0, 4096 * 4, stream);
  hipMemsetAsync(selfc, 0, 4096 * 4, stream);
  hipMemsetAsync(outcnt, 0, 4096 * 4, stream);
  hipMemsetAsync(outfill, 0, 4096 * 4, stream);
  edgestats_k<<<dim3((E + WG - 1) / WG), dim3(WG), 0, stream>>>(esrc, edst, cnt, selfc, E);
  exscan_k<<<dim3(1), dim3(1024), 0, stream>>>(cnt, offb);
  scatterd_k<<<dim3((E + WG - 1) / WG), dim3(WG), 0, stream>>>(esrc, edst, offb, fill, bys, E);
  finalize0_k<<<dim3(16), dim3(WG), 0, stream>>>(cnt, selfc, dinvL[0], fixvL[0], 4096);
  outcount_k<<<dim3((E + WG - 1) / WG), dim3(WG), 0, stream>>>(esrc, edst, outcnt, E);
  exscan_k<<<dim3(1), dim3(1024), 0, stream>>>(outcnt, outoff);
  outscatter_k<<<dim3((E + WG - 1) / WG), dim3(WG), 0, stream>>>(esrc, edst, outoff, outfill, outbys, E);

  // ---- GCN0 (sparse A0) ----
  sgemm(xin, Wd[0], y, 4096, 32, 128, dinvL[0], nullptr, 0, 0, 0);
  spmv_k<1><<<dim3(1024), dim3(256), 0, stream>>>(offb, bys, y, 32, dinvL[0], fixvL[0], bd[0], 1, XS0);

  // ---- pool1 + aug1 (sparse edge-join SpGEMM, exact integers) ----
  pool(XS0, 4096, 32, pw[0], perm1, rank1, XA);
  hipMemsetAsync(A1, 0, (size_t)2048 * 2048 * 4, stream);
  pairs_k<<<dim3((E + WG - 1) / WG), dim3(WG), 0, stream>>>(esrc, edst, outoff, outbys, rank1, A1, E, 2048);
  dbl_k<<<dim3((E + WG - 1) / WG), dim3(WG), 0, stream>>>(esrc, edst, rank1, A1, E, 2048);
  rowsum_k<<<dim3(2048), dim3(WG), 0, stream>>>(A1, 2048, dinvL[1], fixvL[1]);
  gcn_dense(A1, 2048, XA, 32, Wd[1], 64, bd[1], 1, XS1, dinvL[1], fixvL[1], 256, 8);

  // ---- level 2: pool, bf16-MFMA split-K augment (exact), GCN ----
  pool(XS1, 2048, 64, pw[1], perm2, rank2, XA);
  transpose_k<<<dim3(64, 64), dim3(32, 8), 0, stream>>>(A1, A1T, 2048);
  gatherL_k<<<dim3((1024 * 2048 + WG - 1) / WG), dim3(WG), 0, stream>>>(A1, perm2, 2048, 1024, BLf2);
  gatherL_k<<<dim3((1024 * 2048 + WG - 1) / WG), dim3(WG), 0, stream>>>(A1T, perm2, 2048, 1024, BRf2);
  mfma_nt_k<<<dim3(8, 8, 8), dim3(256), 0, stream>>>(BLf2, BRf2, Pbuf, 1024, 1024, 2048, 256);
  mfred_k<<<dim3((1024 * 1024 + WG - 1) / WG), dim3(WG), 0, stream>>>(Pbuf, A2, 1024 * 1024, 8);
  rowsum_k<<<dim3(1024), dim3(WG), 0, stream>>>(A2, 1024, dinvL[2], fixvL[2]);
  gcn_dense(A2, 1024, XA, 64, Wd[2], 128, bd[2], 1, XS2, dinvL[2], fixvL[2], 128, 8);

  // ---- level 3 (fp32 augment: values exceed bf16-exact range) ----
  pool(XS2, 1024, 128, pw[2], perm3, rank3, XA);
  gatherL_k<<<dim3((512 * 1024 + WG - 1) / WG), dim3(WG), 0, stream>>>(A2, perm3, 1024, 512, BLf34);
  gatherR_k<<<dim3((1024 * 512 + WG - 1) / WG), dim3(WG), 0, stream>>>(A2, perm3, 1024, 512, BRf34);
  sgemm(BLf34, BRf34, A3, 512, 512, 1024, nullptr, nullptr, 0, 0, 0);
  rowsum_k<<<dim3(512), dim3(WG), 0, stream>>>(A3, 512, dinvL[3], fixvL[3]);
  gcn_dense(A3, 512, XA, 128, Wd[3], 256, bd[3], 1, XS3, dinvL[3], fixvL[3], 64, 8);

  // ---- level 4 ----
  pool(XS3, 512, 256, pw[3], perm4, rank4, XA);
  gatherL_k<<<dim3((256 * 512 + WG - 1) / WG), dim3(WG), 0, stream>>>(A3, perm4, 512, 256, BLf34);
  gatherR_k<<<dim3((512 * 256 + WG - 1) / WG), dim3(WG), 0, stream>>>(A3, perm4, 512, 256, BRf34);
  sgemm(BLf34, BRf34, A4, 256, 256, 512, nullptr, nullptr, 0, 0, 0);
  rowsum_k<<<dim3(256), dim3(WG), 0, stream>>>(A4, 256, dinvL[4], fixvL[4]);
  gcn_dense(A4, 256, XA, 256, Wd[4], 512, bd[4], 1, XB, dinvL[4], fixvL[4], 64, 4);

  // ---- up path (fused unpool-concat via saved rank arrays) ----
  catfull_k<<<dim3((512 * 512 + WG - 1) / WG), dim3(WG), 0, stream>>>(XS3, XB, rank4, 512, 256, 512, XA);
  gcn_dense(A3, 512, XA, 512, Wu[0], 256, bu[0], 1, XB, dinvL[3], fixvL[3], 64, 8);

  catfull_k<<<dim3((1024 * 256 + WG - 1) / WG), dim3(WG), 0, stream>>>(XS2, XB, rank3, 1024, 128, 256, XA);
  gcn_dense(A2, 1024, XA, 256, Wu[1], 128, bu[1], 1, XB, dinvL[2], fixvL[2], 128, 8);

  catfull_k<<<dim3((2048 * 128 + WG - 1) / WG), dim3(WG), 0, stream>>>(XS1, XB, rank2, 2048, 64, 128, XA);
  gcn_dense(A1, 2048, XA, 128, Wu[2], 64, bu[2], 1, XB, dinvL[1], fixvL[1], 256, 8);

  catfull_k<<<dim3((4096 * 64 + WG - 1) / WG), dim3(WG), 0, stream>>>(XS0, XB, rank1, 4096, 32, 64, XA);
  sgemm(XA, Wu[3], y, 4096, 32, 64, dinvL[0], nullptr, 0, 0, 0);
  spmv_k<1><<<dim3(1024), dim3(256), 0, stream>>>(offb, bys, y, 32, dinvL[0], fixvL[0], bu[3], 0, XB);

  // ---- final GCN (sparse A0) + softmax ----
  sgemm(XB, Wo, y, 4096, 37, 32, dinvL[0], nullptr, 0, 0, 0);
  spmv_k<0><<<dim3(1024), dim3(256), 0, stream>>>(offb, bys, y, 37, dinvL[0], fixvL[0], bo, 0, XA);
  softmax_k<<<dim3((4096 + WG - 1) / WG), dim3(WG), 0, stream>>>(XA, out, 4096, 37);
}

// Round 5
// 915.562 us; speedup vs baseline: 2.7069x; 1.1803x over previous
//
#include <hip/hip_runtime.h>
#include <math.h>
#include <stddef.h>

#define WG 256

typedef short short8_t __attribute__((ext_vector_type(8)));
typedef float f32x4_t __attribute__((ext_vector_type(4)));

// ---------------------------------------------------------------------------
// One pass over edges: in-degree (incl self), self count, out-degree (excl self).
__global__ void edgestats2_k(const int* __restrict__ esrc, const int* __restrict__ edst,
                             int* __restrict__ cnt, int* __restrict__ selfc,
                             int* __restrict__ outcnt, int E) {
  int e = blockIdx.x * blockDim.x + threadIdx.x;
  if (e >= E) return;
  int s = esrc[e], d = edst[e];
  atomicAdd(&cnt[d], 1);
  if (s == d) atomicAdd(&selfc[d], 1);
  else atomicAdd(&outcnt[s], 1);
}

__global__ void finalize0_k(const int* __restrict__ cnt, const int* __restrict__ selfc,
                            float* __restrict__ dinv, float* __restrict__ fixv, int n) {
  int i = blockIdx.x * blockDim.x + threadIdx.x;
  if (i >= n) return;
  float fx = (selfc[i] == 0) ? 2.0f : 0.0f;
  float deg = (float)cnt[i] + fx;
  dinv[i] = (deg > 0.f) ? 1.0f / sqrtf(deg) : 0.f;
  fixv[i] = fx;
}

__global__ void __launch_bounds__(1024) exscan_k(const int* __restrict__ cnt, int* __restrict__ off) {
  __shared__ int part[1024];
  int t = threadIdx.x;
  int l0 = cnt[t * 4], l1 = cnt[t * 4 + 1], l2 = cnt[t * 4 + 2], l3 = cnt[t * 4 + 3];
  int s = l0 + l1 + l2 + l3;
  part[t] = s;
  __syncthreads();
  for (int d = 1; d < 1024; d <<= 1) {
    int v = part[t];
    int u = (t >= d) ? part[t - d] : 0;
    __syncthreads();
    part[t] = v + u;
    __syncthreads();
  }
  int ex = (t > 0) ? part[t - 1] : 0;
  off[t * 4] = ex;
  off[t * 4 + 1] = ex + l0;
  off[t * 4 + 2] = ex + l0 + l1;
  off[t * 4 + 3] = ex + l0 + l1 + l2;
  if (t == 1023) off[4096] = part[1023];
}

// in-CSR (by dst, incl self) for SpMV
__global__ void scatterd_k(const int* __restrict__ esrc, const int* __restrict__ edst,
                           const int* __restrict__ off, int* __restrict__ fill,
                           int* __restrict__ bys, int E) {
  int e = blockIdx.x * blockDim.x + threadIdx.x;
  if (e >= E) return;
  int d = edst[e];
  int p = off[d] + atomicAdd(&fill[d], 1);
  bys[p] = esrc[e];
}

__global__ void outscatter_k(const int* __restrict__ esrc, const int* __restrict__ edst,
                             const int* __restrict__ off, int* __restrict__ fill,
                             int* __restrict__ bys, int E) {
  int e = blockIdx.x * blockDim.x + threadIdx.x;
  if (e >= E) return;
  int s = esrc[e], d = edst[e];
  if (s == d) return;
  int p = off[s] + atomicAdd(&fill[s], 1);
  bys[p] = d;
}

// SpMV: Z[d][c] = dinv[d]*(sum_{e:dst=d} y[src_e][c] + fixv[d]*y[d][c]) + bias[c]
template<int SMALL>
__global__ void __launch_bounds__(256) spmv_k(const int* __restrict__ off, const int* __restrict__ bys,
                                              const float* __restrict__ y, int N,
                                              const float* __restrict__ dinv, const float* __restrict__ fixv,
                                              const float* __restrict__ bias, int relu,
                                              float* __restrict__ Z) {
  int w = threadIdx.x >> 6, l = threadIdx.x & 63;
  int row = blockIdx.x * 4 + w;
  int b0 = off[row], b1 = off[row + 1];
  if (SMALL) {  // N == 32
    int c = l & 31, eh = l >> 5;
    float acc = 0.f;
    for (int e = b0 + eh; e < b1; e += 2) { int s = bys[e]; acc += y[(size_t)s * N + c]; }
    acc += __shfl_xor(acc, 32, 64);
    if (eh == 0) {
      float v = acc + fixv[row] * y[(size_t)row * N + c];
      v = v * dinv[row] + (bias ? bias[c] : 0.f);
      if (relu) v = fmaxf(v, 0.f);
      Z[(size_t)row * N + c] = v;
    }
  } else {
    bool act = l < N;
    float acc = 0.f;
    for (int e = b0; e < b1; e++) { int s = bys[e]; if (act) acc += y[(size_t)s * N + l]; }
    if (act) {
      float v = acc + fixv[row] * y[(size_t)row * N + l];
      v = v * dinv[row] + (bias ? bias[l] : 0.f);
      if (relu) v = fmaxf(v, 0.f);
      Z[(size_t)row * N + l] = v;
    }
  }
}

// ---------------------------------------------------------------------------
// Augmented-A normalization: zero diag in place, deg = offdiag rowsum + 2, fix=2.
__global__ void rowsum_k(float* __restrict__ A, int n,
                         float* __restrict__ dinv, float* __restrict__ fixv) {
  __shared__ float red[WG];
  int row = blockIdx.x;
  float* Ar = A + (size_t)row * n;
  float s = 0.f;
  for (int j = threadIdx.x; j < n; j += WG) {
    if (j == row) Ar[j] = 0.f;
    else s += Ar[j];
  }
  red[threadIdx.x] = s;
  __syncthreads();
  for (int d = WG / 2; d > 0; d >>= 1) {
    if ((int)threadIdx.x < d) red[threadIdx.x] += red[threadIdx.x + d];
    __syncthreads();
  }
  if (threadIdx.x == 0) {
    float deg = red[0] + 2.0f;
    dinv[row] = 1.0f / sqrtf(deg);
    fixv[row] = 2.0f;
  }
}

// ---------------------------------------------------------------------------
// fp32 SGEMM: C = L(MxK)@R(KxN), row scale/bias/relu, optional transposed store.
template<int TNv>
__global__ void __launch_bounds__(256) sgemm_k(
    const float* __restrict__ L, const float* __restrict__ R, float* __restrict__ C,
    int M, int N, int K,
    const float* __restrict__ dinv, const float* __restrict__ bias, int relu,
    int transC, int ldc) {
  const int MN = TNv / 16;
  __shared__ float Ls[16][68];
  __shared__ float Rs[16][TNv];
  int tid = threadIdx.x;
  int tx = tid & 15, ty = tid >> 4;
  int m0 = blockIdx.y * 64;
  int n0 = blockIdx.x * TNv;
  float acc[4][MN];
#pragma unroll
  for (int i = 0; i < 4; i++)
#pragma unroll
    for (int j = 0; j < MN; j++) acc[i][j] = 0.f;

  int lk = tid & 15, lm = tid >> 4;
  int rn = tid % TNv, rk = tid / TNv;
  const int KS = 256 / TNv;

  for (int kt = 0; kt < K; kt += 16) {
#pragma unroll
    for (int r = 0; r < 4; r++) {
      int m = lm + r * 16;
      Ls[lk][m] = L[(size_t)(m0 + m) * K + kt + lk];
    }
#pragma unroll
    for (int r = 0; r < 16 / KS; r++) {
      int k = rk + r * KS;
      int gn = n0 + rn;
      Rs[k][rn] = (gn < N) ? R[(size_t)(kt + k) * N + gn] : 0.f;
    }
    __syncthreads();
#pragma unroll
    for (int k = 0; k < 16; k++) {
      float a[4], b[MN];
#pragma unroll
      for (int i = 0; i < 4; i++) a[i] = Ls[k][ty * 4 + i];
#pragma unroll
      for (int j = 0; j < MN; j++) b[j] = Rs[k][tx * MN + j];
#pragma unroll
      for (int i = 0; i < 4; i++)
#pragma unroll
        for (int j = 0; j < MN; j++) acc[i][j] += a[i] * b[j];
    }
    __syncthreads();
  }
#pragma unroll
  for (int i = 0; i < 4; i++) {
    int gi = m0 + ty * 4 + i;
#pragma unroll
    for (int j = 0; j < MN; j++) {
      int gj = n0 + tx * MN + j;
      if (gj < N) {
        float v = acc[i][j];
        if (dinv) v *= dinv[gi];
        if (bias) v += bias[gj];
        if (relu) v = fmaxf(v, 0.f);
        if (transC) C[(size_t)gj * ldc + gi] = v;
        else C[(size_t)gi * N + gj] = v;
      }
    }
  }
}

// ---------------------------------------------------------------------------
// bf16 MFMA NT GEMM, split-K: P[z] = A(Mx[kbeg,kend)) @ B^T ; exact small ints.
__global__ void __launch_bounds__(256) mfma_nt_k(const float* __restrict__ A, const float* __restrict__ B,
                                                 float* __restrict__ P, int M, int N, int lda, int Kc) {
  __shared__ short As[128 * 32];
  __shared__ short Bs[128 * 32];
  int tid = threadIdx.x;
  int w = tid >> 6, l = tid & 63;
  int wy = w >> 1, wx = w & 1;
  int q = l >> 4, r = l & 15;
  int m0 = blockIdx.y * 128, n0 = blockIdx.x * 128;
  int kbeg = blockIdx.z * Kc;
  float* C = P + (size_t)blockIdx.z * M * N;
  f32x4_t acc[4][4];
#pragma unroll
  for (int i = 0; i < 4; i++)
#pragma unroll
    for (int j = 0; j < 4; j++) acc[i][j] = (f32x4_t){0.f, 0.f, 0.f, 0.f};

  int srow = tid & 127, scp = tid >> 7;
  const float* Ag = A + (size_t)(m0 + srow) * lda + scp * 16 + kbeg;
  const float* Bg = B + (size_t)(n0 + srow) * lda + scp * 16 + kbeg;
  int g = srow >> 4, rr = srow & 15;
  int d0 = ((g * 4 + scp * 2) * 16 + rr) * 8;
  int d1 = ((g * 4 + scp * 2 + 1) * 16 + rr) * 8;

  for (int kt = 0; kt < Kc; kt += 32) {
    float4 a0 = *(const float4*)(Ag + kt), a1 = *(const float4*)(Ag + kt + 4);
    float4 a2 = *(const float4*)(Ag + kt + 8), a3 = *(const float4*)(Ag + kt + 12);
    float4 b0 = *(const float4*)(Bg + kt), b1 = *(const float4*)(Bg + kt + 4);
    float4 b2 = *(const float4*)(Bg + kt + 8), b3 = *(const float4*)(Bg + kt + 12);
    __syncthreads();
    short8_t sa, sb;
    sa[0] = (short)(__float_as_uint(a0.x) >> 16); sa[1] = (short)(__float_as_uint(a0.y) >> 16);
    sa[2] = (short)(__float_as_uint(a0.z) >> 16); sa[3] = (short)(__float_as_uint(a0.w) >> 16);
    sa[4] = (short)(__float_as_uint(a1.x) >> 16); sa[5] = (short)(__float_as_uint(a1.y) >> 16);
    sa[6] = (short)(__float_as_uint(a1.z) >> 16); sa[7] = (short)(__float_as_uint(a1.w) >> 16);
    *(short8_t*)&As[d0] = sa;
    sa[0] = (short)(__float_as_uint(a2.x) >> 16); sa[1] = (short)(__float_as_uint(a2.y) >> 16);
    sa[2] = (short)(__float_as_uint(a2.z) >> 16); sa[3] = (short)(__float_as_uint(a2.w) >> 16);
    sa[4] = (short)(__float_as_uint(a3.x) >> 16); sa[5] = (short)(__float_as_uint(a3.y) >> 16);
    sa[6] = (short)(__float_as_uint(a3.z) >> 16); sa[7] = (short)(__float_as_uint(a3.w) >> 16);
    *(short8_t*)&As[d1] = sa;
    sb[0] = (short)(__float_as_uint(b0.x) >> 16); sb[1] = (short)(__float_as_uint(b0.y) >> 16);
    sb[2] = (short)(__float_as_uint(b0.z) >> 16); sb[3] = (short)(__float_as_uint(b0.w) >> 16);
    sb[4] = (short)(__float_as_uint(b1.x) >> 16); sb[5] = (short)(__float_as_uint(b1.y) >> 16);
    sb[6] = (short)(__float_as_uint(b1.z) >> 16); sb[7] = (short)(__float_as_uint(b1.w) >> 16);
    *(short8_t*)&Bs[d0] = sb;
    sb[0] = (short)(__float_as_uint(b2.x) >> 16); sb[1] = (short)(__float_as_uint(b2.y) >> 16);
    sb[2] = (short)(__float_as_uint(b2.z) >> 16); sb[3] = (short)(__float_as_uint(b2.w) >> 16);
    sb[4] = (short)(__float_as_uint(b3.x) >> 16); sb[5] = (short)(__float_as_uint(b3.y) >> 16);
    sb[6] = (short)(__float_as_uint(b3.z) >> 16); sb[7] = (short)(__float_as_uint(b3.w) >> 16);
    *(short8_t*)&Bs[d1] = sb;
    __syncthreads();
    short8_t af[4], bf[4];
#pragma unroll
    for (int sm = 0; sm < 4; sm++) af[sm] = *(short8_t*)&As[(((wy * 4 + sm) * 4 + q) * 16 + r) * 8];
#pragma unroll
    for (int sn = 0; sn < 4; sn++) bf[sn] = *(short8_t*)&Bs[(((wx * 4 + sn) * 4 + q) * 16 + r) * 8];
#pragma unroll
    for (int sm = 0; sm < 4; sm++)
#pragma unroll
      for (int sn = 0; sn < 4; sn++)
        acc[sm][sn] = __builtin_amdgcn_mfma_f32_16x16x32_bf16(af[sm], bf[sn], acc[sm][sn], 0, 0, 0);
  }
#pragma unroll
  for (int sm = 0; sm < 4; sm++) {
#pragma unroll
    for (int sn = 0; sn < 4; sn++) {
      int grow = m0 + wy * 64 + sm * 16 + q * 4;
      int gcol = n0 + wx * 64 + sn * 16 + r;
#pragma unroll
      for (int v = 0; v < 4; v++) C[(size_t)(grow + v) * N + gcol] = acc[sm][sn][v];
    }
  }
}

__global__ void mfred_k(const float* __restrict__ P, float* __restrict__ C, int MN, int KS) {
  int t = blockIdx.x * blockDim.x + threadIdx.x;
  if (t >= MN) return;
  float s = 0.f;
  for (int z = 0; z < KS; z++) s += P[(size_t)z * MN + t];
  C[t] = s;
}

// ---------------------------------------------------------------------------
// aug1 SpGEMM: A1[rank(p),rank(j)] += #paths j->k->p, then += 2*A0' pooled.
__global__ void pairs_k(const int* __restrict__ esrc, const int* __restrict__ edst,
                        const int* __restrict__ off, const int* __restrict__ bys,
                        const int* __restrict__ rank1, float* __restrict__ A1p, int E, int m) {
  int e = blockIdx.x * blockDim.x + threadIdx.x;
  if (e >= E) return;
  int j = esrc[e], k = edst[e];
  if (j == k) return;
  int rj = rank1[j];
  if (rj < 0) return;
  int b0 = off[k], b1 = off[k + 1];
  for (int t = b0; t < b1; t++) {
    int ri = rank1[bys[t]];
    if (ri >= 0) atomicAdd(&A1p[(size_t)ri * m + rj], 1.0f);
  }
}

__global__ void dbl_k(const int* __restrict__ esrc, const int* __restrict__ edst,
                      const int* __restrict__ rank1, float* __restrict__ A1p, int E, int m) {
  int e = blockIdx.x * blockDim.x + threadIdx.x;
  if (e >= E) return;
  int s = esrc[e], d = edst[e];
  if (s == d) return;
  int rs = rank1[s], rd = rank1[d];
  if (rs >= 0 && rd >= 0) atomicAdd(&A1p[(size_t)rd * m + rs], 2.0f);
}

// Tiled transpose D = S^T (n x n fp32)
__global__ void transpose_k(const float* __restrict__ S, float* __restrict__ D, int n) {
  __shared__ float tile[32][33];
  int bx = blockIdx.x * 32, by = blockIdx.y * 32;
  int tx = threadIdx.x, ty = threadIdx.y;
  for (int j = 0; j < 32; j += 8) tile[ty + j][tx] = S[(size_t)(by + ty + j) * n + bx + tx];
  __syncthreads();
  for (int j = 0; j < 32; j += 8) D[(size_t)(bx + ty + j) * n + by + tx] = tile[tx][ty + j];
}

// Row gather + I: out[a][k] = S[perm[a]][k] + (perm[a]==k)
__global__ void gatherL_k(const float* __restrict__ S, const int* __restrict__ perm,
                          int n, int m, float* __restrict__ out) {
  int t = blockIdx.x * blockDim.x + threadIdx.x;
  if (t >= m * n) return;
  int a = t / n, k = t - a * n;
  int pa = perm[a];
  out[t] = S[(size_t)pa * n + k] + ((pa == k) ? 1.0f : 0.0f);
}

// Col gather + I: out[k][b] = S[k][perm[b]] + (k==perm[b])
__global__ void gatherR_k(const float* __restrict__ S, const int* __restrict__ perm,
                          int n, int m, float* __restrict__ out) {
  int t = blockIdx.x * blockDim.x + threadIdx.x;
  if (t >= n * m) return;
  int k = t / m, b = t - k * m;
  int pb = perm[b];
  out[t] = S[(size_t)k * n + pb] + ((k == pb) ? 1.0f : 0.0f);
}

// ---------------------------------------------------------------------------
// Dense propagation, split-K stage: P[z][m][c] = sum_{k in chunk z} A[m][k]*YT[c][k]
__global__ void __launch_bounds__(256) prop_stage_k(const float* __restrict__ A, const float* __restrict__ YT,
                                                    float* __restrict__ P, int M, int N, int K, int Kc) {
  __shared__ float red[4][4][64];
  int tid = threadIdx.x, wid = tid >> 6, lane = tid & 63;
  int kl = lane & 15, cg = lane >> 4;
  int m0 = (blockIdx.x * 4 + wid) * 4;
  int ncb = blockIdx.y * 64;
  int z = blockIdx.z;
  int kbeg = z * Kc, kend = kbeg + Kc;
  float acc[4][16];
#pragma unroll
  for (int r0 = 0; r0 < 4; r0++)
#pragma unroll
    for (int c = 0; c < 16; c++) acc[r0][c] = 0.f;

  for (int k0 = kbeg; k0 < kend; k0 += 64) {
    float4 a4[4];
#pragma unroll
    for (int r0 = 0; r0 < 4; r0++)
      a4[r0] = *(const float4*)(A + (size_t)(m0 + r0) * K + k0 + kl * 4);
#pragma unroll
    for (int c = 0; c < 16; c++) {
      int cc = ncb + cg * 16 + c;
      float4 y4 = *(const float4*)(YT + (size_t)cc * K + k0 + kl * 4);
#pragma unroll
      for (int r0 = 0; r0 < 4; r0++) {
        acc[r0][c] += a4[r0].x * y4.x;
        acc[r0][c] += a4[r0].y * y4.y;
        acc[r0][c] += a4[r0].z * y4.z;
        acc[r0][c] += a4[r0].w * y4.w;
      }
    }
  }
#pragma unroll
  for (int m = 1; m <= 8; m <<= 1)
#pragma unroll
    for (int r0 = 0; r0 < 4; r0++)
#pragma unroll
      for (int c = 0; c < 16; c++)
        acc[r0][c] += __shfl_xor(acc[r0][c], m, 64);
  if (kl == 0) {
#pragma unroll
    for (int r0 = 0; r0 < 4; r0++)
#pragma unroll
      for (int c = 0; c < 16; c++) red[wid][r0][cg * 16 + c] = acc[r0][c];
  }
  __syncthreads();
  int cc = ncb + lane;
#pragma unroll
  for (int r0 = 0; r0 < 4; r0++)
    P[((size_t)z * M + (m0 + r0)) * N + cc] = red[wid][r0][lane];
}

// Reduce split-K partials + GCN epilogue.
__global__ void propred_k(const float* __restrict__ P, const float* __restrict__ YT,
                          float* __restrict__ C, int M, int N, int K, int KS,
                          const float* __restrict__ dinv, const float* __restrict__ fixv,
                          const float* __restrict__ bias, int relu) {
  int t = blockIdx.x * blockDim.x + threadIdx.x;
  if (t >= M * N) return;
  int row = t / N, c = t - row * N;
  float s = 0.f;
  for (int z = 0; z < KS; z++) s += P[((size_t)z * M + row) * N + c];
  s += fixv[row] * YT[(size_t)c * K + row];
  s = s * dinv[row] + bias[c];
  if (relu) s = fmaxf(s, 0.f);
  C[t] = s;
}

// ---------------------------------------------------------------------------
// TopK pooling: scores (norm fused, zeroes rcnt), parallel counting-rank, gather.
__global__ void __launch_bounds__(256) score_k(const float* __restrict__ x, const float* __restrict__ w,
                                               int n, int c, float* __restrict__ s,
                                               int* __restrict__ rcnt) {
  __shared__ float ws[256];
  __shared__ float red[256];
  __shared__ float nrm;
  int tid = threadIdx.x;
  float t = (tid < c) ? w[tid] : 0.f;
  ws[tid] = t;
  red[tid] = t * t;
  __syncthreads();
  for (int d = 128; d > 0; d >>= 1) {
    if (tid < d) red[tid] += red[tid + d];
    __syncthreads();
  }
  if (tid == 0) nrm = sqrtf(red[0]);
  __syncthreads();
  int i = blockIdx.x * 256 + tid;
  if (i >= n) return;
  rcnt[i] = 0;
  const float* xr = x + (size_t)i * c;
  float d = 0.f;
  for (int k = 0; k < c; k++) d += xr[k] * ws[k];
  s[i] = tanhf(d / nrm);
}

// Partial rank counts: rcnt[i] += #{j in chunk : s_j > s_i || (s_j==s_i && j<i)}.
// Integer atomics -> order-independent, deterministic.
__global__ void __launch_bounds__(256) rankcnt_k(const float* __restrict__ scores, int n,
                                                 int* __restrict__ rcnt) {
  __shared__ float sj[256];
  int tid = threadIdx.x;
  int i = blockIdx.x * 256 + tid;
  int j0 = blockIdx.y * 256;
  sj[tid] = scores[j0 + tid];
  float si = scores[i];
  __syncthreads();
  int cnt = 0;
#pragma unroll 8
  for (int t = 0; t < 256; t++) {
    float s = sj[t];
    cnt += (s > si) || (s == si && (j0 + t) < i);
  }
  if (cnt) atomicAdd(&rcnt[i], cnt);
}

__global__ void rankfin_k(const float* __restrict__ scores, const int* __restrict__ rcnt,
                          int n, int keep, int* __restrict__ perm, float* __restrict__ vals,
                          int* __restrict__ rankL) {
  int i = blockIdx.x * blockDim.x + threadIdx.x;
  if (i >= n) return;
  int r = rcnt[i];
  if (r < keep) { perm[r] = i; vals[r] = scores[i]; rankL[i] = r; }
  else rankL[i] = -1;
}

__global__ void poolx_k(const float* __restrict__ x, const int* __restrict__ perm,
                        const float* __restrict__ vals, int keep, int c, float* __restrict__ out) {
  int t = blockIdx.x * blockDim.x + threadIdx.x;
  if (t >= keep * c) return;
  int a = t / c, j = t - a * c;
  out[t] = x[(size_t)perm[a] * c + j] * vals[a];
}

// ---------------------------------------------------------------------------
// Fused unpool+concat: cat[i] = [res[i], rank[i]>=0 ? cur[rank[i]][:c] : 0]
__global__ void catfull_k(const float* __restrict__ res, const float* __restrict__ cur,
                          const int* __restrict__ rankL, int n, int c, int cw,
                          float* __restrict__ cat) {
  int t = blockIdx.x * blockDim.x + threadIdx.x;
  if (t >= n * 2 * c) return;
  int i = t / (2 * c), j = t - i * 2 * c;
  if (j < c) cat[t] = res[(size_t)i * c + j];
  else {
    int rr = rankL[i];
    cat[t] = (rr >= 0) ? cur[(size_t)rr * cw + (j - c)] : 0.f;
  }
}

__global__ void softmax_k(const float* __restrict__ z, float* __restrict__ out, int n, int c) {
  int i = blockIdx.x * blockDim.x + threadIdx.x;
  if (i >= n) return;
  const float* zr = z + (size_t)i * c;
  float m = zr[0];
  for (int j = 1; j < c; j++) m = fmaxf(m, zr[j]);
  float e[64];
  float s = 0.f;
  for (int j = 0; j < c; j++) { e[j] = expf(zr[j] - m); s += e[j]; }
  for (int j = 0; j < c; j++) out[(size_t)i * c + j] = e[j] / s;
}

// ---------------------------------------------------------------------------
extern "C" void kernel_launch(void* const* d_in, const int* in_sizes, int n_in,
                              void* d_out, int out_size, void* d_ws, size_t ws_size,
                              hipStream_t stream) {
  (void)n_in; (void)out_size; (void)ws_size;
  const float* xin = (const float*)d_in[0];
  const int* ei = (const int*)d_in[1];
  const int E = in_sizes[1] / 2;
  const int* esrc = ei;
  const int* edst = ei + E;
  const float* Wd[5] = {(const float*)d_in[2], (const float*)d_in[4], (const float*)d_in[6],
                        (const float*)d_in[8], (const float*)d_in[10]};
  const float* bd[5] = {(const float*)d_in[3], (const float*)d_in[5], (const float*)d_in[7],
                        (const float*)d_in[9], (const float*)d_in[11]};
  const float* pw[4] = {(const float*)d_in[12], (const float*)d_in[13],
                        (const float*)d_in[14], (const float*)d_in[15]};
  const float* Wu[4] = {(const float*)d_in[16], (const float*)d_in[18],
                        (const float*)d_in[20], (const float*)d_in[22]};
  const float* bu[4] = {(const float*)d_in[17], (const float*)d_in[19],
                        (const float*)d_in[21], (const float*)d_in[23]};
  const float* Wo = (const float*)d_in[24];
  const float* bo = (const float*)d_in[25];
  float* out = (float*)d_out;

  char* p = (char*)d_ws;
  auto bumpf = [&](size_t ne) -> float* { float* r = (float*)p; p += ((ne * 4 + 255) & ~(size_t)255); return r; };
  auto bumpi = [&](size_t ne) -> int* { int* r = (int*)p; p += ((ne * 4 + 255) & ~(size_t)255); return r; };

  float* A1 = bumpf((size_t)2048 * 2048);
  float* A2 = bumpf((size_t)1024 * 1024);
  float* A3 = bumpf((size_t)512 * 512);
  float* A4 = bumpf((size_t)256 * 256);
  float* WS1 = bumpf((size_t)8 * 1024 * 1024);   // Pbuf (<=32MB)
  float* WS2 = bumpf((size_t)8 * 1024 * 1024);   // BLf2|BRf2|A1T ; BLf34|BRf34
  float* y = bumpf((size_t)4096 * 64);
  float* YT = bumpf((size_t)4096 * 64);
  float* XS0 = bumpf((size_t)4096 * 32);
  float* XS1 = bumpf((size_t)2048 * 64);
  float* XS2 = bumpf((size_t)1024 * 128);
  float* XS3 = bumpf((size_t)512 * 256);
  float* XA = bumpf((size_t)4096 * 64);
  float* XB = bumpf((size_t)4096 * 32);
  float* scores = bumpf(4096);
  float* vals = bumpf(2048);
  float* dinvL[5];
  float* fixvL[5];
  int nsz[5] = {4096, 2048, 1024, 512, 256};
  for (int i = 0; i < 5; i++) { dinvL[i] = bumpf(nsz[i]); fixvL[i] = bumpf(nsz[i]); }
  int* perm1 = bumpi(2048);
  int* perm2 = bumpi(1024);
  int* perm3 = bumpi(512);
  int* perm4 = bumpi(256);
  int* rank1 = bumpi(4096);
  int* rank2 = bumpi(2048);
  int* rank3 = bumpi(1024);
  int* rank4 = bumpi(512);
  // contiguous zero-init block: cnt | selfc | outcnt | fill | outfill  (5 x 16KB)
  int* cnt = bumpi(4096);
  int* selfc = bumpi(4096);
  int* outcnt = bumpi(4096);
  int* fill = bumpi(4096);
  int* outfill = bumpi(4096);
  int* offb = bumpi(4100);
  int* outoff = bumpi(4100);
  int* rcnt = bumpi(4096);
  int* bys = bumpi((size_t)E);
  int* outbys = bumpi((size_t)E);

  float* Pbuf = WS1;
  float* BLf2 = WS2;                                   // 1024x2048 = 8MB
  float* BRf2 = WS2 + (size_t)2 * 1024 * 1024;         // 8MB
  float* A1T = WS2 + (size_t)4 * 1024 * 1024;          // 16MB
  float* BLf34 = WS2;                                  // <=2MB
  float* BRf34 = WS2 + (size_t)1024 * 1024;            // <=2MB

  auto sgemm = [&](const float* L, const float* R, float* C, int M, int N, int K,
                   const float* di, const float* bi, int relu, int transC, int ldc) {
    if (N <= 32) {
      dim3 g((N + 31) / 32, M / 64);
      sgemm_k<32><<<g, dim3(256), 0, stream>>>(L, R, C, M, N, K, di, bi, relu, transC, ldc);
    } else {
      dim3 g((N + 63) / 64, M / 64);
      sgemm_k<64><<<g, dim3(256), 0, stream>>>(L, R, C, M, N, K, di, bi, relu, transC, ldc);
    }
  };
  auto gcn_dense = [&](const float* A, int n, const float* x, int cin, const float* W, int cout,
                       const float* bi, int relu, float* zout, const float* di, const float* fx,
                       int Kc, int KS) {
    sgemm(x, W, YT, n, cout, cin, di, nullptr, 0, 1, n);  // YT[cout][n] = (di .* xW)^T
    dim3 g(n / 16, cout / 64, KS);
    prop_stage_k<<<g, dim3(256), 0, stream>>>(A, YT, Pbuf, n, cout, n, Kc);
    propred_k<<<dim3((n * cout + WG - 1) / WG), dim3(WG), 0, stream>>>(
        Pbuf, YT, zout, n, cout, n, KS, di, fx, bi, relu);
  };
  auto pool = [&](const float* x, int n, int c, const float* w, int* perm, int* rankL, float* xout) {
    score_k<<<dim3(n / 256), dim3(256), 0, stream>>>(x, w, n, c, scores, rcnt);
    rankcnt_k<<<dim3(n / 256, n / 256), dim3(256), 0, stream>>>(scores, n, rcnt);
    rankfin_k<<<dim3(n / 256), dim3(256), 0, stream>>>(scores, rcnt, n, n / 2, perm, vals, rankL);
    int keep = n / 2;
    poolx_k<<<dim3((keep * c + WG - 1) / WG), dim3(WG), 0, stream>>>(x, perm, vals, keep, c, xout);
  };

  // ---- CSR build (one memset covers cnt/selfc/outcnt/fill/outfill) ----
  hipMemsetAsync(cnt, 0, 5 * 4096 * 4, stream);
  edgestats2_k<<<dim3((E + WG - 1) / WG), dim3(WG), 0, stream>>>(esrc, edst, cnt, selfc, outcnt, E);
  exscan_k<<<dim3(1), dim3(1024), 0, stream>>>(cnt, offb);
  scatterd_k<<<dim3((E + WG - 1) / WG), dim3(WG), 0, stream>>>(esrc, edst, offb, fill, bys, E);
  finalize0_k<<<dim3(16), dim3(WG), 0, stream>>>(cnt, selfc, dinvL[0], fixvL[0], 4096);
  exscan_k<<<dim3(1), dim3(1024), 0, stream>>>(outcnt, outoff);
  outscatter_k<<<dim3((E + WG - 1) / WG), dim3(WG), 0, stream>>>(esrc, edst, outoff, outfill, outbys, E);

  // ---- GCN0 (sparse A0) ----
  sgemm(xin, Wd[0], y, 4096, 32, 128, dinvL[0], nullptr, 0, 0, 0);
  spmv_k<1><<<dim3(1024), dim3(256), 0, stream>>>(offb, bys, y, 32, dinvL[0], fixvL[0], bd[0], 1, XS0);

  // ---- pool1 + aug1 (sparse edge-join SpGEMM, exact integers) ----
  pool(XS0, 4096, 32, pw[0], perm1, rank1, XA);
  hipMemsetAsync(A1, 0, (size_t)2048 * 2048 * 4, stream);
  pairs_k<<<dim3((E + WG - 1) / WG), dim3(WG), 0, stream>>>(esrc, edst, outoff, outbys, rank1, A1, E, 2048);
  dbl_k<<<dim3((E + WG - 1) / WG), dim3(WG), 0, stream>>>(esrc, edst, rank1, A1, E, 2048);
  rowsum_k<<<dim3(2048), dim3(WG), 0, stream>>>(A1, 2048, dinvL[1], fixvL[1]);
  gcn_dense(A1, 2048, XA, 32, Wd[1], 64, bd[1], 1, XS1, dinvL[1], fixvL[1], 256, 8);

  // ---- level 2: pool, bf16-MFMA split-K augment (exact), GCN ----
  pool(XS1, 2048, 64, pw[1], perm2, rank2, XA);
  transpose_k<<<dim3(64, 64), dim3(32, 8), 0, stream>>>(A1, A1T, 2048);
  gatherL_k<<<dim3((1024 * 2048 + WG - 1) / WG), dim3(WG), 0, stream>>>(A1, perm2, 2048, 1024, BLf2);
  gatherL_k<<<dim3((1024 * 2048 + WG - 1) / WG), dim3(WG), 0, stream>>>(A1T, perm2, 2048, 1024, BRf2);
  mfma_nt_k<<<dim3(8, 8, 8), dim3(256), 0, stream>>>(BLf2, BRf2, Pbuf, 1024, 1024, 2048, 256);
  mfred_k<<<dim3((1024 * 1024 + WG - 1) / WG), dim3(WG), 0, stream>>>(Pbuf, A2, 1024 * 1024, 8);
  rowsum_k<<<dim3(1024), dim3(WG), 0, stream>>>(A2, 1024, dinvL[2], fixvL[2]);
  gcn_dense(A2, 1024, XA, 64, Wd[2], 128, bd[2], 1, XS2, dinvL[2], fixvL[2], 128, 8);

  // ---- level 3 (fp32 augment: values exceed bf16-exact range) ----
  pool(XS2, 1024, 128, pw[2], perm3, rank3, XA);
  gatherL_k<<<dim3((512 * 1024 + WG - 1) / WG), dim3(WG), 0, stream>>>(A2, perm3, 1024, 512, BLf34);
  gatherR_k<<<dim3((1024 * 512 + WG - 1) / WG), dim3(WG), 0, stream>>>(A2, perm3, 1024, 512, BRf34);
  sgemm(BLf34, BRf34, A3, 512, 512, 1024, nullptr, nullptr, 0, 0, 0);
  rowsum_k<<<dim3(512), dim3(WG), 0, stream>>>(A3, 512, dinvL[3], fixvL[3]);
  gcn_dense(A3, 512, XA, 128, Wd[3], 256, bd[3], 1, XS3, dinvL[3], fixvL[3], 64, 8);

  // ---- level 4 ----
  pool(XS3, 512, 256, pw[3], perm4, rank4, XA);
  gatherL_k<<<dim3((256 * 512 + WG - 1) / WG), dim3(WG), 0, stream>>>(A3, perm4, 512, 256, BLf34);
  gatherR_k<<<dim3((512 * 256 + WG - 1) / WG), dim3(WG), 0, stream>>>(A3, perm4, 512, 256, BRf34);
  sgemm(BLf34, BRf34, A4, 256, 256, 512, nullptr, nullptr, 0, 0, 0);
  rowsum_k<<<dim3(256), dim3(WG), 0, stream>>>(A4, 256, dinvL[4], fixvL[4]);
  gcn_dense(A4, 256, XA, 256, Wd[4], 512, bd[4], 1, XB, dinvL[4], fixvL[4], 64, 4);

  // ---- up path (fused unpool-concat via saved rank arrays) ----
  catfull_k<<<dim3((512 * 512 + WG - 1) / WG), dim3(WG), 0, stream>>>(XS3, XB, rank4, 512, 256, 512, XA);
  gcn_dense(A3, 512, XA, 512, Wu[0], 256, bu[0], 1, XB, dinvL[3], fixvL[3], 64, 8);

  catfull_k<<<dim3((1024 * 256 + WG - 1) / WG), dim3(WG), 0, stream>>>(XS2, XB, rank3, 1024, 128, 256, XA);
  gcn_dense(A2, 1024, XA, 256, Wu[1], 128, bu[1], 1, XB, dinvL[2], fixvL[2], 128, 8);

  catfull_k<<<dim3((2048 * 128 + WG - 1) / WG), dim3(WG), 0, stream>>>(XS1, XB, rank2, 2048, 64, 128, XA);
  gcn_dense(A1, 2048, XA, 128, Wu[2], 64, bu[2], 1, XB, dinvL[1], fixvL[1], 256, 8);

  catfull_k<<<dim3((4096 * 64 + WG - 1) / WG), dim3(WG), 0, stream>>>(XS0, XB, rank1, 4096, 32, 64, XA);
  sgemm(XA, Wu[3], y, 4096, 32, 64, dinvL[0], nullptr, 0, 0, 0);
  spmv_k<1><<<dim3(1024), dim3(256), 0, stream>>>(offb, bys, y, 32, dinvL[0], fixvL[0], bu[3], 0, XB);

  // ---- final GCN (sparse A0) + softmax ----
  sgemm(XB, Wo, y, 4096, 37, 32, dinvL[0], nullptr, 0, 0, 0);
  spmv_k<0><<<dim3(1024), dim3(256), 0, stream>>>(offb, bys, y, 37, dinvL[0], fixvL[0], bo, 0, XA);
  softmax_k<<<dim3((4096 + WG - 1) / WG), dim3(WG), 0, stream>>>(XA, out, 4096, 37);
}

// Round 6
// 732.958 us; speedup vs baseline: 3.3812x; 1.2491x over previous
//
#include <hip/hip_runtime.h>
#include <math.h>
#include <stddef.h>

#define WG 256

typedef short short8_t __attribute__((ext_vector_type(8)));
typedef float f32x4_t __attribute__((ext_vector_type(4)));

// ---------------------------------------------------------------------------
// One pass over edges: in-degree (incl self), self count, out-degree (excl self).
__global__ void edgestats2_k(const int* __restrict__ esrc, const int* __restrict__ edst,
                             int* __restrict__ cnt, int* __restrict__ selfc,
                             int* __restrict__ outcnt, int E) {
  int e = blockIdx.x * blockDim.x + threadIdx.x;
  if (e >= E) return;
  int s = esrc[e], d = edst[e];
  atomicAdd(&cnt[d], 1);
  if (s == d) atomicAdd(&selfc[d], 1);
  else atomicAdd(&outcnt[s], 1);
}

__global__ void finalize0_k(const int* __restrict__ cnt, const int* __restrict__ selfc,
                            float* __restrict__ dinv, float* __restrict__ fixv, int n) {
  int i = blockIdx.x * blockDim.x + threadIdx.x;
  if (i >= n) return;
  float fx = (selfc[i] == 0) ? 2.0f : 0.0f;
  float deg = (float)cnt[i] + fx;
  dinv[i] = (deg > 0.f) ? 1.0f / sqrtf(deg) : 0.f;
  fixv[i] = fx;
}

__global__ void __launch_bounds__(1024) exscan_k(const int* __restrict__ cnt, int* __restrict__ off) {
  __shared__ int part[1024];
  int t = threadIdx.x;
  int l0 = cnt[t * 4], l1 = cnt[t * 4 + 1], l2 = cnt[t * 4 + 2], l3 = cnt[t * 4 + 3];
  int s = l0 + l1 + l2 + l3;
  part[t] = s;
  __syncthreads();
  for (int d = 1; d < 1024; d <<= 1) {
    int v = part[t];
    int u = (t >= d) ? part[t - d] : 0;
    __syncthreads();
    part[t] = v + u;
    __syncthreads();
  }
  int ex = (t > 0) ? part[t - 1] : 0;
  off[t * 4] = ex;
  off[t * 4 + 1] = ex + l0;
  off[t * 4 + 2] = ex + l0 + l1;
  off[t * 4 + 3] = ex + l0 + l1 + l2;
  if (t == 1023) off[4096] = part[1023];
}

// in-CSR (by dst, incl self) for SpMV
__global__ void scatterd_k(const int* __restrict__ esrc, const int* __restrict__ edst,
                           const int* __restrict__ off, int* __restrict__ fill,
                           int* __restrict__ bys, int E) {
  int e = blockIdx.x * blockDim.x + threadIdx.x;
  if (e >= E) return;
  int d = edst[e];
  int p = off[d] + atomicAdd(&fill[d], 1);
  bys[p] = esrc[e];
}

__global__ void outscatter_k(const int* __restrict__ esrc, const int* __restrict__ edst,
                             const int* __restrict__ off, int* __restrict__ fill,
                             int* __restrict__ bys, int E) {
  int e = blockIdx.x * blockDim.x + threadIdx.x;
  if (e >= E) return;
  int s = esrc[e], d = edst[e];
  if (s == d) return;
  int p = off[s] + atomicAdd(&fill[s], 1);
  bys[p] = d;
}

// SpMV: Z[d][c] = dinv[d]*(sum_{e:dst=d} y[src_e][c] + fixv[d]*y[d][c]) + bias[c]
template<int SMALL>
__global__ void __launch_bounds__(256) spmv_k(const int* __restrict__ off, const int* __restrict__ bys,
                                              const float* __restrict__ y, int N,
                                              const float* __restrict__ dinv, const float* __restrict__ fixv,
                                              const float* __restrict__ bias, int relu,
                                              float* __restrict__ Z) {
  int w = threadIdx.x >> 6, l = threadIdx.x & 63;
  int row = blockIdx.x * 4 + w;
  int b0 = off[row], b1 = off[row + 1];
  if (SMALL) {  // N == 32
    int c = l & 31, eh = l >> 5;
    float acc = 0.f;
    for (int e = b0 + eh; e < b1; e += 2) { int s = bys[e]; acc += y[(size_t)s * N + c]; }
    acc += __shfl_xor(acc, 32, 64);
    if (eh == 0) {
      float v = acc + fixv[row] * y[(size_t)row * N + c];
      v = v * dinv[row] + (bias ? bias[c] : 0.f);
      if (relu) v = fmaxf(v, 0.f);
      Z[(size_t)row * N + c] = v;
    }
  } else {
    bool act = l < N;
    float acc = 0.f;
    for (int e = b0; e < b1; e++) { int s = bys[e]; if (act) acc += y[(size_t)s * N + l]; }
    if (act) {
      float v = acc + fixv[row] * y[(size_t)row * N + l];
      v = v * dinv[row] + (bias ? bias[l] : 0.f);
      if (relu) v = fmaxf(v, 0.f);
      Z[(size_t)row * N + l] = v;
    }
  }
}

// ---------------------------------------------------------------------------
// Augmented-A normalization: zero diag in place, deg = offdiag rowsum + 2, fix=2.
__global__ void rowsum_k(float* __restrict__ A, int n,
                         float* __restrict__ dinv, float* __restrict__ fixv) {
  __shared__ float red[WG];
  int row = blockIdx.x;
  float* Ar = A + (size_t)row * n;
  float s = 0.f;
  for (int j = threadIdx.x; j < n; j += WG) {
    if (j == row) Ar[j] = 0.f;
    else s += Ar[j];
  }
  red[threadIdx.x] = s;
  __syncthreads();
  for (int d = WG / 2; d > 0; d >>= 1) {
    if ((int)threadIdx.x < d) red[threadIdx.x] += red[threadIdx.x + d];
    __syncthreads();
  }
  if (threadIdx.x == 0) {
    float deg = red[0] + 2.0f;
    dinv[row] = 1.0f / sqrtf(deg);
    fixv[row] = 2.0f;
  }
}

// ---------------------------------------------------------------------------
// fp32 SGEMM: C = L(MxK)@R(KxN). Fused mode (P==null): row scale/bias/relu,
// optional transposed store. Split-K mode (P!=null): blockIdx.z selects a
// Kc-chunk, raw partials to P[z]; epilogue deferred to sgemmred_k.
template<int TNv>
__global__ void __launch_bounds__(256) sgemm_k(
    const float* __restrict__ L, const float* __restrict__ R, float* __restrict__ C,
    int M, int N, int K,
    const float* __restrict__ dinv, const float* __restrict__ bias, int relu,
    int transC, int ldc, float* __restrict__ P, int Kc) {
  const int MN = TNv / 16;
  __shared__ float Ls[16][68];
  __shared__ float Rs[16][TNv];
  int tid = threadIdx.x;
  int tx = tid & 15, ty = tid >> 4;
  int m0 = blockIdx.y * 64;
  int n0 = blockIdx.x * TNv;
  int kbeg = 0, kend = K;
  if (P) { kbeg = blockIdx.z * Kc; kend = kbeg + Kc; }
  float acc[4][MN];
#pragma unroll
  for (int i = 0; i < 4; i++)
#pragma unroll
    for (int j = 0; j < MN; j++) acc[i][j] = 0.f;

  int lk = tid & 15, lm = tid >> 4;
  int rn = tid % TNv, rk = tid / TNv;
  const int KS = 256 / TNv;

  for (int kt = kbeg; kt < kend; kt += 16) {
#pragma unroll
    for (int r = 0; r < 4; r++) {
      int m = lm + r * 16;
      Ls[lk][m] = L[(size_t)(m0 + m) * K + kt + lk];
    }
#pragma unroll
    for (int r = 0; r < 16 / KS; r++) {
      int k = rk + r * KS;
      int gn = n0 + rn;
      Rs[k][rn] = (gn < N) ? R[(size_t)(kt + k) * N + gn] : 0.f;
    }
    __syncthreads();
#pragma unroll
    for (int k = 0; k < 16; k++) {
      float a[4], b[MN];
#pragma unroll
      for (int i = 0; i < 4; i++) a[i] = Ls[k][ty * 4 + i];
#pragma unroll
      for (int j = 0; j < MN; j++) b[j] = Rs[k][tx * MN + j];
#pragma unroll
      for (int i = 0; i < 4; i++)
#pragma unroll
        for (int j = 0; j < MN; j++) acc[i][j] += a[i] * b[j];
    }
    __syncthreads();
  }
  if (P) {
    float* Pz = P + (size_t)blockIdx.z * M * N;
#pragma unroll
    for (int i = 0; i < 4; i++) {
      int gi = m0 + ty * 4 + i;
#pragma unroll
      for (int j = 0; j < MN; j++) {
        int gj = n0 + tx * MN + j;
        if (gj < N) Pz[(size_t)gi * N + gj] = acc[i][j];
      }
    }
    return;
  }
#pragma unroll
  for (int i = 0; i < 4; i++) {
    int gi = m0 + ty * 4 + i;
#pragma unroll
    for (int j = 0; j < MN; j++) {
      int gj = n0 + tx * MN + j;
      if (gj < N) {
        float v = acc[i][j];
        if (dinv) v *= dinv[gi];
        if (bias) v += bias[gj];
        if (relu) v = fmaxf(v, 0.f);
        if (transC) C[(size_t)gj * ldc + gi] = v;
        else C[(size_t)gi * N + gj] = v;
      }
    }
  }
}

// Deterministic fixed-order split-K reduce + epilogue.
__global__ void sgemmred_k(const float* __restrict__ P, float* __restrict__ C,
                           int M, int N, int KS,
                           const float* __restrict__ dinv, const float* __restrict__ bias,
                           int relu, int transC, int ldc) {
  int t = blockIdx.x * blockDim.x + threadIdx.x;
  if (t >= M * N) return;
  int i = t / N, j = t - i * N;
  float s = 0.f;
  for (int z = 0; z < KS; z++) s += P[(size_t)z * M * N + t];
  if (dinv) s *= dinv[i];
  if (bias) s += bias[j];
  if (relu) s = fmaxf(s, 0.f);
  if (transC) C[(size_t)j * ldc + i] = s;
  else C[t] = s;
}

// ---------------------------------------------------------------------------
// bf16 MFMA NT GEMM, split-K: P[z] = A(Mx[kbeg,kend)) @ B^T ; exact small ints.
__global__ void __launch_bounds__(256) mfma_nt_k(const float* __restrict__ A, const float* __restrict__ B,
                                                 float* __restrict__ P, int M, int N, int lda, int Kc) {
  __shared__ short As[128 * 32];
  __shared__ short Bs[128 * 32];
  int tid = threadIdx.x;
  int w = tid >> 6, l = tid & 63;
  int wy = w >> 1, wx = w & 1;
  int q = l >> 4, r = l & 15;
  int m0 = blockIdx.y * 128, n0 = blockIdx.x * 128;
  int kbeg = blockIdx.z * Kc;
  float* C = P + (size_t)blockIdx.z * M * N;
  f32x4_t acc[4][4];
#pragma unroll
  for (int i = 0; i < 4; i++)
#pragma unroll
    for (int j = 0; j < 4; j++) acc[i][j] = (f32x4_t){0.f, 0.f, 0.f, 0.f};

  int srow = tid & 127, scp = tid >> 7;
  const float* Ag = A + (size_t)(m0 + srow) * lda + scp * 16 + kbeg;
  const float* Bg = B + (size_t)(n0 + srow) * lda + scp * 16 + kbeg;
  int g = srow >> 4, rr = srow & 15;
  int d0 = ((g * 4 + scp * 2) * 16 + rr) * 8;
  int d1 = ((g * 4 + scp * 2 + 1) * 16 + rr) * 8;

  for (int kt = 0; kt < Kc; kt += 32) {
    float4 a0 = *(const float4*)(Ag + kt), a1 = *(const float4*)(Ag + kt + 4);
    float4 a2 = *(const float4*)(Ag + kt + 8), a3 = *(const float4*)(Ag + kt + 12);
    float4 b0 = *(const float4*)(Bg + kt), b1 = *(const float4*)(Bg + kt + 4);
    float4 b2 = *(const float4*)(Bg + kt + 8), b3 = *(const float4*)(Bg + kt + 12);
    __syncthreads();
    short8_t sa, sb;
    sa[0] = (short)(__float_as_uint(a0.x) >> 16); sa[1] = (short)(__float_as_uint(a0.y) >> 16);
    sa[2] = (short)(__float_as_uint(a0.z) >> 16); sa[3] = (short)(__float_as_uint(a0.w) >> 16);
    sa[4] = (short)(__float_as_uint(a1.x) >> 16); sa[5] = (short)(__float_as_uint(a1.y) >> 16);
    sa[6] = (short)(__float_as_uint(a1.z) >> 16); sa[7] = (short)(__float_as_uint(a1.w) >> 16);
    *(short8_t*)&As[d0] = sa;
    sa[0] = (short)(__float_as_uint(a2.x) >> 16); sa[1] = (short)(__float_as_uint(a2.y) >> 16);
    sa[2] = (short)(__float_as_uint(a2.z) >> 16); sa[3] = (short)(__float_as_uint(a2.w) >> 16);
    sa[4] = (short)(__float_as_uint(a3.x) >> 16); sa[5] = (short)(__float_as_uint(a3.y) >> 16);
    sa[6] = (short)(__float_as_uint(a3.z) >> 16); sa[7] = (short)(__float_as_uint(a3.w) >> 16);
    *(short8_t*)&As[d1] = sa;
    sb[0] = (short)(__float_as_uint(b0.x) >> 16); sb[1] = (short)(__float_as_uint(b0.y) >> 16);
    sb[2] = (short)(__float_as_uint(b0.z) >> 16); sb[3] = (short)(__float_as_uint(b0.w) >> 16);
    sb[4] = (short)(__float_as_uint(b1.x) >> 16); sb[5] = (short)(__float_as_uint(b1.y) >> 16);
    sb[6] = (short)(__float_as_uint(b1.z) >> 16); sb[7] = (short)(__float_as_uint(b1.w) >> 16);
    *(short8_t*)&Bs[d0] = sb;
    sb[0] = (short)(__float_as_uint(b2.x) >> 16); sb[1] = (short)(__float_as_uint(b2.y) >> 16);
    sb[2] = (short)(__float_as_uint(b2.z) >> 16); sb[3] = (short)(__float_as_uint(b2.w) >> 16);
    sb[4] = (short)(__float_as_uint(b3.x) >> 16); sb[5] = (short)(__float_as_uint(b3.y) >> 16);
    sb[6] = (short)(__float_as_uint(b3.z) >> 16); sb[7] = (short)(__float_as_uint(b3.w) >> 16);
    *(short8_t*)&Bs[d1] = sb;
    __syncthreads();
    short8_t af[4], bf[4];
#pragma unroll
    for (int sm = 0; sm < 4; sm++) af[sm] = *(short8_t*)&As[(((wy * 4 + sm) * 4 + q) * 16 + r) * 8];
#pragma unroll
    for (int sn = 0; sn < 4; sn++) bf[sn] = *(short8_t*)&Bs[(((wx * 4 + sn) * 4 + q) * 16 + r) * 8];
#pragma unroll
    for (int sm = 0; sm < 4; sm++)
#pragma unroll
      for (int sn = 0; sn < 4; sn++)
        acc[sm][sn] = __builtin_amdgcn_mfma_f32_16x16x32_bf16(af[sm], bf[sn], acc[sm][sn], 0, 0, 0);
  }
#pragma unroll
  for (int sm = 0; sm < 4; sm++) {
#pragma unroll
    for (int sn = 0; sn < 4; sn++) {
      int grow = m0 + wy * 64 + sm * 16 + q * 4;
      int gcol = n0 + wx * 64 + sn * 16 + r;
#pragma unroll
      for (int v = 0; v < 4; v++) C[(size_t)(grow + v) * N + gcol] = acc[sm][sn][v];
    }
  }
}

__global__ void mfred_k(const float* __restrict__ P, float* __restrict__ C, int MN, int KS) {
  int t = blockIdx.x * blockDim.x + threadIdx.x;
  if (t >= MN) return;
  float s = 0.f;
  for (int z = 0; z < KS; z++) s += P[(size_t)z * MN + t];
  C[t] = s;
}

// ---------------------------------------------------------------------------
// aug1 SpGEMM: A1[rank(p),rank(j)] += #paths j->k->p, then += 2*A0' pooled.
__global__ void pairs_k(const int* __restrict__ esrc, const int* __restrict__ edst,
                        const int* __restrict__ off, const int* __restrict__ bys,
                        const int* __restrict__ rank1, float* __restrict__ A1p, int E, int m) {
  int e = blockIdx.x * blockDim.x + threadIdx.x;
  if (e >= E) return;
  int j = esrc[e], k = edst[e];
  if (j == k) return;
  int rj = rank1[j];
  if (rj < 0) return;
  int b0 = off[k], b1 = off[k + 1];
  for (int t = b0; t < b1; t++) {
    int ri = rank1[bys[t]];
    if (ri >= 0) atomicAdd(&A1p[(size_t)ri * m + rj], 1.0f);
  }
}

__global__ void dbl_k(const int* __restrict__ esrc, const int* __restrict__ edst,
                      const int* __restrict__ rank1, float* __restrict__ A1p, int E, int m) {
  int e = blockIdx.x * blockDim.x + threadIdx.x;
  if (e >= E) return;
  int s = esrc[e], d = edst[e];
  if (s == d) return;
  int rs = rank1[s], rd = rank1[d];
  if (rs >= 0 && rd >= 0) atomicAdd(&A1p[(size_t)rd * m + rs], 2.0f);
}

// Tiled transpose D = S^T (n x n fp32)
__global__ void transpose_k(const float* __restrict__ S, float* __restrict__ D, int n) {
  __shared__ float tile[32][33];
  int bx = blockIdx.x * 32, by = blockIdx.y * 32;
  int tx = threadIdx.x, ty = threadIdx.y;
  for (int j = 0; j < 32; j += 8) tile[ty + j][tx] = S[(size_t)(by + ty + j) * n + bx + tx];
  __syncthreads();
  for (int j = 0; j < 32; j += 8) D[(size_t)(bx + ty + j) * n + by + tx] = tile[tx][ty + j];
}

// Row gather + I: out[a][k] = S[perm[a]][k] + (perm[a]==k)
__global__ void gatherL_k(const float* __restrict__ S, const int* __restrict__ perm,
                          int n, int m, float* __restrict__ out) {
  int t = blockIdx.x * blockDim.x + threadIdx.x;
  if (t >= m * n) return;
  int a = t / n, k = t - a * n;
  int pa = perm[a];
  out[t] = S[(size_t)pa * n + k] + ((pa == k) ? 1.0f : 0.0f);
}

// Col gather + I: out[k][b] = S[k][perm[b]] + (k==perm[b])
__global__ void gatherR_k(const float* __restrict__ S, const int* __restrict__ perm,
                          int n, int m, float* __restrict__ out) {
  int t = blockIdx.x * blockDim.x + threadIdx.x;
  if (t >= n * m) return;
  int k = t / m, b = t - k * m;
  int pb = perm[b];
  out[t] = S[(size_t)k * n + pb] + ((k == pb) ? 1.0f : 0.0f);
}

// ---------------------------------------------------------------------------
// Dense propagation, split-K stage: P[z][m][c] = sum_{k in chunk z} A[m][k]*YT[c][k]
__global__ void __launch_bounds__(256) prop_stage_k(const float* __restrict__ A, const float* __restrict__ YT,
                                                    float* __restrict__ P, int M, int N, int K, int Kc) {
  __shared__ float red[4][4][64];
  int tid = threadIdx.x, wid = tid >> 6, lane = tid & 63;
  int kl = lane & 15, cg = lane >> 4;
  int m0 = (blockIdx.x * 4 + wid) * 4;
  int ncb = blockIdx.y * 64;
  int z = blockIdx.z;
  int kbeg = z * Kc, kend = kbeg + Kc;
  float acc[4][16];
#pragma unroll
  for (int r0 = 0; r0 < 4; r0++)
#pragma unroll
    for (int c = 0; c < 16; c++) acc[r0][c] = 0.f;

  for (int k0 = kbeg; k0 < kend; k0 += 64) {
    float4 a4[4];
#pragma unroll
    for (int r0 = 0; r0 < 4; r0++)
      a4[r0] = *(const float4*)(A + (size_t)(m0 + r0) * K + k0 + kl * 4);
#pragma unroll
    for (int c = 0; c < 16; c++) {
      int cc = ncb + cg * 16 + c;
      float4 y4 = *(const float4*)(YT + (size_t)cc * K + k0 + kl * 4);
#pragma unroll
      for (int r0 = 0; r0 < 4; r0++) {
        acc[r0][c] += a4[r0].x * y4.x;
        acc[r0][c] += a4[r0].y * y4.y;
        acc[r0][c] += a4[r0].z * y4.z;
        acc[r0][c] += a4[r0].w * y4.w;
      }
    }
  }
#pragma unroll
  for (int m = 1; m <= 8; m <<= 1)
#pragma unroll
    for (int r0 = 0; r0 < 4; r0++)
#pragma unroll
      for (int c = 0; c < 16; c++)
        acc[r0][c] += __shfl_xor(acc[r0][c], m, 64);
  if (kl == 0) {
#pragma unroll
    for (int r0 = 0; r0 < 4; r0++)
#pragma unroll
      for (int c = 0; c < 16; c++) red[wid][r0][cg * 16 + c] = acc[r0][c];
  }
  __syncthreads();
  int cc = ncb + lane;
#pragma unroll
  for (int r0 = 0; r0 < 4; r0++)
    P[((size_t)z * M + (m0 + r0)) * N + cc] = red[wid][r0][lane];
}

// Reduce split-K partials + GCN epilogue.
__global__ void propred_k(const float* __restrict__ P, const float* __restrict__ YT,
                          float* __restrict__ C, int M, int N, int K, int KS,
                          const float* __restrict__ dinv, const float* __restrict__ fixv,
                          const float* __restrict__ bias, int relu) {
  int t = blockIdx.x * blockDim.x + threadIdx.x;
  if (t >= M * N) return;
  int row = t / N, c = t - row * N;
  float s = 0.f;
  for (int z = 0; z < KS; z++) s += P[((size_t)z * M + row) * N + c];
  s += fixv[row] * YT[(size_t)c * K + row];
  s = s * dinv[row] + bias[c];
  if (relu) s = fmaxf(s, 0.f);
  C[t] = s;
}

// ---------------------------------------------------------------------------
// TopK pooling: scores (norm fused, zeroes rcnt), parallel counting-rank, gather.
__global__ void __launch_bounds__(256) score_k(const float* __restrict__ x, const float* __restrict__ w,
                                               int n, int c, float* __restrict__ s,
                                               int* __restrict__ rcnt) {
  __shared__ float ws[256];
  __shared__ float red[256];
  __shared__ float nrm;
  int tid = threadIdx.x;
  float t = (tid < c) ? w[tid] : 0.f;
  ws[tid] = t;
  red[tid] = t * t;
  __syncthreads();
  for (int d = 128; d > 0; d >>= 1) {
    if (tid < d) red[tid] += red[tid + d];
    __syncthreads();
  }
  if (tid == 0) nrm = sqrtf(red[0]);
  __syncthreads();
  int i = blockIdx.x * 256 + tid;
  if (i >= n) return;
  rcnt[i] = 0;
  const float* xr = x + (size_t)i * c;
  float d = 0.f;
  for (int k = 0; k < c; k++) d += xr[k] * ws[k];
  s[i] = tanhf(d / nrm);
}

// Partial rank counts: rcnt[i] += #{j in chunk : s_j > s_i || (s_j==s_i && j<i)}.
__global__ void __launch_bounds__(256) rankcnt_k(const float* __restrict__ scores, int n,
                                                 int* __restrict__ rcnt) {
  __shared__ float sj[256];
  int tid = threadIdx.x;
  int i = blockIdx.x * 256 + tid;
  int j0 = blockIdx.y * 256;
  sj[tid] = scores[j0 + tid];
  float si = scores[i];
  __syncthreads();
  int cnt = 0;
#pragma unroll 8
  for (int t = 0; t < 256; t++) {
    float s = sj[t];
    cnt += (s > si) || (s == si && (j0 + t) < i);
  }
  if (cnt) atomicAdd(&rcnt[i], cnt);
}

__global__ void rankfin_k(const float* __restrict__ scores, const int* __restrict__ rcnt,
                          int n, int keep, int* __restrict__ perm, float* __restrict__ vals,
                          int* __restrict__ rankL) {
  int i = blockIdx.x * blockDim.x + threadIdx.x;
  if (i >= n) return;
  int r = rcnt[i];
  if (r < keep) { perm[r] = i; vals[r] = scores[i]; rankL[i] = r; }
  else rankL[i] = -1;
}

__global__ void poolx_k(const float* __restrict__ x, const int* __restrict__ perm,
                        const float* __restrict__ vals, int keep, int c, float* __restrict__ out) {
  int t = blockIdx.x * blockDim.x + threadIdx.x;
  if (t >= keep * c) return;
  int a = t / c, j = t - a * c;
  out[t] = x[(size_t)perm[a] * c + j] * vals[a];
}

// ---------------------------------------------------------------------------
// Fused unpool+concat: cat[i] = [res[i], rank[i]>=0 ? cur[rank[i]][:c] : 0]
__global__ void catfull_k(const float* __restrict__ res, const float* __restrict__ cur,
                          const int* __restrict__ rankL, int n, int c, int cw,
                          float* __restrict__ cat) {
  int t = blockIdx.x * blockDim.x + threadIdx.x;
  if (t >= n * 2 * c) return;
  int i = t / (2 * c), j = t - i * 2 * c;
  if (j < c) cat[t] = res[(size_t)i * c + j];
  else {
    int rr = rankL[i];
    cat[t] = (rr >= 0) ? cur[(size_t)rr * cw + (j - c)] : 0.f;
  }
}

__global__ void softmax_k(const float* __restrict__ z, float* __restrict__ out, int n, int c) {
  int i = blockIdx.x * blockDim.x + threadIdx.x;
  if (i >= n) return;
  const float* zr = z + (size_t)i * c;
  float m = zr[0];
  for (int j = 1; j < c; j++) m = fmaxf(m, zr[j]);
  float e[64];
  float s = 0.f;
  for (int j = 0; j < c; j++) { e[j] = expf(zr[j] - m); s += e[j]; }
  for (int j = 0; j < c; j++) out[(size_t)i * c + j] = e[j] / s;
}

// ---------------------------------------------------------------------------
extern "C" void kernel_launch(void* const* d_in, const int* in_sizes, int n_in,
                              void* d_out, int out_size, void* d_ws, size_t ws_size,
                              hipStream_t stream) {
  (void)n_in; (void)out_size; (void)ws_size;
  const float* xin = (const float*)d_in[0];
  const int* ei = (const int*)d_in[1];
  const int E = in_sizes[1] / 2;
  const int* esrc = ei;
  const int* edst = ei + E;
  const float* Wd[5] = {(const float*)d_in[2], (const float*)d_in[4], (const float*)d_in[6],
                        (const float*)d_in[8], (const float*)d_in[10]};
  const float* bd[5] = {(const float*)d_in[3], (const float*)d_in[5], (const float*)d_in[7],
                        (const float*)d_in[9], (const float*)d_in[11]};
  const float* pw[4] = {(const float*)d_in[12], (const float*)d_in[13],
                        (const float*)d_in[14], (const float*)d_in[15]};
  const float* Wu[4] = {(const float*)d_in[16], (const float*)d_in[18],
                        (const float*)d_in[20], (const float*)d_in[22]};
  const float* bu[4] = {(const float*)d_in[17], (const float*)d_in[19],
                        (const float*)d_in[21], (const float*)d_in[23]};
  const float* Wo = (const float*)d_in[24];
  const float* bo = (const float*)d_in[25];
  float* out = (float*)d_out;

  char* p = (char*)d_ws;
  auto bumpf = [&](size_t ne) -> float* { float* r = (float*)p; p += ((ne * 4 + 255) & ~(size_t)255); return r; };
  auto bumpi = [&](size_t ne) -> int* { int* r = (int*)p; p += ((ne * 4 + 255) & ~(size_t)255); return r; };

  float* A1 = bumpf((size_t)2048 * 2048);
  float* A2 = bumpf((size_t)1024 * 1024);
  float* A3 = bumpf((size_t)512 * 512);
  float* A4 = bumpf((size_t)256 * 256);
  float* WS1 = bumpf((size_t)8 * 1024 * 1024);   // Pbuf for prop split-K (32MB)
  float* WS2 = bumpf((size_t)8 * 1024 * 1024);   // BLf2|BRf2|A1T ; BLf34|BRf34
  float* Pbuf2 = bumpf((size_t)4 * 1024 * 1024); // sgemm split-K partials (16MB)
  float* y = bumpf((size_t)4096 * 64);
  float* YT = bumpf((size_t)4096 * 64);
  float* XS0 = bumpf((size_t)4096 * 32);
  float* XS1 = bumpf((size_t)2048 * 64);
  float* XS2 = bumpf((size_t)1024 * 128);
  float* XS3 = bumpf((size_t)512 * 256);
  float* XA = bumpf((size_t)4096 * 64);
  float* XB = bumpf((size_t)4096 * 32);
  float* scores = bumpf(4096);
  float* vals = bumpf(2048);
  float* dinvL[5];
  float* fixvL[5];
  int nsz[5] = {4096, 2048, 1024, 512, 256};
  for (int i = 0; i < 5; i++) { dinvL[i] = bumpf(nsz[i]); fixvL[i] = bumpf(nsz[i]); }
  int* perm1 = bumpi(2048);
  int* perm2 = bumpi(1024);
  int* perm3 = bumpi(512);
  int* perm4 = bumpi(256);
  int* rank1 = bumpi(4096);
  int* rank2 = bumpi(2048);
  int* rank3 = bumpi(1024);
  int* rank4 = bumpi(512);
  // contiguous zero-init block: cnt | selfc | outcnt | fill | outfill  (5 x 16KB)
  int* cnt = bumpi(4096);
  int* selfc = bumpi(4096);
  int* outcnt = bumpi(4096);
  int* fill = bumpi(4096);
  int* outfill = bumpi(4096);
  int* offb = bumpi(4100);
  int* outoff = bumpi(4100);
  int* rcnt = bumpi(4096);
  int* bys = bumpi((size_t)E);
  int* outbys = bumpi((size_t)E);

  float* Pbuf = WS1;
  float* BLf2 = WS2;                                   // 1024x2048 = 8MB
  float* BRf2 = WS2 + (size_t)2 * 1024 * 1024;         // 8MB
  float* A1T = WS2 + (size_t)4 * 1024 * 1024;          // 16MB
  float* BLf34 = WS2;                                  // <=2MB
  float* BRf34 = WS2 + (size_t)1024 * 1024;            // <=2MB

  // Split-K fp32 GEMM: partials into Pbuf2, deterministic reduce + epilogue.
  auto sgemm = [&](const float* L, const float* R, float* C, int M, int N, int K,
                   const float* di, const float* bi, int relu, int transC, int ldc) {
    int gx = (N + 63) / 64, tn = 64;
    if (N <= 32) { gx = (N + 31) / 32; tn = 32; }
    int gy = M / 64;
    int KS = K / 16; if (KS > 16) KS = 16;
    while (KS > 1 && gx * gy * KS > 1024) KS >>= 1;
    int Kc = K / KS;
    if (KS == 1) {
      dim3 g(gx, gy);
      if (tn == 32) sgemm_k<32><<<g, dim3(256), 0, stream>>>(L, R, C, M, N, K, di, bi, relu, transC, ldc, nullptr, K);
      else sgemm_k<64><<<g, dim3(256), 0, stream>>>(L, R, C, M, N, K, di, bi, relu, transC, ldc, nullptr, K);
    } else {
      dim3 g(gx, gy, KS);
      if (tn == 32) sgemm_k<32><<<g, dim3(256), 0, stream>>>(L, R, C, M, N, K, nullptr, nullptr, 0, 0, 0, Pbuf2, Kc);
      else sgemm_k<64><<<g, dim3(256), 0, stream>>>(L, R, C, M, N, K, nullptr, nullptr, 0, 0, 0, Pbuf2, Kc);
      sgemmred_k<<<dim3((M * N + WG - 1) / WG), dim3(WG), 0, stream>>>(
          Pbuf2, C, M, N, KS, di, bi, relu, transC, ldc);
    }
  };
  auto gcn_dense = [&](const float* A, int n, const float* x, int cin, const float* W, int cout,
                       const float* bi, int relu, float* zout, const float* di, const float* fx,
                       int Kc, int KS) {
    sgemm(x, W, YT, n, cout, cin, di, nullptr, 0, 1, n);  // YT[cout][n] = (di .* xW)^T
    dim3 g(n / 16, cout / 64, KS);
    prop_stage_k<<<g, dim3(256), 0, stream>>>(A, YT, Pbuf, n, cout, n, Kc);
    propred_k<<<dim3((n * cout + WG - 1) / WG), dim3(WG), 0, stream>>>(
        Pbuf, YT, zout, n, cout, n, KS, di, fx, bi, relu);
  };
  auto pool = [&](const float* x, int n, int c, const float* w, int* perm, int* rankL, float* xout) {
    score_k<<<dim3(n / 256), dim3(256), 0, stream>>>(x, w, n, c, scores, rcnt);
    rankcnt_k<<<dim3(n / 256, n / 256), dim3(256), 0, stream>>>(scores, n, rcnt);
    rankfin_k<<<dim3(n / 256), dim3(256), 0, stream>>>(scores, rcnt, n, n / 2, perm, vals, rankL);
    int keep = n / 2;
    poolx_k<<<dim3((keep * c + WG - 1) / WG), dim3(WG), 0, stream>>>(x, perm, vals, keep, c, xout);
  };

  // ---- CSR build (one memset covers cnt/selfc/outcnt/fill/outfill) ----
  hipMemsetAsync(cnt, 0, 5 * 4096 * 4, stream);
  edgestats2_k<<<dim3((E + WG - 1) / WG), dim3(WG), 0, stream>>>(esrc, edst, cnt, selfc, outcnt, E);
  exscan_k<<<dim3(1), dim3(1024), 0, stream>>>(cnt, offb);
  scatterd_k<<<dim3((E + WG - 1) / WG), dim3(WG), 0, stream>>>(esrc, edst, offb, fill, bys, E);
  finalize0_k<<<dim3(16), dim3(WG), 0, stream>>>(cnt, selfc, dinvL[0], fixvL[0], 4096);
  exscan_k<<<dim3(1), dim3(1024), 0, stream>>>(outcnt, outoff);
  outscatter_k<<<dim3((E + WG - 1) / WG), dim3(WG), 0, stream>>>(esrc, edst, outoff, outfill, outbys, E);

  // ---- GCN0 (sparse A0) ----
  sgemm(xin, Wd[0], y, 4096, 32, 128, dinvL[0], nullptr, 0, 0, 0);
  spmv_k<1><<<dim3(1024), dim3(256), 0, stream>>>(offb, bys, y, 32, dinvL[0], fixvL[0], bd[0], 1, XS0);

  // ---- pool1 + aug1 (sparse edge-join SpGEMM, exact integers) ----
  pool(XS0, 4096, 32, pw[0], perm1, rank1, XA);
  hipMemsetAsync(A1, 0, (size_t)2048 * 2048 * 4, stream);
  pairs_k<<<dim3((E + WG - 1) / WG), dim3(WG), 0, stream>>>(esrc, edst, outoff, outbys, rank1, A1, E, 2048);
  dbl_k<<<dim3((E + WG - 1) / WG), dim3(WG), 0, stream>>>(esrc, edst, rank1, A1, E, 2048);
  rowsum_k<<<dim3(2048), dim3(WG), 0, stream>>>(A1, 2048, dinvL[1], fixvL[1]);
  gcn_dense(A1, 2048, XA, 32, Wd[1], 64, bd[1], 1, XS1, dinvL[1], fixvL[1], 256, 8);

  // ---- level 2: pool, bf16-MFMA split-K augment (exact), GCN ----
  pool(XS1, 2048, 64, pw[1], perm2, rank2, XA);
  transpose_k<<<dim3(64, 64), dim3(32, 8), 0, stream>>>(A1, A1T, 2048);
  gatherL_k<<<dim3((1024 * 2048 + WG - 1) / WG), dim3(WG), 0, stream>>>(A1, perm2, 2048, 1024, BLf2);
  gatherL_k<<<dim3((1024 * 2048 + WG - 1) / WG), dim3(WG), 0, stream>>>(A1T, perm2, 2048, 1024, BRf2);
  mfma_nt_k<<<dim3(8, 8, 8), dim3(256), 0, stream>>>(BLf2, BRf2, Pbuf, 1024, 1024, 2048, 256);
  mfred_k<<<dim3((1024 * 1024 + WG - 1) / WG), dim3(WG), 0, stream>>>(Pbuf, A2, 1024 * 1024, 8);
  rowsum_k<<<dim3(1024), dim3(WG), 0, stream>>>(A2, 1024, dinvL[2], fixvL[2]);
  gcn_dense(A2, 1024, XA, 64, Wd[2], 128, bd[2], 1, XS2, dinvL[2], fixvL[2], 128, 8);

  // ---- level 3 (fp32 augment: values exceed bf16-exact range) ----
  pool(XS2, 1024, 128, pw[2], perm3, rank3, XA);
  gatherL_k<<<dim3((512 * 1024 + WG - 1) / WG), dim3(WG), 0, stream>>>(A2, perm3, 1024, 512, BLf34);
  gatherR_k<<<dim3((1024 * 512 + WG - 1) / WG), dim3(WG), 0, stream>>>(A2, perm3, 1024, 512, BRf34);
  sgemm(BLf34, BRf34, A3, 512, 512, 1024, nullptr, nullptr, 0, 0, 0);
  rowsum_k<<<dim3(512), dim3(WG), 0, stream>>>(A3, 512, dinvL[3], fixvL[3]);
  gcn_dense(A3, 512, XA, 128, Wd[3], 256, bd[3], 1, XS3, dinvL[3], fixvL[3], 64, 8);

  // ---- level 4 ----
  pool(XS3, 512, 256, pw[3], perm4, rank4, XA);
  gatherL_k<<<dim3((256 * 512 + WG - 1) / WG), dim3(WG), 0, stream>>>(A3, perm4, 512, 256, BLf34);
  gatherR_k<<<dim3((512 * 256 + WG - 1) / WG), dim3(WG), 0, stream>>>(A3, perm4, 512, 256, BRf34);
  sgemm(BLf34, BRf34, A4, 256, 256, 512, nullptr, nullptr, 0, 0, 0);
  rowsum_k<<<dim3(256), dim3(WG), 0, stream>>>(A4, 256, dinvL[4], fixvL[4]);
  gcn_dense(A4, 256, XA, 256, Wd[4], 512, bd[4], 1, XB, dinvL[4], fixvL[4], 64, 4);

  // ---- up path (fused unpool-concat via saved rank arrays) ----
  catfull_k<<<dim3((512 * 512 + WG - 1) / WG), dim3(WG), 0, stream>>>(XS3, XB, rank4, 512, 256, 512, XA);
  gcn_dense(A3, 512, XA, 512, Wu[0], 256, bu[0], 1, XB, dinvL[3], fixvL[3], 64, 8);

  catfull_k<<<dim3((1024 * 256 + WG - 1) / WG), dim3(WG), 0, stream>>>(XS2, XB, rank3, 1024, 128, 256, XA);
  gcn_dense(A2, 1024, XA, 256, Wu[1], 128, bu[1], 1, XB, dinvL[2], fixvL[2], 128, 8);

  catfull_k<<<dim3((2048 * 128 + WG - 1) / WG), dim3(WG), 0, stream>>>(XS1, XB, rank2, 2048, 64, 128, XA);
  gcn_dense(A1, 2048, XA, 128, Wu[2], 64, bu[2], 1, XB, dinvL[1], fixvL[1], 256, 8);

  catfull_k<<<dim3((4096 * 64 + WG - 1) / WG), dim3(WG), 0, stream>>>(XS0, XB, rank1, 4096, 32, 64, XA);
  sgemm(XA, Wu[3], y, 4096, 32, 64, dinvL[0], nullptr, 0, 0, 0);
  spmv_k<1><<<dim3(1024), dim3(256), 0, stream>>>(offb, bys, y, 32, dinvL[0], fixvL[0], bu[3], 0, XB);

  // ---- final GCN (sparse A0) + softmax ----
  sgemm(XB, Wo, y, 4096, 37, 32, dinvL[0], nullptr, 0, 0, 0);
  spmv_k<0><<<dim3(1024), dim3(256), 0, stream>>>(offb, bys, y, 37, dinvL[0], fixvL[0], bo, 0, XA);
  softmax_k<<<dim3((4096 + WG - 1) / WG), dim3(WG), 0, stream>>>(XA, out, 4096, 37);
}

// Round 7
// 655.783 us; speedup vs baseline: 3.7791x; 1.1177x over previous
//
#include <hip/hip_runtime.h>
#include <math.h>
#include <stddef.h>

#define WG 256

typedef short short8_t __attribute__((ext_vector_type(8)));
typedef float f32x4_t __attribute__((ext_vector_type(4)));

// ---------------------------------------------------------------------------
// One pass over edges: in-degree (incl self) + self-edge count.
__global__ void edgestats_k(const int* __restrict__ esrc, const int* __restrict__ edst,
                            int* __restrict__ cnt, int* __restrict__ selfc, int E) {
  int e = blockIdx.x * blockDim.x + threadIdx.x;
  if (e >= E) return;
  int s = esrc[e], d = edst[e];
  atomicAdd(&cnt[d], 1);
  if (s == d) atomicAdd(&selfc[d], 1);
}

__global__ void finalize0_k(const int* __restrict__ cnt, const int* __restrict__ selfc,
                            float* __restrict__ dinv, float* __restrict__ fixv, int n) {
  int i = blockIdx.x * blockDim.x + threadIdx.x;
  if (i >= n) return;
  float fx = (selfc[i] == 0) ? 2.0f : 0.0f;
  float deg = (float)cnt[i] + fx;
  dinv[i] = (deg > 0.f) ? 1.0f / sqrtf(deg) : 0.f;
  fixv[i] = fx;
}

__global__ void __launch_bounds__(1024) exscan_k(const int* __restrict__ cnt, int* __restrict__ off) {
  __shared__ int part[1024];
  int t = threadIdx.x;
  int l0 = cnt[t * 4], l1 = cnt[t * 4 + 1], l2 = cnt[t * 4 + 2], l3 = cnt[t * 4 + 3];
  int s = l0 + l1 + l2 + l3;
  part[t] = s;
  __syncthreads();
  for (int d = 1; d < 1024; d <<= 1) {
    int v = part[t];
    int u = (t >= d) ? part[t - d] : 0;
    __syncthreads();
    part[t] = v + u;
    __syncthreads();
  }
  int ex = (t > 0) ? part[t - 1] : 0;
  off[t * 4] = ex;
  off[t * 4 + 1] = ex + l0;
  off[t * 4 + 2] = ex + l0 + l1;
  off[t * 4 + 3] = ex + l0 + l1 + l2;
  if (t == 1023) off[4096] = part[1023];
}

// in-CSR (by dst, incl self) for SpMV and the aug1 row join
__global__ void scatterd_k(const int* __restrict__ esrc, const int* __restrict__ edst,
                           const int* __restrict__ off, int* __restrict__ fill,
                           int* __restrict__ bys, int E) {
  int e = blockIdx.x * blockDim.x + threadIdx.x;
  if (e >= E) return;
  int d = edst[e];
  int p = off[d] + atomicAdd(&fill[d], 1);
  bys[p] = esrc[e];
}

// SpMV: Z[d][c] = dinv[d]*(sum_{e:dst=d} y[src_e][c] + fixv[d]*y[d][c]) + bias[c]
template<int SMALL>
__global__ void __launch_bounds__(256) spmv_k(const int* __restrict__ off, const int* __restrict__ bys,
                                              const float* __restrict__ y, int N,
                                              const float* __restrict__ dinv, const float* __restrict__ fixv,
                                              const float* __restrict__ bias, int relu,
                                              float* __restrict__ Z) {
  int w = threadIdx.x >> 6, l = threadIdx.x & 63;
  int row = blockIdx.x * 4 + w;
  int b0 = off[row], b1 = off[row + 1];
  if (SMALL) {  // N == 32
    int c = l & 31, eh = l >> 5;
    float acc = 0.f;
    for (int e = b0 + eh; e < b1; e += 2) { int s = bys[e]; acc += y[(size_t)s * N + c]; }
    acc += __shfl_xor(acc, 32, 64);
    if (eh == 0) {
      float v = acc + fixv[row] * y[(size_t)row * N + c];
      v = v * dinv[row] + (bias ? bias[c] : 0.f);
      if (relu) v = fmaxf(v, 0.f);
      Z[(size_t)row * N + c] = v;
    }
  } else {
    bool act = l < N;
    float acc = 0.f;
    for (int e = b0; e < b1; e++) { int s = bys[e]; if (act) acc += y[(size_t)s * N + l]; }
    if (act) {
      float v = acc + fixv[row] * y[(size_t)row * N + l];
      v = v * dinv[row] + (bias ? bias[l] : 0.f);
      if (relu) v = fmaxf(v, 0.f);
      Z[(size_t)row * N + l] = v;
    }
  }
}

// ---------------------------------------------------------------------------
// aug1, row-centric: for kept row d (rank rd), accumulate in LDS:
//   row[rank(j)] += #paths j->k->d (k,j over in-edge instances, excl self)
//   row[rank(j)] += 2 per in-edge instance j->d (excl self)
// zero diag, write coalesced, fused rowsum -> dinv/fixv. All addends exact
// small ints in fp32 -> LDS atomic order irrelevant (deterministic).
__global__ void __launch_bounds__(256) aug1row_k(
    const int* __restrict__ off, const int* __restrict__ bys,
    const int* __restrict__ perm, const int* __restrict__ rank1,
    float* __restrict__ A1, int m,
    float* __restrict__ dinv, float* __restrict__ fixv) {
  __shared__ float row[2048];
  __shared__ float red[WG];
  int tid = threadIdx.x;
  int rd = blockIdx.x;
  int d = perm[rd];
  for (int i = tid; i < m; i += WG) row[i] = 0.f;
  __syncthreads();
  int b0 = off[d], b1 = off[d + 1];
  int wave = tid >> 6, lane = tid & 63;
  for (int e = b0 + wave; e < b1; e += 4) {
    int k = bys[e];
    if (k == d) continue;
    int o0 = off[k], o1 = off[k + 1];
    for (int t = o0 + lane; t < o1; t += 64) {
      int j = bys[t];
      if (j == k) continue;
      int rj = rank1[j];
      if (rj >= 0) atomicAdd(&row[rj], 1.0f);
    }
  }
  for (int e = b0 + tid; e < b1; e += WG) {
    int j = bys[e];
    if (j == d) continue;
    int rj = rank1[j];
    if (rj >= 0) atomicAdd(&row[rj], 2.0f);
  }
  __syncthreads();
  if (tid == 0) row[rd] = 0.f;
  __syncthreads();
  float s = 0.f;
  float* Ar = A1 + (size_t)rd * m;
  for (int i = tid; i < m; i += WG) { float v = row[i]; s += v; Ar[i] = v; }
  red[tid] = s;
  __syncthreads();
  for (int dd = WG / 2; dd > 0; dd >>= 1) {
    if (tid < dd) red[tid] += red[tid + dd];
    __syncthreads();
  }
  if (tid == 0) {
    dinv[rd] = 1.0f / sqrtf(red[0] + 2.0f);
    fixv[rd] = 2.0f;
  }
}

// ---------------------------------------------------------------------------
// Augmented-A normalization: zero diag in place, deg = offdiag rowsum + 2, fix=2.
__global__ void rowsum_k(float* __restrict__ A, int n,
                         float* __restrict__ dinv, float* __restrict__ fixv) {
  __shared__ float red[WG];
  int row = blockIdx.x;
  float* Ar = A + (size_t)row * n;
  float s = 0.f;
  for (int j = threadIdx.x; j < n; j += WG) {
    if (j == row) Ar[j] = 0.f;
    else s += Ar[j];
  }
  red[threadIdx.x] = s;
  __syncthreads();
  for (int d = WG / 2; d > 0; d >>= 1) {
    if ((int)threadIdx.x < d) red[threadIdx.x] += red[threadIdx.x + d];
    __syncthreads();
  }
  if (threadIdx.x == 0) {
    float deg = red[0] + 2.0f;
    dinv[row] = 1.0f / sqrtf(deg);
    fixv[row] = 2.0f;
  }
}

// ---------------------------------------------------------------------------
// fp32 SGEMM: C = L(MxK)@R(KxN). Fused mode (P==null): row scale/bias/relu,
// optional transposed store. Split-K mode (P!=null): blockIdx.z selects a
// Kc-chunk, raw partials to P[z]; epilogue deferred to sgemmred_k.
template<int TNv>
__global__ void __launch_bounds__(256) sgemm_k(
    const float* __restrict__ L, const float* __restrict__ R, float* __restrict__ C,
    int M, int N, int K,
    const float* __restrict__ dinv, const float* __restrict__ bias, int relu,
    int transC, int ldc, float* __restrict__ P, int Kc) {
  const int MN = TNv / 16;
  __shared__ float Ls[16][68];
  __shared__ float Rs[16][TNv];
  int tid = threadIdx.x;
  int tx = tid & 15, ty = tid >> 4;
  int m0 = blockIdx.y * 64;
  int n0 = blockIdx.x * TNv;
  int kbeg = 0, kend = K;
  if (P) { kbeg = blockIdx.z * Kc; kend = kbeg + Kc; }
  float acc[4][MN];
#pragma unroll
  for (int i = 0; i < 4; i++)
#pragma unroll
    for (int j = 0; j < MN; j++) acc[i][j] = 0.f;

  int lk = tid & 15, lm = tid >> 4;
  int rn = tid % TNv, rk = tid / TNv;
  const int KS = 256 / TNv;

  for (int kt = kbeg; kt < kend; kt += 16) {
#pragma unroll
    for (int r = 0; r < 4; r++) {
      int m = lm + r * 16;
      Ls[lk][m] = L[(size_t)(m0 + m) * K + kt + lk];
    }
#pragma unroll
    for (int r = 0; r < 16 / KS; r++) {
      int k = rk + r * KS;
      int gn = n0 + rn;
      Rs[k][rn] = (gn < N) ? R[(size_t)(kt + k) * N + gn] : 0.f;
    }
    __syncthreads();
#pragma unroll
    for (int k = 0; k < 16; k++) {
      float a[4], b[MN];
#pragma unroll
      for (int i = 0; i < 4; i++) a[i] = Ls[k][ty * 4 + i];
#pragma unroll
      for (int j = 0; j < MN; j++) b[j] = Rs[k][tx * MN + j];
#pragma unroll
      for (int i = 0; i < 4; i++)
#pragma unroll
        for (int j = 0; j < MN; j++) acc[i][j] += a[i] * b[j];
    }
    __syncthreads();
  }
  if (P) {
    float* Pz = P + (size_t)blockIdx.z * M * N;
#pragma unroll
    for (int i = 0; i < 4; i++) {
      int gi = m0 + ty * 4 + i;
#pragma unroll
      for (int j = 0; j < MN; j++) {
        int gj = n0 + tx * MN + j;
        if (gj < N) Pz[(size_t)gi * N + gj] = acc[i][j];
      }
    }
    return;
  }
#pragma unroll
  for (int i = 0; i < 4; i++) {
    int gi = m0 + ty * 4 + i;
#pragma unroll
    for (int j = 0; j < MN; j++) {
      int gj = n0 + tx * MN + j;
      if (gj < N) {
        float v = acc[i][j];
        if (dinv) v *= dinv[gi];
        if (bias) v += bias[gj];
        if (relu) v = fmaxf(v, 0.f);
        if (transC) C[(size_t)gj * ldc + gi] = v;
        else C[(size_t)gi * N + gj] = v;
      }
    }
  }
}

// Deterministic fixed-order split-K reduce + epilogue.
__global__ void sgemmred_k(const float* __restrict__ P, float* __restrict__ C,
                           int M, int N, int KS,
                           const float* __restrict__ dinv, const float* __restrict__ bias,
                           int relu, int transC, int ldc) {
  int t = blockIdx.x * blockDim.x + threadIdx.x;
  if (t >= M * N) return;
  int i = t / N, j = t - i * N;
  float s = 0.f;
  for (int z = 0; z < KS; z++) s += P[(size_t)z * M * N + t];
  if (dinv) s *= dinv[i];
  if (bias) s += bias[j];
  if (relu) s = fmaxf(s, 0.f);
  if (transC) C[(size_t)j * ldc + i] = s;
  else C[t] = s;
}

// ---------------------------------------------------------------------------
// bf16 MFMA NT GEMM, split-K: P[z] = A(Mx[kbeg,kend)) @ B^T ; exact small ints.
__global__ void __launch_bounds__(256) mfma_nt_k(const float* __restrict__ A, const float* __restrict__ B,
                                                 float* __restrict__ P, int M, int N, int lda, int Kc) {
  __shared__ short As[128 * 32];
  __shared__ short Bs[128 * 32];
  int tid = threadIdx.x;
  int w = tid >> 6, l = tid & 63;
  int wy = w >> 1, wx = w & 1;
  int q = l >> 4, r = l & 15;
  int m0 = blockIdx.y * 128, n0 = blockIdx.x * 128;
  int kbeg = blockIdx.z * Kc;
  float* C = P + (size_t)blockIdx.z * M * N;
  f32x4_t acc[4][4];
#pragma unroll
  for (int i = 0; i < 4; i++)
#pragma unroll
    for (int j = 0; j < 4; j++) acc[i][j] = (f32x4_t){0.f, 0.f, 0.f, 0.f};

  int srow = tid & 127, scp = tid >> 7;
  const float* Ag = A + (size_t)(m0 + srow) * lda + scp * 16 + kbeg;
  const float* Bg = B + (size_t)(n0 + srow) * lda + scp * 16 + kbeg;
  int g = srow >> 4, rr = srow & 15;
  int d0 = ((g * 4 + scp * 2) * 16 + rr) * 8;
  int d1 = ((g * 4 + scp * 2 + 1) * 16 + rr) * 8;

  for (int kt = 0; kt < Kc; kt += 32) {
    float4 a0 = *(const float4*)(Ag + kt), a1 = *(const float4*)(Ag + kt + 4);
    float4 a2 = *(const float4*)(Ag + kt + 8), a3 = *(const float4*)(Ag + kt + 12);
    float4 b0 = *(const float4*)(Bg + kt), b1 = *(const float4*)(Bg + kt + 4);
    float4 b2 = *(const float4*)(Bg + kt + 8), b3 = *(const float4*)(Bg + kt + 12);
    __syncthreads();
    short8_t sa, sb;
    sa[0] = (short)(__float_as_uint(a0.x) >> 16); sa[1] = (short)(__float_as_uint(a0.y) >> 16);
    sa[2] = (short)(__float_as_uint(a0.z) >> 16); sa[3] = (short)(__float_as_uint(a0.w) >> 16);
    sa[4] = (short)(__float_as_uint(a1.x) >> 16); sa[5] = (short)(__float_as_uint(a1.y) >> 16);
    sa[6] = (short)(__float_as_uint(a1.z) >> 16); sa[7] = (short)(__float_as_uint(a1.w) >> 16);
    *(short8_t*)&As[d0] = sa;
    sa[0] = (short)(__float_as_uint(a2.x) >> 16); sa[1] = (short)(__float_as_uint(a2.y) >> 16);
    sa[2] = (short)(__float_as_uint(a2.z) >> 16); sa[3] = (short)(__float_as_uint(a2.w) >> 16);
    sa[4] = (short)(__float_as_uint(a3.x) >> 16); sa[5] = (short)(__float_as_uint(a3.y) >> 16);
    sa[6] = (short)(__float_as_uint(a3.z) >> 16); sa[7] = (short)(__float_as_uint(a3.w) >> 16);
    *(short8_t*)&As[d1] = sa;
    sb[0] = (short)(__float_as_uint(b0.x) >> 16); sb[1] = (short)(__float_as_uint(b0.y) >> 16);
    sb[2] = (short)(__float_as_uint(b0.z) >> 16); sb[3] = (short)(__float_as_uint(b0.w) >> 16);
    sb[4] = (short)(__float_as_uint(b1.x) >> 16); sb[5] = (short)(__float_as_uint(b1.y) >> 16);
    sb[6] = (short)(__float_as_uint(b1.z) >> 16); sb[7] = (short)(__float_as_uint(b1.w) >> 16);
    *(short8_t*)&Bs[d0] = sb;
    sb[0] = (short)(__float_as_uint(b2.x) >> 16); sb[1] = (short)(__float_as_uint(b2.y) >> 16);
    sb[2] = (short)(__float_as_uint(b2.z) >> 16); sb[3] = (short)(__float_as_uint(b2.w) >> 16);
    sb[4] = (short)(__float_as_uint(b3.x) >> 16); sb[5] = (short)(__float_as_uint(b3.y) >> 16);
    sb[6] = (short)(__float_as_uint(b3.z) >> 16); sb[7] = (short)(__float_as_uint(b3.w) >> 16);
    *(short8_t*)&Bs[d1] = sb;
    __syncthreads();
    short8_t af[4], bf[4];
#pragma unroll
    for (int sm = 0; sm < 4; sm++) af[sm] = *(short8_t*)&As[(((wy * 4 + sm) * 4 + q) * 16 + r) * 8];
#pragma unroll
    for (int sn = 0; sn < 4; sn++) bf[sn] = *(short8_t*)&Bs[(((wx * 4 + sn) * 4 + q) * 16 + r) * 8];
#pragma unroll
    for (int sm = 0; sm < 4; sm++)
#pragma unroll
      for (int sn = 0; sn < 4; sn++)
        acc[sm][sn] = __builtin_amdgcn_mfma_f32_16x16x32_bf16(af[sm], bf[sn], acc[sm][sn], 0, 0, 0);
  }
#pragma unroll
  for (int sm = 0; sm < 4; sm++) {
#pragma unroll
    for (int sn = 0; sn < 4; sn++) {
      int grow = m0 + wy * 64 + sm * 16 + q * 4;
      int gcol = n0 + wx * 64 + sn * 16 + r;
#pragma unroll
      for (int v = 0; v < 4; v++) C[(size_t)(grow + v) * N + gcol] = acc[sm][sn][v];
    }
  }
}

// Row-oriented split-K reduce + zero diag + fused rowsum -> dinv/fixv.
__global__ void __launch_bounds__(256) mfredrow_k(const float* __restrict__ P, float* __restrict__ C,
                                                  int n, int KS,
                                                  float* __restrict__ dinv, float* __restrict__ fixv) {
  __shared__ float red[WG];
  int row = blockIdx.x, tid = threadIdx.x;
  float s = 0.f;
  for (int c = tid; c < n; c += WG) {
    float v = 0.f;
    size_t idx = (size_t)row * n + c;
    for (int z = 0; z < KS; z++) v += P[(size_t)z * n * n + idx];
    if (c == row) v = 0.f;
    C[idx] = v;
    s += v;
  }
  red[tid] = s;
  __syncthreads();
  for (int d = WG / 2; d > 0; d >>= 1) {
    if (tid < d) red[tid] += red[tid + d];
    __syncthreads();
  }
  if (tid == 0) {
    dinv[row] = 1.0f / sqrtf(red[0] + 2.0f);
    fixv[row] = 2.0f;
  }
}

// Tiled transpose D = S^T (n x n fp32)
__global__ void transpose_k(const float* __restrict__ S, float* __restrict__ D, int n) {
  __shared__ float tile[32][33];
  int bx = blockIdx.x * 32, by = blockIdx.y * 32;
  int tx = threadIdx.x, ty = threadIdx.y;
  for (int j = 0; j < 32; j += 8) tile[ty + j][tx] = S[(size_t)(by + ty + j) * n + bx + tx];
  __syncthreads();
  for (int j = 0; j < 32; j += 8) D[(size_t)(bx + ty + j) * n + by + tx] = tile[tx][ty + j];
}

// Row gather + I: out[a][k] = S[perm[a]][k] + (perm[a]==k)
__global__ void gatherL_k(const float* __restrict__ S, const int* __restrict__ perm,
                          int n, int m, float* __restrict__ out) {
  int t = blockIdx.x * blockDim.x + threadIdx.x;
  if (t >= m * n) return;
  int a = t / n, k = t - a * n;
  int pa = perm[a];
  out[t] = S[(size_t)pa * n + k] + ((pa == k) ? 1.0f : 0.0f);
}

// Col gather + I: out[k][b] = S[k][perm[b]] + (k==perm[b])
__global__ void gatherR_k(const float* __restrict__ S, const int* __restrict__ perm,
                          int n, int m, float* __restrict__ out) {
  int t = blockIdx.x * blockDim.x + threadIdx.x;
  if (t >= n * m) return;
  int k = t / m, b = t - k * m;
  int pb = perm[b];
  out[t] = S[(size_t)k * n + pb] + ((k == pb) ? 1.0f : 0.0f);
}

// ---------------------------------------------------------------------------
// Dense propagation, split-K stage: P[z][m][c] = sum_{k in chunk z} A[m][k]*YT[c][k]
__global__ void __launch_bounds__(256) prop_stage_k(const float* __restrict__ A, const float* __restrict__ YT,
                                                    float* __restrict__ P, int M, int N, int K, int Kc) {
  __shared__ float red[4][4][64];
  int tid = threadIdx.x, wid = tid >> 6, lane = tid & 63;
  int kl = lane & 15, cg = lane >> 4;
  int m0 = (blockIdx.x * 4 + wid) * 4;
  int ncb = blockIdx.y * 64;
  int z = blockIdx.z;
  int kbeg = z * Kc, kend = kbeg + Kc;
  float acc[4][16];
#pragma unroll
  for (int r0 = 0; r0 < 4; r0++)
#pragma unroll
    for (int c = 0; c < 16; c++) acc[r0][c] = 0.f;

  for (int k0 = kbeg; k0 < kend; k0 += 64) {
    float4 a4[4];
#pragma unroll
    for (int r0 = 0; r0 < 4; r0++)
      a4[r0] = *(const float4*)(A + (size_t)(m0 + r0) * K + k0 + kl * 4);
#pragma unroll
    for (int c = 0; c < 16; c++) {
      int cc = ncb + cg * 16 + c;
      float4 y4 = *(const float4*)(YT + (size_t)cc * K + k0 + kl * 4);
#pragma unroll
      for (int r0 = 0; r0 < 4; r0++) {
        acc[r0][c] += a4[r0].x * y4.x;
        acc[r0][c] += a4[r0].y * y4.y;
        acc[r0][c] += a4[r0].z * y4.z;
        acc[r0][c] += a4[r0].w * y4.w;
      }
    }
  }
#pragma unroll
  for (int m = 1; m <= 8; m <<= 1)
#pragma unroll
    for (int r0 = 0; r0 < 4; r0++)
#pragma unroll
      for (int c = 0; c < 16; c++)
        acc[r0][c] += __shfl_xor(acc[r0][c], m, 64);
  if (kl == 0) {
#pragma unroll
    for (int r0 = 0; r0 < 4; r0++)
#pragma unroll
      for (int c = 0; c < 16; c++) red[wid][r0][cg * 16 + c] = acc[r0][c];
  }
  __syncthreads();
  int cc = ncb + lane;
#pragma unroll
  for (int r0 = 0; r0 < 4; r0++)
    P[((size_t)z * M + (m0 + r0)) * N + cc] = red[wid][r0][lane];
}

// Reduce split-K partials + GCN epilogue.
__global__ void propred_k(const float* __restrict__ P, const float* __restrict__ YT,
                          float* __restrict__ C, int M, int N, int K, int KS,
                          const float* __restrict__ dinv, const float* __restrict__ fixv,
                          const float* __restrict__ bias, int relu) {
  int t = blockIdx.x * blockDim.x + threadIdx.x;
  if (t >= M * N) return;
  int row = t / N, c = t - row * N;
  float s = 0.f;
  for (int z = 0; z < KS; z++) s += P[((size_t)z * M + row) * N + c];
  s += fixv[row] * YT[(size_t)c * K + row];
  s = s * dinv[row] + bias[c];
  if (relu) s = fmaxf(s, 0.f);
  C[t] = s;
}

// ---------------------------------------------------------------------------
// TopK pooling: scores (norm fused, zeroes rcnt), parallel counting-rank, gather.
__global__ void __launch_bounds__(256) score_k(const float* __restrict__ x, const float* __restrict__ w,
                                               int n, int c, float* __restrict__ s,
                                               int* __restrict__ rcnt) {
  __shared__ float ws[256];
  __shared__ float red[256];
  __shared__ float nrm;
  int tid = threadIdx.x;
  float t = (tid < c) ? w[tid] : 0.f;
  ws[tid] = t;
  red[tid] = t * t;
  __syncthreads();
  for (int d = 128; d > 0; d >>= 1) {
    if (tid < d) red[tid] += red[tid + d];
    __syncthreads();
  }
  if (tid == 0) nrm = sqrtf(red[0]);
  __syncthreads();
  int i = blockIdx.x * 256 + tid;
  if (i >= n) return;
  rcnt[i] = 0;
  const float* xr = x + (size_t)i * c;
  float d = 0.f;
  for (int k = 0; k < c; k++) d += xr[k] * ws[k];
  s[i] = tanhf(d / nrm);
}

// Partial rank counts: rcnt[i] += #{j in chunk : s_j > s_i || (s_j==s_i && j<i)}.
__global__ void __launch_bounds__(256) rankcnt_k(const float* __restrict__ scores, int n,
                                                 int* __restrict__ rcnt) {
  __shared__ float sj[256];
  int tid = threadIdx.x;
  int i = blockIdx.x * 256 + tid;
  int j0 = blockIdx.y * 256;
  sj[tid] = scores[j0 + tid];
  float si = scores[i];
  __syncthreads();
  int cnt = 0;
#pragma unroll 8
  for (int t = 0; t < 256; t++) {
    float s = sj[t];
    cnt += (s > si) || (s == si && (j0 + t) < i);
  }
  if (cnt) atomicAdd(&rcnt[i], cnt);
}

__global__ void rankfin_k(const float* __restrict__ scores, const int* __restrict__ rcnt,
                          int n, int keep, int* __restrict__ perm, float* __restrict__ vals,
                          int* __restrict__ rankL) {
  int i = blockIdx.x * blockDim.x + threadIdx.x;
  if (i >= n) return;
  int r = rcnt[i];
  if (r < keep) { perm[r] = i; vals[r] = scores[i]; rankL[i] = r; }
  else rankL[i] = -1;
}

__global__ void poolx_k(const float* __restrict__ x, const int* __restrict__ perm,
                        const float* __restrict__ vals, int keep, int c, float* __restrict__ out) {
  int t = blockIdx.x * blockDim.x + threadIdx.x;
  if (t >= keep * c) return;
  int a = t / c, j = t - a * c;
  out[t] = x[(size_t)perm[a] * c + j] * vals[a];
}

// ---------------------------------------------------------------------------
// Fused unpool+concat: cat[i] = [res[i], rank[i]>=0 ? cur[rank[i]][:c] : 0]
__global__ void catfull_k(const float* __restrict__ res, const float* __restrict__ cur,
                          const int* __restrict__ rankL, int n, int c, int cw,
                          float* __restrict__ cat) {
  int t = blockIdx.x * blockDim.x + threadIdx.x;
  if (t >= n * 2 * c) return;
  int i = t / (2 * c), j = t - i * 2 * c;
  if (j < c) cat[t] = res[(size_t)i * c + j];
  else {
    int rr = rankL[i];
    cat[t] = (rr >= 0) ? cur[(size_t)rr * cw + (j - c)] : 0.f;
  }
}

__global__ void softmax_k(const float* __restrict__ z, float* __restrict__ out, int n, int c) {
  int i = blockIdx.x * blockDim.x + threadIdx.x;
  if (i >= n) return;
  const float* zr = z + (size_t)i * c;
  float m = zr[0];
  for (int j = 1; j < c; j++) m = fmaxf(m, zr[j]);
  float e[64];
  float s = 0.f;
  for (int j = 0; j < c; j++) { e[j] = expf(zr[j] - m); s += e[j]; }
  for (int j = 0; j < c; j++) out[(size_t)i * c + j] = e[j] / s;
}

// ---------------------------------------------------------------------------
extern "C" void kernel_launch(void* const* d_in, const int* in_sizes, int n_in,
                              void* d_out, int out_size, void* d_ws, size_t ws_size,
                              hipStream_t stream) {
  (void)n_in; (void)out_size; (void)ws_size;
  const float* xin = (const float*)d_in[0];
  const int* ei = (const int*)d_in[1];
  const int E = in_sizes[1] / 2;
  const int* esrc = ei;
  const int* edst = ei + E;
  const float* Wd[5] = {(const float*)d_in[2], (const float*)d_in[4], (const float*)d_in[6],
                        (const float*)d_in[8], (const float*)d_in[10]};
  const float* bd[5] = {(const float*)d_in[3], (const float*)d_in[5], (const float*)d_in[7],
                        (const float*)d_in[9], (const float*)d_in[11]};
  const float* pw[4] = {(const float*)d_in[12], (const float*)d_in[13],
                        (const float*)d_in[14], (const float*)d_in[15]};
  const float* Wu[4] = {(const float*)d_in[16], (const float*)d_in[18],
                        (const float*)d_in[20], (const float*)d_in[22]};
  const float* bu[4] = {(const float*)d_in[17], (const float*)d_in[19],
                        (const float*)d_in[21], (const float*)d_in[23]};
  const float* Wo = (const float*)d_in[24];
  const float* bo = (const float*)d_in[25];
  float* out = (float*)d_out;

  char* p = (char*)d_ws;
  auto bumpf = [&](size_t ne) -> float* { float* r = (float*)p; p += ((ne * 4 + 255) & ~(size_t)255); return r; };
  auto bumpi = [&](size_t ne) -> int* { int* r = (int*)p; p += ((ne * 4 + 255) & ~(size_t)255); return r; };

  float* A1 = bumpf((size_t)2048 * 2048);
  float* A2 = bumpf((size_t)1024 * 1024);
  float* A3 = bumpf((size_t)512 * 512);
  float* A4 = bumpf((size_t)256 * 256);
  float* WS1 = bumpf((size_t)8 * 1024 * 1024);   // Pbuf for prop split-K (32MB)
  float* WS2 = bumpf((size_t)8 * 1024 * 1024);   // BLf2|BRf2|A1T ; BLf34|BRf34
  float* Pbuf2 = bumpf((size_t)4 * 1024 * 1024); // sgemm split-K partials (16MB)
  float* y = bumpf((size_t)4096 * 64);
  float* YT = bumpf((size_t)4096 * 64);
  float* XS0 = bumpf((size_t)4096 * 32);
  float* XS1 = bumpf((size_t)2048 * 64);
  float* XS2 = bumpf((size_t)1024 * 128);
  float* XS3 = bumpf((size_t)512 * 256);
  float* XA = bumpf((size_t)4096 * 64);
  float* XB = bumpf((size_t)4096 * 32);
  float* scores = bumpf(4096);
  float* vals = bumpf(2048);
  float* dinvL[5];
  float* fixvL[5];
  int nsz[5] = {4096, 2048, 1024, 512, 256};
  for (int i = 0; i < 5; i++) { dinvL[i] = bumpf(nsz[i]); fixvL[i] = bumpf(nsz[i]); }
  int* perm1 = bumpi(2048);
  int* perm2 = bumpi(1024);
  int* perm3 = bumpi(512);
  int* perm4 = bumpi(256);
  int* rank1 = bumpi(4096);
  int* rank2 = bumpi(2048);
  int* rank3 = bumpi(1024);
  int* rank4 = bumpi(512);
  // contiguous zero-init block: cnt | selfc | fill  (3 x 16KB)
  int* cnt = bumpi(4096);
  int* selfc = bumpi(4096);
  int* fill = bumpi(4096);
  int* offb = bumpi(4100);
  int* rcnt = bumpi(4096);
  int* bys = bumpi((size_t)E);

  float* Pbuf = WS1;
  float* BLf2 = WS2;                                   // 1024x2048 = 8MB
  float* BRf2 = WS2 + (size_t)2 * 1024 * 1024;         // 8MB
  float* A1T = WS2 + (size_t)4 * 1024 * 1024;          // 16MB
  float* BLf34 = WS2;                                  // <=2MB
  float* BRf34 = WS2 + (size_t)1024 * 1024;            // <=2MB

  // Split-K fp32 GEMM: partials into Pbuf2, deterministic reduce + epilogue.
  auto sgemm = [&](const float* L, const float* R, float* C, int M, int N, int K,
                   const float* di, const float* bi, int relu, int transC, int ldc) {
    int gx = (N + 63) / 64, tn = 64;
    if (N <= 32) { gx = (N + 31) / 32; tn = 32; }
    int gy = M / 64;
    int KS = K / 16; if (KS > 16) KS = 16;
    while (KS > 1 && gx * gy * KS > 1024) KS >>= 1;
    int Kc = K / KS;
    if (KS == 1) {
      dim3 g(gx, gy);
      if (tn == 32) sgemm_k<32><<<g, dim3(256), 0, stream>>>(L, R, C, M, N, K, di, bi, relu, transC, ldc, nullptr, K);
      else sgemm_k<64><<<g, dim3(256), 0, stream>>>(L, R, C, M, N, K, di, bi, relu, transC, ldc, nullptr, K);
    } else {
      dim3 g(gx, gy, KS);
      if (tn == 32) sgemm_k<32><<<g, dim3(256), 0, stream>>>(L, R, C, M, N, K, nullptr, nullptr, 0, 0, 0, Pbuf2, Kc);
      else sgemm_k<64><<<g, dim3(256), 0, stream>>>(L, R, C, M, N, K, nullptr, nullptr, 0, 0, 0, Pbuf2, Kc);
      sgemmred_k<<<dim3((M * N + WG - 1) / WG), dim3(WG), 0, stream>>>(
          Pbuf2, C, M, N, KS, di, bi, relu, transC, ldc);
    }
  };
  auto gcn_dense = [&](const float* A, int n, const float* x, int cin, const float* W, int cout,
                       const float* bi, int relu, float* zout, const float* di, const float* fx,
                       int Kc, int KS) {
    sgemm(x, W, YT, n, cout, cin, di, nullptr, 0, 1, n);  // YT[cout][n] = (di .* xW)^T
    dim3 g(n / 16, cout / 64, KS);
    prop_stage_k<<<g, dim3(256), 0, stream>>>(A, YT, Pbuf, n, cout, n, Kc);
    propred_k<<<dim3((n * cout + WG - 1) / WG), dim3(WG), 0, stream>>>(
        Pbuf, YT, zout, n, cout, n, KS, di, fx, bi, relu);
  };
  auto pool = [&](const float* x, int n, int c, const float* w, int* perm, int* rankL, float* xout) {
    score_k<<<dim3(n / 256), dim3(256), 0, stream>>>(x, w, n, c, scores, rcnt);
    rankcnt_k<<<dim3(n / 256, n / 256), dim3(256), 0, stream>>>(scores, n, rcnt);
    rankfin_k<<<dim3(n / 256), dim3(256), 0, stream>>>(scores, rcnt, n, n / 2, perm, vals, rankL);
    int keep = n / 2;
    poolx_k<<<dim3((keep * c + WG - 1) / WG), dim3(WG), 0, stream>>>(x, perm, vals, keep, c, xout);
  };

  // ---- CSR build (one memset covers cnt/selfc/fill) ----
  hipMemsetAsync(cnt, 0, 3 * 4096 * 4, stream);
  edgestats_k<<<dim3((E + WG - 1) / WG), dim3(WG), 0, stream>>>(esrc, edst, cnt, selfc, E);
  exscan_k<<<dim3(1), dim3(1024), 0, stream>>>(cnt, offb);
  scatterd_k<<<dim3((E + WG - 1) / WG), dim3(WG), 0, stream>>>(esrc, edst, offb, fill, bys, E);
  finalize0_k<<<dim3(16), dim3(WG), 0, stream>>>(cnt, selfc, dinvL[0], fixvL[0], 4096);

  // ---- GCN0 (sparse A0) ----
  sgemm(xin, Wd[0], y, 4096, 32, 128, dinvL[0], nullptr, 0, 0, 0);
  spmv_k<1><<<dim3(1024), dim3(256), 0, stream>>>(offb, bys, y, 32, dinvL[0], fixvL[0], bd[0], 1, XS0);

  // ---- pool1 + aug1 (row-centric LDS SpGEMM, exact ints, fused rowsum) ----
  pool(XS0, 4096, 32, pw[0], perm1, rank1, XA);
  aug1row_k<<<dim3(2048), dim3(WG), 0, stream>>>(offb, bys, perm1, rank1, A1, 2048,
                                                 dinvL[1], fixvL[1]);
  gcn_dense(A1, 2048, XA, 32, Wd[1], 64, bd[1], 1, XS1, dinvL[1], fixvL[1], 256, 8);

  // ---- level 2: pool, bf16-MFMA split-K augment (exact), fused reduce+rowsum ----
  pool(XS1, 2048, 64, pw[1], perm2, rank2, XA);
  transpose_k<<<dim3(64, 64), dim3(32, 8), 0, stream>>>(A1, A1T, 2048);
  gatherL_k<<<dim3((1024 * 2048 + WG - 1) / WG), dim3(WG), 0, stream>>>(A1, perm2, 2048, 1024, BLf2);
  gatherL_k<<<dim3((1024 * 2048 + WG - 1) / WG), dim3(WG), 0, stream>>>(A1T, perm2, 2048, 1024, BRf2);
  mfma_nt_k<<<dim3(8, 8, 8), dim3(256), 0, stream>>>(BLf2, BRf2, Pbuf, 1024, 1024, 2048, 256);
  mfredrow_k<<<dim3(1024), dim3(WG), 0, stream>>>(Pbuf, A2, 1024, 8, dinvL[2], fixvL[2]);
  gcn_dense(A2, 1024, XA, 64, Wd[2], 128, bd[2], 1, XS2, dinvL[2], fixvL[2], 128, 8);

  // ---- level 3 (fp32 augment: values exceed bf16-exact range) ----
  pool(XS2, 1024, 128, pw[2], perm3, rank3, XA);
  gatherL_k<<<dim3((512 * 1024 + WG - 1) / WG), dim3(WG), 0, stream>>>(A2, perm3, 1024, 512, BLf34);
  gatherR_k<<<dim3((1024 * 512 + WG - 1) / WG), dim3(WG), 0, stream>>>(A2, perm3, 1024, 512, BRf34);
  sgemm(BLf34, BRf34, A3, 512, 512, 1024, nullptr, nullptr, 0, 0, 0);
  rowsum_k<<<dim3(512), dim3(WG), 0, stream>>>(A3, 512, dinvL[3], fixvL[3]);
  gcn_dense(A3, 512, XA, 128, Wd[3], 256, bd[3], 1, XS3, dinvL[3], fixvL[3], 64, 8);

  // ---- level 4 ----
  pool(XS3, 512, 256, pw[3], perm4, rank4, XA);
  gatherL_k<<<dim3((256 * 512 + WG - 1) / WG), dim3(WG), 0, stream>>>(A3, perm4, 512, 256, BLf34);
  gatherR_k<<<dim3((512 * 256 + WG - 1) / WG), dim3(WG), 0, stream>>>(A3, perm4, 512, 256, BRf34);
  sgemm(BLf34, BRf34, A4, 256, 256, 512, nullptr, nullptr, 0, 0, 0);
  rowsum_k<<<dim3(256), dim3(WG), 0, stream>>>(A4, 256, dinvL[4], fixvL[4]);
  gcn_dense(A4, 256, XA, 256, Wd[4], 512, bd[4], 1, XB, dinvL[4], fixvL[4], 64, 4);

  // ---- up path (fused unpool-concat via saved rank arrays) ----
  catfull_k<<<dim3((512 * 512 + WG - 1) / WG), dim3(WG), 0, stream>>>(XS3, XB, rank4, 512, 256, 512, XA);
  gcn_dense(A3, 512, XA, 512, Wu[0], 256, bu[0], 1, XB, dinvL[3], fixvL[3], 64, 8);

  catfull_k<<<dim3((1024 * 256 + WG - 1) / WG), dim3(WG), 0, stream>>>(XS2, XB, rank3, 1024, 128, 256, XA);
  gcn_dense(A2, 1024, XA, 256, Wu[1], 128, bu[1], 1, XB, dinvL[2], fixvL[2], 128, 8);

  catfull_k<<<dim3((2048 * 128 + WG - 1) / WG), dim3(WG), 0, stream>>>(XS1, XB, rank2, 2048, 64, 128, XA);
  gcn_dense(A1, 2048, XA, 128, Wu[2], 64, bu[2], 1, XB, dinvL[1], fixvL[1], 256, 8);

  catfull_k<<<dim3((4096 * 64 + WG - 1) / WG), dim3(WG), 0, stream>>>(XS0, XB, rank1, 4096, 32, 64, XA);
  sgemm(XA, Wu[3], y, 4096, 32, 64, dinvL[0], nullptr, 0, 0, 0);
  spmv_k<1><<<dim3(1024), dim3(256), 0, stream>>>(offb, bys, y, 32, dinvL[0], fixvL[0], bu[3], 0, XB);

  // ---- final GCN (sparse A0) + softmax ----
  sgemm(XB, Wo, y, 4096, 37, 32, dinvL[0], nullptr, 0, 0, 0);
  spmv_k<0><<<dim3(1024), dim3(256), 0, stream>>>(offb, bys, y, 37, dinvL[0], fixvL[0], bo, 0, XA);
  softmax_k<<<dim3((4096 + WG - 1) / WG), dim3(WG), 0, stream>>>(XA, out, 4096, 37);
}